// Round 1
// baseline (9720.113 us; speedup 1.0000x reference)
//
#include <hip/hip_runtime.h>
#include <hip/hip_bf16.h>
#include <math.h>

#define L_ALL 704
#define NB 64
#define DM 256
#define HD 32
#define M_TOT (L_ALL*NB)
#define Q_SCALE 0.17677669529663687f

// ---------------------------------------------------------------- QKV GEMM
// X (45056 x 256) @ W (256 x 768) + bias -> scatter to q/k/v [h][b][t][32]
__global__ __launch_bounds__(256) void k_qkv(const float* __restrict__ X,
    const float* __restrict__ W, const float* __restrict__ bias,
    float* __restrict__ qb, float* __restrict__ kb, float* __restrict__ vb) {
  __shared__ float Xs[16][66];
  __shared__ float Ws[16][64];
  const int tid = threadIdx.x;
  const int m0 = blockIdx.x * 64;
  const int n0 = blockIdx.y * 64;
  const int ty = tid >> 4, tx = tid & 15;
  const int lr = tid >> 2, lc4 = (tid & 3) * 4;   // X tile load
  const int wr = tid >> 4, wc4 = (tid & 15) * 4;  // W tile load
  float acc[4][4] = {};
  for (int k0 = 0; k0 < 256; k0 += 16) {
    float4 xv = *(const float4*)(X + (size_t)(m0 + lr) * DM + k0 + lc4);
    Xs[lc4 + 0][lr] = xv.x; Xs[lc4 + 1][lr] = xv.y;
    Xs[lc4 + 2][lr] = xv.z; Xs[lc4 + 3][lr] = xv.w;
    *(float4*)&Ws[wr][wc4] = *(const float4*)(W + (size_t)(k0 + wr) * 768 + n0 + wc4);
    __syncthreads();
#pragma unroll
    for (int kk = 0; kk < 16; ++kk) {
      float a0 = Xs[kk][ty*4+0], a1 = Xs[kk][ty*4+1], a2 = Xs[kk][ty*4+2], a3 = Xs[kk][ty*4+3];
      float b0 = Ws[kk][tx*4+0], b1 = Ws[kk][tx*4+1], b2 = Ws[kk][tx*4+2], b3 = Ws[kk][tx*4+3];
      acc[0][0] += a0*b0; acc[0][1] += a0*b1; acc[0][2] += a0*b2; acc[0][3] += a0*b3;
      acc[1][0] += a1*b0; acc[1][1] += a1*b1; acc[1][2] += a1*b2; acc[1][3] += a1*b3;
      acc[2][0] += a2*b0; acc[2][1] += a2*b1; acc[2][2] += a2*b2; acc[2][3] += a2*b3;
      acc[3][0] += a3*b0; acc[3][1] += a3*b1; acc[3][2] += a3*b2; acc[3][3] += a3*b3;
    }
    __syncthreads();
  }
#pragma unroll
  for (int i = 0; i < 4; ++i) {
    int m = m0 + ty * 4 + i;
    int t = m >> 6, bb = m & 63;
#pragma unroll
    for (int j = 0; j < 4; ++j) {
      int jj = n0 + tx * 4 + j;
      float v = acc[i][j] + bias[jj];
      int sect = jj >> 8;
      int hh = (jj & 255) >> 5;
      int e = jj & 31;
      size_t di = ((size_t)(hh * 64 + bb) * L_ALL + t) * HD + e;
      if (sect == 0)      qb[di] = v * Q_SCALE;
      else if (sect == 1) kb[di] = v;
      else                vb[di] = v;
    }
  }
}

// ---------------------------------------------------------------- ws=1 attention (heads 0,4)
__global__ __launch_bounds__(256) void k_attn1(const float* __restrict__ qb,
    const float* __restrict__ kb, const float* __restrict__ vb,
    const float* __restrict__ rel, float* __restrict__ ao) {
  const int i = blockIdx.x;
  const int b = blockIdx.y;
  const int h = blockIdx.z ? 4 : 0;
  const int tid = threadIdx.x;
  __shared__ float qv[32];
  __shared__ float sc[L_ALL];
  __shared__ float red[4];
  __shared__ float part[8][32];
  const size_t base = (size_t)(h * 64 + b) * L_ALL * HD;
  if (tid < 32) qv[tid] = qb[base + (size_t)i * HD + tid];
  __syncthreads();
  float lmax = -1e30f;
  for (int j = tid; j < L_ALL; j += 256) {
    const float4* kr = (const float4*)(kb + base + (size_t)j * HD);
    float4 k0 = kr[0], k1 = kr[1], k2 = kr[2], k3 = kr[3];
    float4 k4 = kr[4], k5 = kr[5], k6 = kr[6], k7 = kr[7];
    float d;
    d  = qv[0]*k0.x + qv[1]*k0.y + qv[2]*k0.z + qv[3]*k0.w;
    d += qv[4]*k1.x + qv[5]*k1.y + qv[6]*k1.z + qv[7]*k1.w;
    d += qv[8]*k2.x + qv[9]*k2.y + qv[10]*k2.z + qv[11]*k2.w;
    d += qv[12]*k3.x + qv[13]*k3.y + qv[14]*k3.z + qv[15]*k3.w;
    d += qv[16]*k4.x + qv[17]*k4.y + qv[18]*k4.z + qv[19]*k4.w;
    d += qv[20]*k5.x + qv[21]*k5.y + qv[22]*k5.z + qv[23]*k5.w;
    d += qv[24]*k6.x + qv[25]*k6.y + qv[26]*k6.z + qv[27]*k6.w;
    d += qv[28]*k7.x + qv[29]*k7.y + qv[30]*k7.z + qv[31]*k7.w;
    d += rel[(size_t)i * L_ALL + j];
    sc[j] = d;
    lmax = fmaxf(lmax, d);
  }
  for (int off = 32; off; off >>= 1) lmax = fmaxf(lmax, __shfl_down(lmax, off));
  if ((tid & 63) == 0) red[tid >> 6] = lmax;
  __syncthreads();
  float mx = fmaxf(fmaxf(red[0], red[1]), fmaxf(red[2], red[3]));
  __syncthreads();
  float lsum = 0.f;
  for (int j = tid; j < L_ALL; j += 256) {
    float p = __expf(sc[j] - mx);
    sc[j] = p;
    lsum += p;
  }
  for (int off = 32; off; off >>= 1) lsum += __shfl_down(lsum, off);
  if ((tid & 63) == 0) red[tid >> 6] = lsum;
  __syncthreads();
  float invS = 1.0f / (red[0] + red[1] + red[2] + red[3]);
  const int e = tid & 31, g = tid >> 5;
  float acc = 0.f;
  for (int j = g; j < L_ALL; j += 8)
    acc += sc[j] * vb[base + (size_t)j * HD + e];
  part[g][e] = acc;
  __syncthreads();
  if (tid < 32) {
    float s = 0.f;
#pragma unroll
    for (int gg = 0; gg < 8; ++gg) s += part[gg][tid];
    ao[((size_t)i * 64 + b) * DM + h * HD + tid] = s * invS;
  }
}

// ---------------------------------------------------------------- ws>1 attention
__device__ __forceinline__ float wfun(int t, int ws) {
  float f = (float)t / (float)ws;
  return f > 0.5f ? f : 1.0f - f;
}

template<int WS>
__global__ __launch_bounds__(256) void k_attnw(const float* __restrict__ qb,
    const float* __restrict__ kb, const float* __restrict__ vb,
    const float* __restrict__ rel, float* __restrict__ ao,
    int headA, int headB, int shiftB) {
  constexpr int WS2 = WS * WS;
  constexpr int LW = (WS == 2) ? 1 : (WS == 4) ? 2 : 3;
  constexpr int LW2 = 2 * LW;
  constexpr int NW8 = 8 / WS;
  constexpr int N1 = NW8 * NW8;
  constexpr int NW24 = 24 / WS;
  constexpr int NOUT = (WS2 * 32 + 255) / 256;
  const int i = blockIdx.x;
  const int b = blockIdx.y;
  const int h = blockIdx.z ? headB : headA;
  const int shift = blockIdx.z ? shiftB : 0;
  const int tid = threadIdx.x;
  __shared__ float qt[32 * WS2];     // transposed [e][u]
  __shared__ float sc[L_ALL];
  __shared__ int toktab[L_ALL];
  __shared__ float red[4];
  const size_t base = (size_t)(h * 64 + b) * L_ALL * HD;

  // token table for every (window l, in-window pos u)
  for (int idx = tid; idx < L_ALL; idx += 256) {
    int l = idx >> LW2, u = idx & (WS2 - 1);
    int a = u >> LW, c = u & (WS - 1);
    int t;
    if (l < 2 * N1) {
      int fr = l / N1, li = l % N1;
      int wi = li / NW8, wj = li % NW8;
      t = fr * 64 + (wi * WS + a) * 8 + (wj * WS + c);
    } else {
      int ls = l - 2 * N1;
      int wi = ls / NW24, wj = ls % NW24;
      int r = (wi * WS + a + shift) % 24;
      int cc = (wj * WS + c + shift) % 24;
      t = 128 + r * 24 + cc;
    }
    toktab[idx] = t;
  }
  __syncthreads();
  // stage q window transposed
  for (int idx = tid; idx < WS2 * 32; idx += 256) {
    int u = idx >> 5, e = idx & 31;
    qt[e * WS2 + u] = qb[base + (size_t)toktab[(i << LW2) + u] * HD + e];
  }
  __syncthreads();

  float lmax = -1e30f;
  for (int J = tid; J < L_ALL; J += 256) {
    int l = J >> LW2;
    int r = J & (WS2 - 1);
    int mi = r >> LW, ni = r & (WS - 1);
    float acc = 0.f;
    for (int a = 0; a < WS; ++a) {
      int am = ((a + mi) & (WS - 1)) * WS;
#pragma unroll
      for (int c = 0; c < WS; ++c) {
        int qu = am + ((c + ni) & (WS - 1));
        int kt = toktab[(l << LW2) + a * WS + c];
        const float4* kr = (const float4*)(kb + base + (size_t)kt * HD);
        float4 k0 = kr[0], k1 = kr[1], k2 = kr[2], k3 = kr[3];
        float4 k4 = kr[4], k5 = kr[5], k6 = kr[6], k7 = kr[7];
        acc += qt[0*WS2+qu]*k0.x + qt[1*WS2+qu]*k0.y + qt[2*WS2+qu]*k0.z + qt[3*WS2+qu]*k0.w;
        acc += qt[4*WS2+qu]*k1.x + qt[5*WS2+qu]*k1.y + qt[6*WS2+qu]*k1.z + qt[7*WS2+qu]*k1.w;
        acc += qt[8*WS2+qu]*k2.x + qt[9*WS2+qu]*k2.y + qt[10*WS2+qu]*k2.z + qt[11*WS2+qu]*k2.w;
        acc += qt[12*WS2+qu]*k3.x + qt[13*WS2+qu]*k3.y + qt[14*WS2+qu]*k3.z + qt[15*WS2+qu]*k3.w;
        acc += qt[16*WS2+qu]*k4.x + qt[17*WS2+qu]*k4.y + qt[18*WS2+qu]*k4.z + qt[19*WS2+qu]*k4.w;
        acc += qt[20*WS2+qu]*k5.x + qt[21*WS2+qu]*k5.y + qt[22*WS2+qu]*k5.z + qt[23*WS2+qu]*k5.w;
        acc += qt[24*WS2+qu]*k6.x + qt[25*WS2+qu]*k6.y + qt[26*WS2+qu]*k6.z + qt[27*WS2+qu]*k6.w;
        acc += qt[28*WS2+qu]*k7.x + qt[29*WS2+qu]*k7.y + qt[30*WS2+qu]*k7.z + qt[31*WS2+qu]*k7.w;
      }
    }
    float s = (acc + (wfun(mi, WS) * wfun(ni, WS) - 1.0f)) * (1.0f / WS2)
            + rel[(size_t)i * L_ALL + J];
    sc[J] = s;
    lmax = fmaxf(lmax, s);
  }
  for (int off = 32; off; off >>= 1) lmax = fmaxf(lmax, __shfl_down(lmax, off));
  if ((tid & 63) == 0) red[tid >> 6] = lmax;
  __syncthreads();
  float mx = fmaxf(fmaxf(red[0], red[1]), fmaxf(red[2], red[3]));
  __syncthreads();
  float lsum = 0.f;
  for (int J = tid; J < L_ALL; J += 256) {
    float p = __expf(sc[J] - mx);
    sc[J] = p;
    lsum += p;
  }
  for (int off = 32; off; off >>= 1) lsum += __shfl_down(lsum, off);
  if ((tid & 63) == 0) red[tid >> 6] = lsum;
  __syncthreads();
  float invS = 1.0f / (red[0] + red[1] + red[2] + red[3]);

  // phase 2: outputs
  float oacc[NOUT] = {};
  int apA[NOUT], bpA[NOUT], eA[NOUT];
#pragma unroll
  for (int o = 0; o < NOUT; ++o) {
    int oidx = tid + o * 256;
    int up = oidx >> 5;
    apA[o] = (up >> LW) & (WS - 1);
    bpA[o] = up & (WS - 1);
    eA[o] = oidx & 31;
  }
  for (int J = 0; J < L_ALL; ++J) {
    int l = J >> LW2;
    int r = J & (WS2 - 1);
    int mi = r >> LW, ni = r & (WS - 1);
    float p = sc[J];
#pragma unroll
    for (int o = 0; o < NOUT; ++o) {
      int vt = toktab[(l << LW2) + (((apA[o] - mi) & (WS - 1)) << LW) + ((bpA[o] - ni) & (WS - 1))];
      oacc[o] += p * vb[base + (size_t)vt * HD + eA[o]];
    }
  }
#pragma unroll
  for (int o = 0; o < NOUT; ++o) {
    int oidx = tid + o * 256;
    if (oidx < WS2 * 32) {
      int up = oidx >> 5;
      int t = toktab[(i << LW2) + up];
      ao[((size_t)t * 64 + b) * DM + h * HD + eA[o]] = oacc[o] * invS;
    }
  }
}

// ---------------------------------------------------------------- out proj + residual
__global__ __launch_bounds__(256) void k_proj(const float* __restrict__ A,
    const float* __restrict__ W, const float* __restrict__ bias,
    const float* __restrict__ X0, float* __restrict__ out) {
  __shared__ float Xs[16][66];
  __shared__ float Ws[16][64];
  const int tid = threadIdx.x;
  const int m0 = blockIdx.x * 64;
  const int n0 = blockIdx.y * 64;
  const int ty = tid >> 4, tx = tid & 15;
  const int lr = tid >> 2, lc4 = (tid & 3) * 4;
  const int wr = tid >> 4, wc4 = (tid & 15) * 4;
  float acc[4][4] = {};
  for (int k0 = 0; k0 < 256; k0 += 16) {
    float4 xv = *(const float4*)(A + (size_t)(m0 + lr) * DM + k0 + lc4);
    Xs[lc4 + 0][lr] = xv.x; Xs[lc4 + 1][lr] = xv.y;
    Xs[lc4 + 2][lr] = xv.z; Xs[lc4 + 3][lr] = xv.w;
    *(float4*)&Ws[wr][wc4] = *(const float4*)(W + (size_t)(k0 + wr) * DM + n0 + wc4);
    __syncthreads();
#pragma unroll
    for (int kk = 0; kk < 16; ++kk) {
      float a0 = Xs[kk][ty*4+0], a1 = Xs[kk][ty*4+1], a2 = Xs[kk][ty*4+2], a3 = Xs[kk][ty*4+3];
      float b0 = Ws[kk][tx*4+0], b1 = Ws[kk][tx*4+1], b2 = Ws[kk][tx*4+2], b3 = Ws[kk][tx*4+3];
      acc[0][0] += a0*b0; acc[0][1] += a0*b1; acc[0][2] += a0*b2; acc[0][3] += a0*b3;
      acc[1][0] += a1*b0; acc[1][1] += a1*b1; acc[1][2] += a1*b2; acc[1][3] += a1*b3;
      acc[2][0] += a2*b0; acc[2][1] += a2*b1; acc[2][2] += a2*b2; acc[2][3] += a2*b3;
      acc[3][0] += a3*b0; acc[3][1] += a3*b1; acc[3][2] += a3*b2; acc[3][3] += a3*b3;
    }
    __syncthreads();
  }
#pragma unroll
  for (int i = 0; i < 4; ++i) {
    size_t m = m0 + ty * 4 + i;
#pragma unroll
    for (int j = 0; j < 4; ++j) {
      int jj = n0 + tx * 4 + j;
      out[m * DM + jj] = acc[i][j] + bias[jj] + X0[m * DM + jj];
    }
  }
}

// ---------------------------------------------------------------- layernorm
__global__ __launch_bounds__(256) void k_ln(const float* __restrict__ in,
    const float* __restrict__ g, const float* __restrict__ be,
    float* __restrict__ out) {
  const size_t row = (size_t)blockIdx.x * 4 + (threadIdx.x >> 6);
  const int lane = threadIdx.x & 63;
  float4 v = *(const float4*)(in + row * DM + lane * 4);
  float s = v.x + v.y + v.z + v.w;
  float q = v.x*v.x + v.y*v.y + v.z*v.z + v.w*v.w;
  for (int off = 32; off; off >>= 1) { s += __shfl_down(s, off); q += __shfl_down(q, off); }
  s = __shfl(s, 0); q = __shfl(q, 0);
  float mu = s * (1.0f / 256.0f);
  float var = q * (1.0f / 256.0f) - mu * mu;
  float inv = rsqrtf(var + 1e-5f);
  float4 gv = *(const float4*)(g + lane * 4);
  float4 bv = *(const float4*)(be + lane * 4);
  float4 o;
  o.x = (v.x - mu) * inv * gv.x + bv.x;
  o.y = (v.y - mu) * inv * gv.y + bv.y;
  o.z = (v.z - mu) * inv * gv.z + bv.z;
  o.w = (v.w - mu) * inv * gv.w + bv.w;
  *(float4*)(out + row * DM + lane * 4) = o;
}

// ---------------------------------------------------------------- fused FFN + LN2
__global__ __launch_bounds__(256) void k_ffn(const float* __restrict__ x1,
    const float* __restrict__ W1, const float* __restrict__ b1,
    const float* __restrict__ W2, const float* __restrict__ b2,
    const float* __restrict__ g, const float* __restrict__ be,
    float* __restrict__ out) {
  __shared__ float xs[32][DM];
  __shared__ float hs[32][64];
  const int tid = threadIdx.x;
  const int r0 = blockIdx.x * 32;
  for (int idx = tid; idx < 32 * 64; idx += 256) {
    int rr = idx >> 6, c4 = (idx & 63) * 4;
    *(float4*)&xs[rr][c4] = *(const float4*)(x1 + (size_t)(r0 + rr) * DM + c4);
  }
  __syncthreads();
  float acc[32] = {};
  const int kk_l = tid & 63, rr4 = tid >> 6;
  for (int ch = 0; ch < 32; ++ch) {
    float ha[8] = {};
    const float* w1p = W1 + ch * 64 + kk_l;
    for (int k = 0; k < 256; ++k) {
      float w = w1p[(size_t)k * 2048];
#pragma unroll
      for (int p = 0; p < 8; ++p) ha[p] += xs[rr4 * 8 + p][k] * w;
    }
    float bb = b1[ch * 64 + kk_l];
#pragma unroll
    for (int p = 0; p < 8; ++p) hs[rr4 * 8 + p][kk_l] = fmaxf(ha[p] + bb, 0.f);
    __syncthreads();
    const float* w2p = W2 + (size_t)ch * 64 * DM + tid;
    for (int kk = 0; kk < 64; ++kk) {
      float w = w2p[(size_t)kk * DM];
#pragma unroll
      for (int r = 0; r < 32; ++r) acc[r] += hs[r][kk] * w;
    }
    __syncthreads();
  }
  float bj = b2[tid];
#pragma unroll
  for (int r = 0; r < 32; ++r) xs[r][tid] = acc[r] + bj + xs[r][tid];
  __syncthreads();
  const int lane = tid & 63, w = tid >> 6;
  float4 gv = *(const float4*)(g + lane * 4);
  float4 bv = *(const float4*)(be + lane * 4);
  for (int rr = w * 8; rr < w * 8 + 8; ++rr) {
    float4 v = *(const float4*)&xs[rr][lane * 4];
    float s = v.x + v.y + v.z + v.w;
    float q = v.x*v.x + v.y*v.y + v.z*v.z + v.w*v.w;
    for (int off = 32; off; off >>= 1) { s += __shfl_down(s, off); q += __shfl_down(q, off); }
    s = __shfl(s, 0); q = __shfl(q, 0);
    float mu = s * (1.0f / 256.0f);
    float var = q * (1.0f / 256.0f) - mu * mu;
    float inv = rsqrtf(var + 1e-5f);
    float4 o;
    o.x = (v.x - mu) * inv * gv.x + bv.x;
    o.y = (v.y - mu) * inv * gv.y + bv.y;
    o.z = (v.z - mu) * inv * gv.z + bv.z;
    o.w = (v.w - mu) * inv * gv.w + bv.w;
    *(float4*)(out + (size_t)(r0 + rr) * DM + lane * 4) = o;
  }
}

// ---------------------------------------------------------------- launch
extern "C" void kernel_launch(void* const* d_in, const int* in_sizes, int n_in,
                              void* d_out, int out_size, void* d_ws, size_t ws_size,
                              hipStream_t stream) {
  const float* X    = (const float*)d_in[0];
  const float* Wqkv = (const float*)d_in[2];
  const float* bqkv = (const float*)d_in[3];
  const float* Wout = (const float*)d_in[4];
  const float* bout = (const float*)d_in[5];
  const float* W1   = (const float*)d_in[6];
  const float* b1   = (const float*)d_in[7];
  const float* W2   = (const float*)d_in[8];
  const float* b2   = (const float*)d_in[9];
  const float* g1   = (const float*)d_in[10];
  const float* be1  = (const float*)d_in[11];
  const float* g2   = (const float*)d_in[12];
  const float* be2  = (const float*)d_in[13];
  const float* rel1 = (const float*)d_in[14];
  const float* rel2 = (const float*)d_in[15];
  const float* rel4 = (const float*)d_in[16];
  const float* rel8 = (const float*)d_in[17];
  float* out = (float*)d_out;
  float* wsf = (float*)d_ws;
  const size_t NE = (size_t)8 * 64 * L_ALL * HD;  // 11,534,336
  float* qb = wsf;
  float* kb = qb + NE;
  float* vb = kb + NE;
  float* ao = vb + NE;
  float* rs = qb;  // reuse after attention
  float* x1 = kb;  // reuse after LN1 input consumed

  k_qkv<<<dim3(704, 12), 256, 0, stream>>>(X, Wqkv, bqkv, qb, kb, vb);
  k_attn1<<<dim3(704, 64, 2), 256, 0, stream>>>(qb, kb, vb, rel1, ao);
  k_attnw<2><<<dim3(176, 64, 2), 256, 0, stream>>>(qb, kb, vb, rel2, ao, 1, 5, 1);
  k_attnw<4><<<dim3(44, 64, 2), 256, 0, stream>>>(qb, kb, vb, rel4, ao, 2, 6, 2);
  k_attnw<8><<<dim3(11, 64, 2), 256, 0, stream>>>(qb, kb, vb, rel8, ao, 3, 7, 4);
  k_proj<<<dim3(704, 4), 256, 0, stream>>>(ao, Wout, bout, X, rs);
  k_ln<<<dim3(M_TOT / 4), 256, 0, stream>>>(rs, g1, be1, x1);
  k_ffn<<<dim3(M_TOT / 32), 256, 0, stream>>>(x1, W1, b1, W2, b2, g2, be2, out);
}

// Round 2
// 5610.706 us; speedup vs baseline: 1.7324x; 1.7324x over previous
//
#include <hip/hip_runtime.h>
#include <hip/hip_bf16.h>
#include <math.h>

#define L_ALL 704
#define NB 64
#define DM 256
#define HD 32
#define M_TOT (L_ALL*NB)
#define Q_SCALE 0.17677669529663687f

typedef __attribute__((ext_vector_type(8))) short bf16x8;
typedef __attribute__((ext_vector_type(4))) float f32x4;

static __device__ __forceinline__ unsigned short f2b(float x) {
  __hip_bfloat16 h = __float2bfloat16(x);
  return *reinterpret_cast<unsigned short*>(&h);
}

// ---------------------------------------------------------------- QKV GEMM
// X (45056 x 256) @ W (256 x 768) + bias -> scatter to q/k/v [h][b][t][32]
__global__ __launch_bounds__(256) void k_qkv(const float* __restrict__ X,
    const float* __restrict__ W, const float* __restrict__ bias,
    float* __restrict__ qb, float* __restrict__ kb, float* __restrict__ vb) {
  __shared__ float Xs[16][66];
  __shared__ float Ws[16][64];
  const int tid = threadIdx.x;
  const int m0 = blockIdx.x * 64;
  const int n0 = blockIdx.y * 64;
  const int ty = tid >> 4, tx = tid & 15;
  const int lr = tid >> 2, lc4 = (tid & 3) * 4;   // X tile load
  const int wr = tid >> 4, wc4 = (tid & 15) * 4;  // W tile load
  float acc[4][4] = {};
  for (int k0 = 0; k0 < 256; k0 += 16) {
    float4 xv = *(const float4*)(X + (size_t)(m0 + lr) * DM + k0 + lc4);
    Xs[lc4 + 0][lr] = xv.x; Xs[lc4 + 1][lr] = xv.y;
    Xs[lc4 + 2][lr] = xv.z; Xs[lc4 + 3][lr] = xv.w;
    *(float4*)&Ws[wr][wc4] = *(const float4*)(W + (size_t)(k0 + wr) * 768 + n0 + wc4);
    __syncthreads();
#pragma unroll
    for (int kk = 0; kk < 16; ++kk) {
      float a0 = Xs[kk][ty*4+0], a1 = Xs[kk][ty*4+1], a2 = Xs[kk][ty*4+2], a3 = Xs[kk][ty*4+3];
      float b0 = Ws[kk][tx*4+0], b1 = Ws[kk][tx*4+1], b2 = Ws[kk][tx*4+2], b3 = Ws[kk][tx*4+3];
      acc[0][0] += a0*b0; acc[0][1] += a0*b1; acc[0][2] += a0*b2; acc[0][3] += a0*b3;
      acc[1][0] += a1*b0; acc[1][1] += a1*b1; acc[1][2] += a1*b2; acc[1][3] += a1*b3;
      acc[2][0] += a2*b0; acc[2][1] += a2*b1; acc[2][2] += a2*b2; acc[2][3] += a2*b3;
      acc[3][0] += a3*b0; acc[3][1] += a3*b1; acc[3][2] += a3*b2; acc[3][3] += a3*b3;
    }
    __syncthreads();
  }
#pragma unroll
  for (int i = 0; i < 4; ++i) {
    int m = m0 + ty * 4 + i;
    int t = m >> 6, bb = m & 63;
#pragma unroll
    for (int j = 0; j < 4; ++j) {
      int jj = n0 + tx * 4 + j;
      float v = acc[i][j] + bias[jj];
      int sect = jj >> 8;
      int hh = (jj & 255) >> 5;
      int e = jj & 31;
      size_t di = ((size_t)(hh * 64 + bb) * L_ALL + t) * HD + e;
      if (sect == 0)      qb[di] = v * Q_SCALE;
      else if (sect == 1) kb[di] = v;
      else                vb[di] = v;
    }
  }
}

// ---------------------------------------------------------------- ws=1 attention (heads 0,4)
__global__ __launch_bounds__(256) void k_attn1(const float* __restrict__ qb,
    const float* __restrict__ kb, const float* __restrict__ vb,
    const float* __restrict__ rel, float* __restrict__ ao) {
  const int i = blockIdx.x;
  const int b = blockIdx.y;
  const int h = blockIdx.z ? 4 : 0;
  const int tid = threadIdx.x;
  __shared__ float qv[32];
  __shared__ float sc[L_ALL];
  __shared__ float red[4];
  __shared__ float part[8][32];
  const size_t base = (size_t)(h * 64 + b) * L_ALL * HD;
  if (tid < 32) qv[tid] = qb[base + (size_t)i * HD + tid];
  __syncthreads();
  float lmax = -1e30f;
  for (int j = tid; j < L_ALL; j += 256) {
    const float4* kr = (const float4*)(kb + base + (size_t)j * HD);
    float4 k0 = kr[0], k1 = kr[1], k2 = kr[2], k3 = kr[3];
    float4 k4 = kr[4], k5 = kr[5], k6 = kr[6], k7 = kr[7];
    float d;
    d  = qv[0]*k0.x + qv[1]*k0.y + qv[2]*k0.z + qv[3]*k0.w;
    d += qv[4]*k1.x + qv[5]*k1.y + qv[6]*k1.z + qv[7]*k1.w;
    d += qv[8]*k2.x + qv[9]*k2.y + qv[10]*k2.z + qv[11]*k2.w;
    d += qv[12]*k3.x + qv[13]*k3.y + qv[14]*k3.z + qv[15]*k3.w;
    d += qv[16]*k4.x + qv[17]*k4.y + qv[18]*k4.z + qv[19]*k4.w;
    d += qv[20]*k5.x + qv[21]*k5.y + qv[22]*k5.z + qv[23]*k5.w;
    d += qv[24]*k6.x + qv[25]*k6.y + qv[26]*k6.z + qv[27]*k6.w;
    d += qv[28]*k7.x + qv[29]*k7.y + qv[30]*k7.z + qv[31]*k7.w;
    d += rel[(size_t)i * L_ALL + j];
    sc[j] = d;
    lmax = fmaxf(lmax, d);
  }
  for (int off = 32; off; off >>= 1) lmax = fmaxf(lmax, __shfl_down(lmax, off));
  if ((tid & 63) == 0) red[tid >> 6] = lmax;
  __syncthreads();
  float mx = fmaxf(fmaxf(red[0], red[1]), fmaxf(red[2], red[3]));
  __syncthreads();
  float lsum = 0.f;
  for (int j = tid; j < L_ALL; j += 256) {
    float p = __expf(sc[j] - mx);
    sc[j] = p;
    lsum += p;
  }
  for (int off = 32; off; off >>= 1) lsum += __shfl_down(lsum, off);
  if ((tid & 63) == 0) red[tid >> 6] = lsum;
  __syncthreads();
  float invS = 1.0f / (red[0] + red[1] + red[2] + red[3]);
  const int e = tid & 31, g = tid >> 5;
  float acc = 0.f;
  for (int j = g; j < L_ALL; j += 8)
    acc += sc[j] * vb[base + (size_t)j * HD + e];
  part[g][e] = acc;
  __syncthreads();
  if (tid < 32) {
    float s = 0.f;
#pragma unroll
    for (int gg = 0; gg < 8; ++gg) s += part[gg][tid];
    ao[((size_t)i * 64 + b) * DM + h * HD + tid] = s * invS;
  }
}

// ---------------------------------------------------------------- ws>1 attention
__device__ __forceinline__ float wfun(int t, int ws) {
  float f = (float)t / (float)ws;
  return f > 0.5f ? f : 1.0f - f;
}

template<int WS>
__global__ __launch_bounds__(256) void k_attnw(const float* __restrict__ qb,
    const float* __restrict__ kb, const float* __restrict__ vb,
    const float* __restrict__ rel, float* __restrict__ ao,
    int headA, int headB, int shiftB) {
  constexpr int WS2 = WS * WS;
  constexpr int LW = (WS == 2) ? 1 : (WS == 4) ? 2 : 3;
  constexpr int LW2 = 2 * LW;
  constexpr int NW8 = 8 / WS;
  constexpr int N1 = NW8 * NW8;
  constexpr int NW24 = 24 / WS;
  constexpr int NOUT = (WS2 * 32 + 255) / 256;
  const int i = blockIdx.x;
  const int b = blockIdx.y;
  const int h = blockIdx.z ? headB : headA;
  const int shift = blockIdx.z ? shiftB : 0;
  const int tid = threadIdx.x;
  __shared__ float qt[32 * WS2];     // transposed [e][u]
  __shared__ float sc[L_ALL];
  __shared__ int toktab[L_ALL];
  __shared__ float red[4];
  const size_t base = (size_t)(h * 64 + b) * L_ALL * HD;

  // token table for every (window l, in-window pos u)
  for (int idx = tid; idx < L_ALL; idx += 256) {
    int l = idx >> LW2, u = idx & (WS2 - 1);
    int a = u >> LW, c = u & (WS - 1);
    int t;
    if (l < 2 * N1) {
      int fr = l / N1, li = l % N1;
      int wi = li / NW8, wj = li % NW8;
      t = fr * 64 + (wi * WS + a) * 8 + (wj * WS + c);
    } else {
      int ls = l - 2 * N1;
      int wi = ls / NW24, wj = ls % NW24;
      int r = (wi * WS + a + shift) % 24;
      int cc = (wj * WS + c + shift) % 24;
      t = 128 + r * 24 + cc;
    }
    toktab[idx] = t;
  }
  __syncthreads();
  // stage q window transposed
  for (int idx = tid; idx < WS2 * 32; idx += 256) {
    int u = idx >> 5, e = idx & 31;
    qt[e * WS2 + u] = qb[base + (size_t)toktab[(i << LW2) + u] * HD + e];
  }
  __syncthreads();

  float lmax = -1e30f;
  for (int J = tid; J < L_ALL; J += 256) {
    int l = J >> LW2;
    int r = J & (WS2 - 1);
    int mi = r >> LW, ni = r & (WS - 1);
    float acc = 0.f;
    for (int a = 0; a < WS; ++a) {
      int am = ((a + mi) & (WS - 1)) * WS;
#pragma unroll
      for (int c = 0; c < WS; ++c) {
        int qu = am + ((c + ni) & (WS - 1));
        int kt = toktab[(l << LW2) + a * WS + c];
        const float4* kr = (const float4*)(kb + base + (size_t)kt * HD);
        float4 k0 = kr[0], k1 = kr[1], k2 = kr[2], k3 = kr[3];
        float4 k4 = kr[4], k5 = kr[5], k6 = kr[6], k7 = kr[7];
        acc += qt[0*WS2+qu]*k0.x + qt[1*WS2+qu]*k0.y + qt[2*WS2+qu]*k0.z + qt[3*WS2+qu]*k0.w;
        acc += qt[4*WS2+qu]*k1.x + qt[5*WS2+qu]*k1.y + qt[6*WS2+qu]*k1.z + qt[7*WS2+qu]*k1.w;
        acc += qt[8*WS2+qu]*k2.x + qt[9*WS2+qu]*k2.y + qt[10*WS2+qu]*k2.z + qt[11*WS2+qu]*k2.w;
        acc += qt[12*WS2+qu]*k3.x + qt[13*WS2+qu]*k3.y + qt[14*WS2+qu]*k3.z + qt[15*WS2+qu]*k3.w;
        acc += qt[16*WS2+qu]*k4.x + qt[17*WS2+qu]*k4.y + qt[18*WS2+qu]*k4.z + qt[19*WS2+qu]*k4.w;
        acc += qt[20*WS2+qu]*k5.x + qt[21*WS2+qu]*k5.y + qt[22*WS2+qu]*k5.z + qt[23*WS2+qu]*k5.w;
        acc += qt[24*WS2+qu]*k6.x + qt[25*WS2+qu]*k6.y + qt[26*WS2+qu]*k6.z + qt[27*WS2+qu]*k6.w;
        acc += qt[28*WS2+qu]*k7.x + qt[29*WS2+qu]*k7.y + qt[30*WS2+qu]*k7.z + qt[31*WS2+qu]*k7.w;
      }
    }
    float s = (acc + (wfun(mi, WS) * wfun(ni, WS) - 1.0f)) * (1.0f / WS2)
            + rel[(size_t)i * L_ALL + J];
    sc[J] = s;
    lmax = fmaxf(lmax, s);
  }
  for (int off = 32; off; off >>= 1) lmax = fmaxf(lmax, __shfl_down(lmax, off));
  if ((tid & 63) == 0) red[tid >> 6] = lmax;
  __syncthreads();
  float mx = fmaxf(fmaxf(red[0], red[1]), fmaxf(red[2], red[3]));
  __syncthreads();
  float lsum = 0.f;
  for (int J = tid; J < L_ALL; J += 256) {
    float p = __expf(sc[J] - mx);
    sc[J] = p;
    lsum += p;
  }
  for (int off = 32; off; off >>= 1) lsum += __shfl_down(lsum, off);
  if ((tid & 63) == 0) red[tid >> 6] = lsum;
  __syncthreads();
  float invS = 1.0f / (red[0] + red[1] + red[2] + red[3]);

  // phase 2: outputs
  float oacc[NOUT] = {};
  int apA[NOUT], bpA[NOUT], eA[NOUT];
#pragma unroll
  for (int o = 0; o < NOUT; ++o) {
    int oidx = tid + o * 256;
    int up = oidx >> 5;
    apA[o] = (up >> LW) & (WS - 1);
    bpA[o] = up & (WS - 1);
    eA[o] = oidx & 31;
  }
  for (int J = 0; J < L_ALL; ++J) {
    int l = J >> LW2;
    int r = J & (WS2 - 1);
    int mi = r >> LW, ni = r & (WS - 1);
    float p = sc[J];
#pragma unroll
    for (int o = 0; o < NOUT; ++o) {
      int vt = toktab[(l << LW2) + (((apA[o] - mi) & (WS - 1)) << LW) + ((bpA[o] - ni) & (WS - 1))];
      oacc[o] += p * vb[base + (size_t)vt * HD + eA[o]];
    }
  }
#pragma unroll
  for (int o = 0; o < NOUT; ++o) {
    int oidx = tid + o * 256;
    if (oidx < WS2 * 32) {
      int up = oidx >> 5;
      int t = toktab[(i << LW2) + up];
      ao[((size_t)t * 64 + b) * DM + h * HD + eA[o]] = oacc[o] * invS;
    }
  }
}

// ---------------------------------------------------------------- out proj + residual
__global__ __launch_bounds__(256) void k_proj(const float* __restrict__ A,
    const float* __restrict__ W, const float* __restrict__ bias,
    const float* __restrict__ X0, float* __restrict__ out) {
  __shared__ float Xs[16][66];
  __shared__ float Ws[16][64];
  const int tid = threadIdx.x;
  const int m0 = blockIdx.x * 64;
  const int n0 = blockIdx.y * 64;
  const int ty = tid >> 4, tx = tid & 15;
  const int lr = tid >> 2, lc4 = (tid & 3) * 4;
  const int wr = tid >> 4, wc4 = (tid & 15) * 4;
  float acc[4][4] = {};
  for (int k0 = 0; k0 < 256; k0 += 16) {
    float4 xv = *(const float4*)(A + (size_t)(m0 + lr) * DM + k0 + lc4);
    Xs[lc4 + 0][lr] = xv.x; Xs[lc4 + 1][lr] = xv.y;
    Xs[lc4 + 2][lr] = xv.z; Xs[lc4 + 3][lr] = xv.w;
    *(float4*)&Ws[wr][wc4] = *(const float4*)(W + (size_t)(k0 + wr) * DM + n0 + wc4);
    __syncthreads();
#pragma unroll
    for (int kk = 0; kk < 16; ++kk) {
      float a0 = Xs[kk][ty*4+0], a1 = Xs[kk][ty*4+1], a2 = Xs[kk][ty*4+2], a3 = Xs[kk][ty*4+3];
      float b0 = Ws[kk][tx*4+0], b1 = Ws[kk][tx*4+1], b2 = Ws[kk][tx*4+2], b3 = Ws[kk][tx*4+3];
      acc[0][0] += a0*b0; acc[0][1] += a0*b1; acc[0][2] += a0*b2; acc[0][3] += a0*b3;
      acc[1][0] += a1*b0; acc[1][1] += a1*b1; acc[1][2] += a1*b2; acc[1][3] += a1*b3;
      acc[2][0] += a2*b0; acc[2][1] += a2*b1; acc[2][2] += a2*b2; acc[2][3] += a2*b3;
      acc[3][0] += a3*b0; acc[3][1] += a3*b1; acc[3][2] += a3*b2; acc[3][3] += a3*b3;
    }
    __syncthreads();
  }
#pragma unroll
  for (int i = 0; i < 4; ++i) {
    size_t m = m0 + ty * 4 + i;
#pragma unroll
    for (int j = 0; j < 4; ++j) {
      int jj = n0 + tx * 4 + j;
      out[m * DM + jj] = acc[i][j] + bias[jj] + X0[m * DM + jj];
    }
  }
}

// ---------------------------------------------------------------- layernorm (fp32 + bf16 out)
__global__ __launch_bounds__(256) void k_ln(const float* __restrict__ in,
    const float* __restrict__ g, const float* __restrict__ be,
    float* __restrict__ out, unsigned short* __restrict__ outb) {
  const size_t row = (size_t)blockIdx.x * 4 + (threadIdx.x >> 6);
  const int lane = threadIdx.x & 63;
  float4 v = *(const float4*)(in + row * DM + lane * 4);
  float s = v.x + v.y + v.z + v.w;
  float q = v.x*v.x + v.y*v.y + v.z*v.z + v.w*v.w;
  for (int off = 32; off; off >>= 1) { s += __shfl_down(s, off); q += __shfl_down(q, off); }
  s = __shfl(s, 0); q = __shfl(q, 0);
  float mu = s * (1.0f / 256.0f);
  float var = q * (1.0f / 256.0f) - mu * mu;
  float inv = rsqrtf(var + 1e-5f);
  float4 gv = *(const float4*)(g + lane * 4);
  float4 bv = *(const float4*)(be + lane * 4);
  float4 o;
  o.x = (v.x - mu) * inv * gv.x + bv.x;
  o.y = (v.y - mu) * inv * gv.y + bv.y;
  o.z = (v.z - mu) * inv * gv.z + bv.z;
  o.w = (v.w - mu) * inv * gv.w + bv.w;
  *(float4*)(out + row * DM + lane * 4) = o;
  ushort4 ob;
  ob.x = f2b(o.x); ob.y = f2b(o.y); ob.z = f2b(o.z); ob.w = f2b(o.w);
  *(ushort4*)(outb + row * DM + lane * 4) = ob;
}

// ---------------------------------------------------------------- weight convert+transpose
// dst[c][r] = bf16(src[r][c]); src is R x C
__global__ __launch_bounds__(256) void k_cvtw(const float* __restrict__ src,
    unsigned short* __restrict__ dst, int R, int C) {
  __shared__ float tile[32][33];
  const int r0 = blockIdx.x * 32, c0 = blockIdx.y * 32;
  const int tr = threadIdx.x >> 5, tc = threadIdx.x & 31;
#pragma unroll
  for (int i = 0; i < 4; ++i)
    tile[tr + i * 8][tc] = src[(size_t)(r0 + tr + i * 8) * C + c0 + tc];
  __syncthreads();
#pragma unroll
  for (int i = 0; i < 4; ++i)
    dst[(size_t)(c0 + tr + i * 8) * R + r0 + tc] = f2b(tile[tc][tr + i * 8]);
}

// ---------------------------------------------------------------- fused FFN + LN2 (bf16 MFMA)
// x1b: [45056][256] bf16   W1t: [2048][256] bf16 (W1t[n][k]=W1[k][n])
// W2t: [256][2048] bf16 (W2t[n][k]=W2[k][n])
__global__ __launch_bounds__(256) void k_ffn2(
    const unsigned short* __restrict__ x1b, const float* __restrict__ x1,
    const unsigned short* __restrict__ W1t, const float* __restrict__ b1,
    const unsigned short* __restrict__ W2t, const float* __restrict__ b2,
    const float* __restrict__ g, const float* __restrict__ be,
    float* __restrict__ out) {
  __shared__ unsigned short Hl[64 * 64];   // swizzled bf16 hidden tile
  __shared__ float b1s[2048];
  __shared__ float b2s[256], gs[256], bs[256];
  const int tid = threadIdx.x;
  const int w = tid >> 6, l = tid & 63;
  const int li = l & 15, g16 = l >> 4;
  const int m0 = blockIdx.x * 64;
  for (int i = tid; i < 2048; i += 256) b1s[i] = b1[i];
  b2s[tid & 255] = b2[tid & 255];
  gs[tid & 255] = g[tid & 255];
  bs[tid & 255] = be[tid & 255];
  __syncthreads();

  f32x4 acc2[16];
#pragma unroll
  for (int i = 0; i < 16; ++i) acc2[i] = (f32x4){0.f, 0.f, 0.f, 0.f};
  const int arow = m0 + w * 16 + li;
  const unsigned short* aptr = x1b + (size_t)arow * 256 + g16 * 8;

  for (int ch = 0; ch < 32; ++ch) {
    // ---- GEMM1: H[16 rows of this wave][64] = relu(x1 @ W1chunk + b1)
    f32x4 hacc[4];
#pragma unroll
    for (int f = 0; f < 4; ++f) hacc[f] = (f32x4){0.f, 0.f, 0.f, 0.f};
#pragma unroll
    for (int kk = 0; kk < 8; ++kk) {
      bf16x8 a = *(const bf16x8*)(aptr + kk * 32);
#pragma unroll
      for (int f = 0; f < 4; ++f) {
        const unsigned short* bp = W1t + (size_t)(ch * 64 + f * 16 + li) * 256 + kk * 32 + g16 * 8;
        bf16x8 bfr = *(const bf16x8*)bp;
        hacc[f] = __builtin_amdgcn_mfma_f32_16x16x32_bf16(a, bfr, hacc[f], 0, 0, 0);
      }
    }
    // relu + bias -> LDS (XOR-swizzled rows)
#pragma unroll
    for (int f = 0; f < 4; ++f) {
      int col = f * 16 + li;
      float bb = b1s[ch * 64 + col];
#pragma unroll
      for (int r = 0; r < 4; ++r) {
        int row = w * 16 + g16 * 4 + r;
        float hv = fmaxf(hacc[f][r] + bb, 0.f);
        unsigned off = (unsigned)((row * 64 + col) * 2) ^ (unsigned)((row & 7) << 4);
        *(unsigned short*)((char*)Hl + off) = f2b(hv);
      }
    }
    __syncthreads();
    // ---- GEMM2: acc2 += H @ W2chunk
#pragma unroll
    for (int ks = 0; ks < 2; ++ks) {
      int hrow = w * 16 + li;
      unsigned off = (unsigned)((hrow * 64 + ks * 32 + g16 * 8) * 2) ^ (unsigned)((hrow & 7) << 4);
      bf16x8 a = *(const bf16x8*)((char*)Hl + off);
#pragma unroll
      for (int nb = 0; nb < 16; ++nb) {
        const unsigned short* bp = W2t + (size_t)(nb * 16 + li) * 2048 + ch * 64 + ks * 32 + g16 * 8;
        bf16x8 bfr = *(const bf16x8*)bp;
        acc2[nb] = __builtin_amdgcn_mfma_f32_16x16x32_bf16(a, bfr, acc2[nb], 0, 0, 0);
      }
    }
    __syncthreads();
  }

  // ---- epilogue: +b2 +residual, LN over 256 cols (16-lane-group shuffle reduce)
  float s[4] = {0.f, 0.f, 0.f, 0.f}, q[4] = {0.f, 0.f, 0.f, 0.f};
#pragma unroll
  for (int nb = 0; nb < 16; ++nb) {
    int col = nb * 16 + li;
    float bb = b2s[col];
#pragma unroll
    for (int r = 0; r < 4; ++r) {
      int row = m0 + w * 16 + g16 * 4 + r;
      float v = acc2[nb][r] + bb + x1[(size_t)row * 256 + col];
      acc2[nb][r] = v;
      s[r] += v; q[r] += v * v;
    }
  }
#pragma unroll
  for (int r = 0; r < 4; ++r) {
    float ss = s[r], qq = q[r];
    for (int m = 1; m < 16; m <<= 1) { ss += __shfl_xor(ss, m); qq += __shfl_xor(qq, m); }
    float mu = ss * (1.0f / 256.0f);
    float var = qq * (1.0f / 256.0f) - mu * mu;
    s[r] = mu; q[r] = rsqrtf(var + 1e-5f);
  }
#pragma unroll
  for (int nb = 0; nb < 16; ++nb) {
    int col = nb * 16 + li;
    float gv = gs[col], bv = bs[col];
#pragma unroll
    for (int r = 0; r < 4; ++r) {
      int row = m0 + w * 16 + g16 * 4 + r;
      out[(size_t)row * 256 + col] = (acc2[nb][r] - s[r]) * q[r] * gv + bv;
    }
  }
}

// ---------------------------------------------------------------- launch
extern "C" void kernel_launch(void* const* d_in, const int* in_sizes, int n_in,
                              void* d_out, int out_size, void* d_ws, size_t ws_size,
                              hipStream_t stream) {
  const float* X    = (const float*)d_in[0];
  const float* Wqkv = (const float*)d_in[2];
  const float* bqkv = (const float*)d_in[3];
  const float* Wout = (const float*)d_in[4];
  const float* bout = (const float*)d_in[5];
  const float* W1   = (const float*)d_in[6];
  const float* b1   = (const float*)d_in[7];
  const float* W2   = (const float*)d_in[8];
  const float* b2   = (const float*)d_in[9];
  const float* g1   = (const float*)d_in[10];
  const float* be1  = (const float*)d_in[11];
  const float* g2   = (const float*)d_in[12];
  const float* be2  = (const float*)d_in[13];
  const float* rel1 = (const float*)d_in[14];
  const float* rel2 = (const float*)d_in[15];
  const float* rel4 = (const float*)d_in[16];
  const float* rel8 = (const float*)d_in[17];
  float* out = (float*)d_out;
  float* wsf = (float*)d_ws;
  const size_t NE = (size_t)8 * 64 * L_ALL * HD;  // 11,534,336 floats per buffer
  float* qb = wsf;
  float* kb = qb + NE;
  float* vb = kb + NE;
  float* ao = vb + NE;
  float* rs = qb;                       // reuse after attention
  float* x1 = kb;                       // LN1 output fp32
  unsigned short* x1b = (unsigned short*)vb;            // LN1 output bf16 (23MB < 46MB)
  unsigned short* W1t = (unsigned short*)(vb + 6000000); // 1MB
  unsigned short* W2t = (unsigned short*)(vb + 6400000); // 1MB

  k_qkv<<<dim3(704, 12), 256, 0, stream>>>(X, Wqkv, bqkv, qb, kb, vb);
  k_attn1<<<dim3(704, 64, 2), 256, 0, stream>>>(qb, kb, vb, rel1, ao);
  k_attnw<2><<<dim3(176, 64, 2), 256, 0, stream>>>(qb, kb, vb, rel2, ao, 1, 5, 1);
  k_attnw<4><<<dim3(44, 64, 2), 256, 0, stream>>>(qb, kb, vb, rel4, ao, 2, 6, 2);
  k_attnw<8><<<dim3(11, 64, 2), 256, 0, stream>>>(qb, kb, vb, rel8, ao, 3, 7, 4);
  // vb (raw v) is dead after attention; W1t/W2t live in its tail
  k_cvtw<<<dim3(8, 64), 256, 0, stream>>>(W1, W1t, 256, 2048);
  k_cvtw<<<dim3(64, 8), 256, 0, stream>>>(W2, W2t, 2048, 256);
  k_proj<<<dim3(704, 4), 256, 0, stream>>>(ao, Wout, bout, X, rs);
  k_ln<<<dim3(M_TOT / 4), 256, 0, stream>>>(rs, g1, be1, x1, x1b);
  k_ffn2<<<dim3(704), 256, 0, stream>>>(x1b, x1, W1t, b1, W2t, b2, g2, be2, out);
}

// Round 3
// 4751.709 us; speedup vs baseline: 2.0456x; 1.1808x over previous
//
#include <hip/hip_runtime.h>
#include <hip/hip_bf16.h>
#include <math.h>

#define L_ALL 704
#define NB 64
#define DM 256
#define HD 32
#define M_TOT (L_ALL*NB)
#define Q_SCALE 0.17677669529663687f

typedef __attribute__((ext_vector_type(8))) short bf16x8;
typedef __attribute__((ext_vector_type(4))) float f32x4;
typedef unsigned short ushort_t;

static __device__ __forceinline__ unsigned short f2b(float x) {
  __hip_bfloat16 h = __float2bfloat16(x);
  return *reinterpret_cast<unsigned short*>(&h);
}
static __device__ __forceinline__ float blo(unsigned u) { return __uint_as_float(u << 16); }
static __device__ __forceinline__ float bhi(unsigned u) { return __uint_as_float(u & 0xffff0000u); }

// ---------------------------------------------------------------- weight convert+transpose
// dst[c][r] = bf16(src[r][c]); src is R x C.  grid (R/32, C/32)
__global__ __launch_bounds__(256) void k_cvtw(const float* __restrict__ src,
    ushort_t* __restrict__ dst, int R, int C) {
  __shared__ float tile[32][33];
  const int r0 = blockIdx.x * 32, c0 = blockIdx.y * 32;
  const int tr = threadIdx.x >> 5, tc = threadIdx.x & 31;
#pragma unroll
  for (int i = 0; i < 4; ++i)
    tile[tr + i * 8][tc] = src[(size_t)(r0 + tr + i * 8) * C + c0 + tc];
  __syncthreads();
#pragma unroll
  for (int i = 0; i < 4; ++i)
    dst[(size_t)(c0 + tr + i * 8) * R + r0 + tc] = f2b(tile[tc][tr + i * 8]);
}

// ---------------------------------------------------------------- QKV GEMM (bf16 MFMA)
// X fp32 [45056][256] @ Wqkvt bf16 [768][256] -> qbb/kbb/vbb bf16 [m][256], vbt [2][64][32][704]
// grid (704, 3): sec 0=q 1=k 2=v, 64 rows per block
__global__ __launch_bounds__(256) void k_qkv2(const float* __restrict__ X,
    const ushort_t* __restrict__ Wt, const float* __restrict__ bias,
    ushort_t* __restrict__ qbb, ushort_t* __restrict__ kbb,
    ushort_t* __restrict__ vbb, ushort_t* __restrict__ vbt) {
  const int tid = threadIdx.x;
  const int w = tid >> 6, lane = tid & 63, li = lane & 15, g16 = lane >> 4;
  const int m0 = blockIdx.x * 64;
  const int sec = blockIdx.y;
  f32x4 acc[16];
#pragma unroll
  for (int t = 0; t < 16; ++t) acc[t] = (f32x4){0.f, 0.f, 0.f, 0.f};
  const float* arow = X + (size_t)(m0 + w * 16 + li) * 256;
  for (int k0 = 0; k0 < 256; k0 += 32) {
    float4 xa = *(const float4*)(arow + k0 + g16 * 8);
    float4 xb = *(const float4*)(arow + k0 + g16 * 8 + 4);
    bf16x8 a;
    a[0] = f2b(xa.x); a[1] = f2b(xa.y); a[2] = f2b(xa.z); a[3] = f2b(xa.w);
    a[4] = f2b(xb.x); a[5] = f2b(xb.y); a[6] = f2b(xb.z); a[7] = f2b(xb.w);
#pragma unroll
    for (int t = 0; t < 16; ++t) {
      const ushort_t* bp = Wt + (size_t)(sec * 256 + t * 16 + li) * 256 + k0 + g16 * 8;
      bf16x8 bf = *(const bf16x8*)bp;
      acc[t] = __builtin_amdgcn_mfma_f32_16x16x32_bf16(a, bf, acc[t], 0, 0, 0);
    }
  }
#pragma unroll
  for (int t = 0; t < 16; ++t) {
    int col = sec * 256 + t * 16 + li;            // 0..767
    float bv = bias[col];
    int c255 = col & 255;
    int hh = c255 >> 5, e = c255 & 31;
#pragma unroll
    for (int r = 0; r < 4; ++r) {
      int row = m0 + w * 16 + g16 * 4 + r;        // m = token*64 + b
      float v = acc[t][r] + bv;
      size_t di = (size_t)row * 256 + c255;
      if (sec == 0)      qbb[di] = f2b(v * Q_SCALE);
      else if (sec == 1) kbb[di] = f2b(v);
      else {
        vbb[di] = f2b(v);
        if ((hh & 3) == 0) {
          int slot = hh >> 2;
          int tok = row >> 6, b = row & 63;
          vbt[((size_t)(slot * 64 + b) * 32 + e) * 704 + tok] = f2b(v);
        }
      }
    }
  }
}

// ---------------------------------------------------------------- ws=1 attention (MFMA flash)
// grid (11, 64, 2): z -> head 0 / 4.  4 waves x 16 query rows.
__global__ __launch_bounds__(256) void k_attn1m(const ushort_t* __restrict__ qbb,
    const ushort_t* __restrict__ kbb, const ushort_t* __restrict__ vbt,
    const float* __restrict__ rel, ushort_t* __restrict__ ao) {
  __shared__ ushort_t P_lds[4 * 512];   // 1KB per wave
  const int tid = threadIdx.x;
  const int w = tid >> 6, lane = tid & 63, li = lane & 15, g16 = lane >> 4;
  const int b = blockIdx.y;
  const int h = blockIdx.z ? 4 : 0;
  const int slot = blockIdx.z;
  const int qrow0 = blockIdx.x * 64 + w * 16;
  char* myP = (char*)P_lds + w * 1024;

  const bf16x8 qfrag = *(const bf16x8*)(qbb +
      (size_t)((qrow0 + li) * 64 + b) * 256 + h * 32 + g16 * 8);
  f32x4 o0 = (f32x4){0.f, 0.f, 0.f, 0.f}, o1 = o0;
  float m_run[4] = {-1e30f, -1e30f, -1e30f, -1e30f};
  float l_run[4] = {0.f, 0.f, 0.f, 0.f};

  const size_t vrow0 = (size_t)(slot * 64 + b) * 32;

  for (int kt = 0; kt < 704; kt += 32) {
    f32x4 s0 = (f32x4){0.f, 0.f, 0.f, 0.f}, s1 = s0;
    bf16x8 kf0 = *(const bf16x8*)(kbb + (size_t)((kt + li) * 64 + b) * 256 + h * 32 + g16 * 8);
    bf16x8 kf1 = *(const bf16x8*)(kbb + (size_t)((kt + 16 + li) * 64 + b) * 256 + h * 32 + g16 * 8);
    s0 = __builtin_amdgcn_mfma_f32_16x16x32_bf16(qfrag, kf0, s0, 0, 0, 0);
    s1 = __builtin_amdgcn_mfma_f32_16x16x32_bf16(qfrag, kf1, s1, 0, 0, 0);
    const float* rb = rel + (size_t)(qrow0 + g16 * 4) * 704 + kt;
#pragma unroll
    for (int r = 0; r < 4; ++r) {
      s0[r] += rb[(size_t)r * 704 + li];
      s1[r] += rb[(size_t)r * 704 + 16 + li];
    }
#pragma unroll
    for (int r = 0; r < 4; ++r) {
      float pm = fmaxf(s0[r], s1[r]);
      for (int m = 1; m < 16; m <<= 1) pm = fmaxf(pm, __shfl_xor(pm, m));
      float mn = fmaxf(m_run[r], pm);
      float corr = __expf(m_run[r] - mn);
      float p0 = __expf(s0[r] - mn);
      float p1 = __expf(s1[r] - mn);
      float ps = p0 + p1;
      for (int m = 1; m < 16; m <<= 1) ps += __shfl_xor(ps, m);
      l_run[r] = l_run[r] * corr + ps;
      m_run[r] = mn;
      o0[r] *= corr; o1[r] *= corr;
      int row = g16 * 4 + r;
      unsigned sw = (unsigned)((row & 7) << 4);
      *(ushort_t*)(myP + (((unsigned)(row * 64 + li * 2)) ^ sw)) = f2b(p0);
      *(ushort_t*)(myP + (((unsigned)(row * 64 + 32 + li * 2)) ^ sw)) = f2b(p1);
    }
    // PV: A = P (row=li, k=g16*8+j), B = V^T
    bf16x8 pa = *(const bf16x8*)(myP + (((unsigned)(li * 64 + g16 * 16)) ^ ((unsigned)((li & 7) << 4))));
    bf16x8 v0 = *(const bf16x8*)(vbt + (vrow0 + li) * 704 + kt + g16 * 8);
    bf16x8 v1 = *(const bf16x8*)(vbt + (vrow0 + 16 + li) * 704 + kt + g16 * 8);
    o0 = __builtin_amdgcn_mfma_f32_16x16x32_bf16(pa, v0, o0, 0, 0, 0);
    o1 = __builtin_amdgcn_mfma_f32_16x16x32_bf16(pa, v1, o1, 0, 0, 0);
  }
#pragma unroll
  for (int r = 0; r < 4; ++r) {
    float inv = 1.0f / l_run[r];
    int token = qrow0 + g16 * 4 + r;
    size_t orow = (size_t)(token * 64 + b) * 256 + h * 32;
    ao[orow + li] = f2b(o0[r] * inv);
    ao[orow + 16 + li] = f2b(o1[r] * inv);
  }
}

// ---------------------------------------------------------------- ws>1 attention (bf16 in)
__device__ __forceinline__ float wfun(int t, int ws) {
  float f = (float)t / (float)ws;
  return f > 0.5f ? f : 1.0f - f;
}

template<int WS>
__global__ __launch_bounds__(256) void k_attnw(const ushort_t* __restrict__ qbb,
    const ushort_t* __restrict__ kbb, const ushort_t* __restrict__ vbb,
    const float* __restrict__ rel, ushort_t* __restrict__ ao,
    int headA, int headB, int shiftB) {
  constexpr int WS2 = WS * WS;
  constexpr int LW = (WS == 2) ? 1 : (WS == 4) ? 2 : 3;
  constexpr int LW2 = 2 * LW;
  constexpr int NW8 = 8 / WS;
  constexpr int N1 = NW8 * NW8;
  constexpr int NW24 = 24 / WS;
  constexpr int NOUT = (WS2 * 32 + 255) / 256;
  const int i = blockIdx.x;
  const int b = blockIdx.y;
  const int h = blockIdx.z ? headB : headA;
  const int shift = blockIdx.z ? shiftB : 0;
  const int tid = threadIdx.x;
  __shared__ float qt[32 * WS2];     // transposed [e][u]
  __shared__ float sc[L_ALL];
  __shared__ int toktab[L_ALL];
  __shared__ float red[4];

  for (int idx = tid; idx < L_ALL; idx += 256) {
    int l = idx >> LW2, u = idx & (WS2 - 1);
    int a = u >> LW, c = u & (WS - 1);
    int t;
    if (l < 2 * N1) {
      int fr = l / N1, li2 = l % N1;
      int wi = li2 / NW8, wj = li2 % NW8;
      t = fr * 64 + (wi * WS + a) * 8 + (wj * WS + c);
    } else {
      int ls = l - 2 * N1;
      int wi = ls / NW24, wj = ls % NW24;
      int r = (wi * WS + a + shift) % 24;
      int cc = (wj * WS + c + shift) % 24;
      t = 128 + r * 24 + cc;
    }
    toktab[idx] = t;
  }
  __syncthreads();
  for (int idx = tid; idx < WS2 * 32; idx += 256) {
    int u = idx >> 5, e = idx & 31;
    int tok = toktab[(i << LW2) + u];
    qt[e * WS2 + u] = blo(qbb[(size_t)(tok * 64 + b) * 256 + h * 32 + e]);
  }
  __syncthreads();

  float lmax = -1e30f;
  for (int J = tid; J < L_ALL; J += 256) {
    int l = J >> LW2;
    int r = J & (WS2 - 1);
    int mi = r >> LW, ni = r & (WS - 1);
    float acc = 0.f;
    for (int a = 0; a < WS; ++a) {
      int am = ((a + mi) & (WS - 1)) * WS;
#pragma unroll
      for (int c = 0; c < WS; ++c) {
        int qu = am + ((c + ni) & (WS - 1));
        int kt = toktab[(l << LW2) + a * WS + c];
        const uint4* kr = (const uint4*)(kbb + (size_t)(kt * 64 + b) * 256 + h * 32);
        uint4 u0 = kr[0], u1 = kr[1], u2 = kr[2], u3 = kr[3];
        float kv[32];
        kv[0]=blo(u0.x); kv[1]=bhi(u0.x); kv[2]=blo(u0.y); kv[3]=bhi(u0.y);
        kv[4]=blo(u0.z); kv[5]=bhi(u0.z); kv[6]=blo(u0.w); kv[7]=bhi(u0.w);
        kv[8]=blo(u1.x); kv[9]=bhi(u1.x); kv[10]=blo(u1.y); kv[11]=bhi(u1.y);
        kv[12]=blo(u1.z); kv[13]=bhi(u1.z); kv[14]=blo(u1.w); kv[15]=bhi(u1.w);
        kv[16]=blo(u2.x); kv[17]=bhi(u2.x); kv[18]=blo(u2.y); kv[19]=bhi(u2.y);
        kv[20]=blo(u2.z); kv[21]=bhi(u2.z); kv[22]=blo(u2.w); kv[23]=bhi(u2.w);
        kv[24]=blo(u3.x); kv[25]=bhi(u3.x); kv[26]=blo(u3.y); kv[27]=bhi(u3.y);
        kv[28]=blo(u3.z); kv[29]=bhi(u3.z); kv[30]=blo(u3.w); kv[31]=bhi(u3.w);
        float s_ = 0.f;
#pragma unroll
        for (int e = 0; e < 32; ++e) s_ += qt[e * WS2 + qu] * kv[e];
        acc += s_;
      }
    }
    float s = (acc + (wfun(mi, WS) * wfun(ni, WS) - 1.0f)) * (1.0f / WS2)
            + rel[(size_t)i * L_ALL + J];
    sc[J] = s;
    lmax = fmaxf(lmax, s);
  }
  for (int off = 32; off; off >>= 1) lmax = fmaxf(lmax, __shfl_down(lmax, off));
  if ((tid & 63) == 0) red[tid >> 6] = lmax;
  __syncthreads();
  float mx = fmaxf(fmaxf(red[0], red[1]), fmaxf(red[2], red[3]));
  __syncthreads();
  float lsum = 0.f;
  for (int J = tid; J < L_ALL; J += 256) {
    float p = __expf(sc[J] - mx);
    sc[J] = p;
    lsum += p;
  }
  for (int off = 32; off; off >>= 1) lsum += __shfl_down(lsum, off);
  if ((tid & 63) == 0) red[tid >> 6] = lsum;
  __syncthreads();
  float invS = 1.0f / (red[0] + red[1] + red[2] + red[3]);

  float oacc[NOUT] = {};
  int apA[NOUT], bpA[NOUT], eA[NOUT];
#pragma unroll
  for (int o = 0; o < NOUT; ++o) {
    int oidx = tid + o * 256;
    int up = oidx >> 5;
    apA[o] = (up >> LW) & (WS - 1);
    bpA[o] = up & (WS - 1);
    eA[o] = oidx & 31;
  }
  for (int J = 0; J < L_ALL; ++J) {
    int l = J >> LW2;
    int r = J & (WS2 - 1);
    int mi = r >> LW, ni = r & (WS - 1);
    float p = sc[J];
#pragma unroll
    for (int o = 0; o < NOUT; ++o) {
      int vt = toktab[(l << LW2) + (((apA[o] - mi) & (WS - 1)) << LW) + ((bpA[o] - ni) & (WS - 1))];
      oacc[o] += p * blo(vbb[(size_t)(vt * 64 + b) * 256 + h * 32 + eA[o]]);
    }
  }
#pragma unroll
  for (int o = 0; o < NOUT; ++o) {
    int oidx = tid + o * 256;
    if (oidx < WS2 * 32) {
      int up = oidx >> 5;
      int t = toktab[(i << LW2) + up];
      ao[(size_t)(t * 64 + b) * 256 + h * 32 + eA[o]] = f2b(oacc[o] * invS);
    }
  }
}

// ---------------------------------------------------------------- out-proj + residual + LN1 (MFMA)
// ao bf16 [m][256] @ Woutt bf16 [256][256] + bout + X0 -> x1 fp32, x1b bf16. grid 704.
__global__ __launch_bounds__(256) void k_projln(const ushort_t* __restrict__ ao,
    const ushort_t* __restrict__ Wt, const float* __restrict__ bout,
    const float* __restrict__ X0, const float* __restrict__ g,
    const float* __restrict__ be, float* __restrict__ x1, ushort_t* __restrict__ x1b) {
  const int tid = threadIdx.x;
  const int w = tid >> 6, lane = tid & 63, li = lane & 15, g16 = lane >> 4;
  const int m0 = blockIdx.x * 64;
  f32x4 acc[16];
#pragma unroll
  for (int t = 0; t < 16; ++t) acc[t] = (f32x4){0.f, 0.f, 0.f, 0.f};
  const ushort_t* arow = ao + (size_t)(m0 + w * 16 + li) * 256;
  for (int k0 = 0; k0 < 256; k0 += 32) {
    bf16x8 a = *(const bf16x8*)(arow + k0 + g16 * 8);
#pragma unroll
    for (int t = 0; t < 16; ++t) {
      bf16x8 bf = *(const bf16x8*)(Wt + (size_t)(t * 16 + li) * 256 + k0 + g16 * 8);
      acc[t] = __builtin_amdgcn_mfma_f32_16x16x32_bf16(a, bf, acc[t], 0, 0, 0);
    }
  }
  float s[4] = {0.f, 0.f, 0.f, 0.f}, q[4] = {0.f, 0.f, 0.f, 0.f};
#pragma unroll
  for (int t = 0; t < 16; ++t) {
    int col = t * 16 + li;
    float bb = bout[col];
#pragma unroll
    for (int r = 0; r < 4; ++r) {
      int row = m0 + w * 16 + g16 * 4 + r;
      float v = acc[t][r] + bb + X0[(size_t)row * 256 + col];
      acc[t][r] = v;
      s[r] += v; q[r] += v * v;
    }
  }
#pragma unroll
  for (int r = 0; r < 4; ++r) {
    float ss = s[r], qq = q[r];
    for (int m = 1; m < 16; m <<= 1) { ss += __shfl_xor(ss, m); qq += __shfl_xor(qq, m); }
    float mu = ss * (1.0f / 256.0f);
    float var = qq * (1.0f / 256.0f) - mu * mu;
    s[r] = mu; q[r] = rsqrtf(var + 1e-5f);
  }
#pragma unroll
  for (int t = 0; t < 16; ++t) {
    int col = t * 16 + li;
    float gv = g[col], bv = be[col];
#pragma unroll
    for (int r = 0; r < 4; ++r) {
      int row = m0 + w * 16 + g16 * 4 + r;
      float o = (acc[t][r] - s[r]) * q[r] * gv + bv;
      x1[(size_t)row * 256 + col] = o;
      x1b[(size_t)row * 256 + col] = f2b(o);
    }
  }
}

// ---------------------------------------------------------------- fused FFN + LN2 (bf16 MFMA)
__global__ __launch_bounds__(256) void k_ffn2(
    const ushort_t* __restrict__ x1b, const float* __restrict__ x1,
    const ushort_t* __restrict__ W1t, const float* __restrict__ b1,
    const ushort_t* __restrict__ W2t, const float* __restrict__ b2,
    const float* __restrict__ g, const float* __restrict__ be,
    float* __restrict__ out) {
  __shared__ ushort_t Hl[64 * 64];
  __shared__ float b1s[2048];
  __shared__ float b2s[256], gs[256], bs[256];
  const int tid = threadIdx.x;
  const int w = tid >> 6, l = tid & 63;
  const int li = l & 15, g16 = l >> 4;
  const int m0 = blockIdx.x * 64;
  for (int i = tid; i < 2048; i += 256) b1s[i] = b1[i];
  b2s[tid & 255] = b2[tid & 255];
  gs[tid & 255] = g[tid & 255];
  bs[tid & 255] = be[tid & 255];
  __syncthreads();

  f32x4 acc2[16];
#pragma unroll
  for (int i = 0; i < 16; ++i) acc2[i] = (f32x4){0.f, 0.f, 0.f, 0.f};
  const int arow = m0 + w * 16 + li;
  const ushort_t* aptr = x1b + (size_t)arow * 256 + g16 * 8;

  for (int ch = 0; ch < 32; ++ch) {
    f32x4 hacc[4];
#pragma unroll
    for (int f = 0; f < 4; ++f) hacc[f] = (f32x4){0.f, 0.f, 0.f, 0.f};
#pragma unroll
    for (int kk = 0; kk < 8; ++kk) {
      bf16x8 a = *(const bf16x8*)(aptr + kk * 32);
#pragma unroll
      for (int f = 0; f < 4; ++f) {
        const ushort_t* bp = W1t + (size_t)(ch * 64 + f * 16 + li) * 256 + kk * 32 + g16 * 8;
        bf16x8 bfr = *(const bf16x8*)bp;
        hacc[f] = __builtin_amdgcn_mfma_f32_16x16x32_bf16(a, bfr, hacc[f], 0, 0, 0);
      }
    }
#pragma unroll
    for (int f = 0; f < 4; ++f) {
      int col = f * 16 + li;
      float bb = b1s[ch * 64 + col];
#pragma unroll
      for (int r = 0; r < 4; ++r) {
        int row = w * 16 + g16 * 4 + r;
        float hv = fmaxf(hacc[f][r] + bb, 0.f);
        unsigned off = (unsigned)((row * 64 + col) * 2) ^ (unsigned)((row & 7) << 4);
        *(ushort_t*)((char*)Hl + off) = f2b(hv);
      }
    }
    __syncthreads();
#pragma unroll
    for (int ks = 0; ks < 2; ++ks) {
      int hrow = w * 16 + li;
      unsigned off = (unsigned)((hrow * 64 + ks * 32 + g16 * 8) * 2) ^ (unsigned)((hrow & 7) << 4);
      bf16x8 a = *(const bf16x8*)((char*)Hl + off);
#pragma unroll
      for (int nb = 0; nb < 16; ++nb) {
        const ushort_t* bp = W2t + (size_t)(nb * 16 + li) * 2048 + ch * 64 + ks * 32 + g16 * 8;
        bf16x8 bfr = *(const bf16x8*)bp;
        acc2[nb] = __builtin_amdgcn_mfma_f32_16x16x32_bf16(a, bfr, acc2[nb], 0, 0, 0);
      }
    }
    __syncthreads();
  }

  float s[4] = {0.f, 0.f, 0.f, 0.f}, q[4] = {0.f, 0.f, 0.f, 0.f};
#pragma unroll
  for (int nb = 0; nb < 16; ++nb) {
    int col = nb * 16 + li;
    float bb = b2s[col];
#pragma unroll
    for (int r = 0; r < 4; ++r) {
      int row = m0 + w * 16 + g16 * 4 + r;
      float v = acc2[nb][r] + bb + x1[(size_t)row * 256 + col];
      acc2[nb][r] = v;
      s[r] += v; q[r] += v * v;
    }
  }
#pragma unroll
  for (int r = 0; r < 4; ++r) {
    float ss = s[r], qq = q[r];
    for (int m = 1; m < 16; m <<= 1) { ss += __shfl_xor(ss, m); qq += __shfl_xor(qq, m); }
    float mu = ss * (1.0f / 256.0f);
    float var = qq * (1.0f / 256.0f) - mu * mu;
    s[r] = mu; q[r] = rsqrtf(var + 1e-5f);
  }
#pragma unroll
  for (int nb = 0; nb < 16; ++nb) {
    int col = nb * 16 + li;
    float gv = gs[col], bv = bs[col];
#pragma unroll
    for (int r = 0; r < 4; ++r) {
      int row = m0 + w * 16 + g16 * 4 + r;
      out[(size_t)row * 256 + col] = (acc2[nb][r] - s[r]) * q[r] * gv + bv;
    }
  }
}

// ---------------------------------------------------------------- launch
extern "C" void kernel_launch(void* const* d_in, const int* in_sizes, int n_in,
                              void* d_out, int out_size, void* d_ws, size_t ws_size,
                              hipStream_t stream) {
  const float* X    = (const float*)d_in[0];
  const float* Wqkv = (const float*)d_in[2];
  const float* bqkv = (const float*)d_in[3];
  const float* Wout = (const float*)d_in[4];
  const float* bout = (const float*)d_in[5];
  const float* W1   = (const float*)d_in[6];
  const float* b1   = (const float*)d_in[7];
  const float* W2   = (const float*)d_in[8];
  const float* b2   = (const float*)d_in[9];
  const float* g1   = (const float*)d_in[10];
  const float* be1  = (const float*)d_in[11];
  const float* g2   = (const float*)d_in[12];
  const float* be2  = (const float*)d_in[13];
  const float* rel1 = (const float*)d_in[14];
  const float* rel2 = (const float*)d_in[15];
  const float* rel4 = (const float*)d_in[16];
  const float* rel8 = (const float*)d_in[17];
  float* out = (float*)d_out;

  char* W = (char*)d_ws;
  ushort_t* qbb  = (ushort_t*)(W);                 // 23,068,672
  ushort_t* kbb  = (ushort_t*)(W + 23068672);      // 23,068,672
  ushort_t* vbb  = (ushort_t*)(W + 46137344);      // 23,068,672
  ushort_t* vbt  = (ushort_t*)(W + 69206016);      //  5,767,168
  ushort_t* ao   = (ushort_t*)(W + 74973184);      // 23,068,672
  float*    x1   = (float*)   (W + 98041856);      // 46,137,344
  ushort_t* x1b  = (ushort_t*)(W + 144179200);     // 23,068,672
  ushort_t* Wqkvt= (ushort_t*)(W + 167247872);     //    393,216
  ushort_t* Woutt= (ushort_t*)(W + 167641088);     //    131,072
  ushort_t* W1t  = (ushort_t*)(W + 167772160);     //  1,048,576
  ushort_t* W2t  = (ushort_t*)(W + 168820736);     //  1,048,576

  k_cvtw<<<dim3(8, 24), 256, 0, stream>>>(Wqkv, Wqkvt, 256, 768);
  k_cvtw<<<dim3(8, 8),  256, 0, stream>>>(Wout, Woutt, 256, 256);
  k_cvtw<<<dim3(8, 64), 256, 0, stream>>>(W1, W1t, 256, 2048);
  k_cvtw<<<dim3(64, 8), 256, 0, stream>>>(W2, W2t, 2048, 256);
  k_qkv2<<<dim3(704, 3), 256, 0, stream>>>(X, Wqkvt, bqkv, qbb, kbb, vbb, vbt);
  k_attn1m<<<dim3(11, 64, 2), 256, 0, stream>>>(qbb, kbb, vbt, rel1, ao);
  k_attnw<2><<<dim3(176, 64, 2), 256, 0, stream>>>(qbb, kbb, vbb, rel2, ao, 1, 5, 1);
  k_attnw<4><<<dim3(44, 64, 2), 256, 0, stream>>>(qbb, kbb, vbb, rel4, ao, 2, 6, 2);
  k_attnw<8><<<dim3(11, 64, 2), 256, 0, stream>>>(qbb, kbb, vbb, rel8, ao, 3, 7, 4);
  k_projln<<<dim3(704), 256, 0, stream>>>(ao, Woutt, bout, X, g1, be1, x1, x1b);
  k_ffn2<<<dim3(704), 256, 0, stream>>>(x1b, x1, W1t, b1, W2t, b2, g2, be2, out);
}

// Round 4
// 2074.646 us; speedup vs baseline: 4.6852x; 2.2904x over previous
//
#include <hip/hip_runtime.h>
#include <hip/hip_bf16.h>
#include <math.h>

#define L_ALL 704
#define NB 64
#define DM 256
#define HD 32
#define M_TOT (L_ALL*NB)
#define Q_SCALE 0.17677669529663687f

typedef __attribute__((ext_vector_type(8))) short bf16x8;
typedef __attribute__((ext_vector_type(4))) float f32x4;
typedef unsigned short ushort_t;

static __device__ __forceinline__ unsigned short f2b(float x) {
  __hip_bfloat16 h = __float2bfloat16(x);
  return *reinterpret_cast<unsigned short*>(&h);
}

__device__ __forceinline__ float wfun(int t, int ws) {
  float f = (float)t / (float)ws;
  return f > 0.5f ? f : 1.0f - f;
}

template<int WS>
__device__ __forceinline__ int tokf(int i, int a, int c, int shift) {
  constexpr int NW8 = 8 / WS;          // 4,2,1
  constexpr int N1 = NW8 * NW8;        // 16,4,1
  constexpr int NW24 = 24 / WS;        // 12,6,3
  if (i < 2 * N1) {
    int fr = i / N1, li2 = i % N1;
    int wi = li2 / NW8, wj = li2 % NW8;
    return fr * 64 + (wi * WS + a) * 8 + (wj * WS + c);
  }
  int ls = i - 2 * N1;
  int wi = ls / NW24, wj = ls % NW24;
  int r = (wi * WS + a + shift) % 24;
  int cc = (wj * WS + c + shift) % 24;
  return 128 + r * 24 + cc;
}

// ---------------------------------------------------------------- weight convert+transpose
__global__ __launch_bounds__(256) void k_cvtw(const float* __restrict__ src,
    ushort_t* __restrict__ dst, int R, int C) {
  __shared__ float tile[32][33];
  const int r0 = blockIdx.x * 32, c0 = blockIdx.y * 32;
  const int tr = threadIdx.x >> 5, tc = threadIdx.x & 31;
#pragma unroll
  for (int i = 0; i < 4; ++i)
    tile[tr + i * 8][tc] = src[(size_t)(r0 + tr + i * 8) * C + c0 + tc];
  __syncthreads();
#pragma unroll
  for (int i = 0; i < 4; ++i)
    dst[(size_t)(c0 + tr + i * 8) * R + r0 + tc] = f2b(tile[tc][tr + i * 8]);
}

// ---------------------------------------------------------------- QKV GEMM (bf16 MFMA)
__global__ __launch_bounds__(256) void k_qkv2(const float* __restrict__ X,
    const ushort_t* __restrict__ Wt, const float* __restrict__ bias,
    ushort_t* __restrict__ qbb, ushort_t* __restrict__ kbb,
    ushort_t* __restrict__ vbb, ushort_t* __restrict__ vbt) {
  const int tid = threadIdx.x;
  const int w = tid >> 6, lane = tid & 63, li = lane & 15, g16 = lane >> 4;
  const int m0 = blockIdx.x * 64;
  const int sec = blockIdx.y;
  f32x4 acc[16];
#pragma unroll
  for (int t = 0; t < 16; ++t) acc[t] = (f32x4){0.f, 0.f, 0.f, 0.f};
  const float* arow = X + (size_t)(m0 + w * 16 + li) * 256;
  for (int k0 = 0; k0 < 256; k0 += 32) {
    float4 xa = *(const float4*)(arow + k0 + g16 * 8);
    float4 xb = *(const float4*)(arow + k0 + g16 * 8 + 4);
    bf16x8 a;
    a[0] = f2b(xa.x); a[1] = f2b(xa.y); a[2] = f2b(xa.z); a[3] = f2b(xa.w);
    a[4] = f2b(xb.x); a[5] = f2b(xb.y); a[6] = f2b(xb.z); a[7] = f2b(xb.w);
#pragma unroll
    for (int t = 0; t < 16; ++t) {
      const ushort_t* bp = Wt + (size_t)(sec * 256 + t * 16 + li) * 256 + k0 + g16 * 8;
      bf16x8 bf = *(const bf16x8*)bp;
      acc[t] = __builtin_amdgcn_mfma_f32_16x16x32_bf16(a, bf, acc[t], 0, 0, 0);
    }
  }
#pragma unroll
  for (int t = 0; t < 16; ++t) {
    int col = sec * 256 + t * 16 + li;
    float bv = bias[col];
    int c255 = col & 255;
    int hh = c255 >> 5, e = c255 & 31;
#pragma unroll
    for (int r = 0; r < 4; ++r) {
      int row = m0 + w * 16 + g16 * 4 + r;
      float v = acc[t][r] + bv;
      size_t di = (size_t)row * 256 + c255;
      if (sec == 0)      qbb[di] = f2b(v * Q_SCALE);
      else if (sec == 1) kbb[di] = f2b(v);
      else {
        vbb[di] = f2b(v);
        if ((hh & 3) == 0) {
          int slot = hh >> 2;
          int tok = row >> 6, b = row & 63;
          vbt[((size_t)(slot * 64 + b) * 32 + e) * 704 + tok] = f2b(v);
        }
      }
    }
  }
}

// ---------------------------------------------------------------- ws=1 attention (MFMA flash)
__global__ __launch_bounds__(256) void k_attn1m(const ushort_t* __restrict__ qbb,
    const ushort_t* __restrict__ kbb, const ushort_t* __restrict__ vbt,
    const float* __restrict__ rel, ushort_t* __restrict__ ao) {
  __shared__ ushort_t P_lds[4 * 512];
  const int tid = threadIdx.x;
  const int w = tid >> 6, lane = tid & 63, li = lane & 15, g16 = lane >> 4;
  const int b = blockIdx.y;
  const int h = blockIdx.z ? 4 : 0;
  const int slot = blockIdx.z;
  const int qrow0 = blockIdx.x * 64 + w * 16;
  char* myP = (char*)P_lds + w * 1024;

  const bf16x8 qfrag = *(const bf16x8*)(qbb +
      (size_t)((qrow0 + li) * 64 + b) * 256 + h * 32 + g16 * 8);
  f32x4 o0 = (f32x4){0.f, 0.f, 0.f, 0.f}, o1 = o0;
  float m_run[4] = {-1e30f, -1e30f, -1e30f, -1e30f};
  float l_run[4] = {0.f, 0.f, 0.f, 0.f};

  const size_t vrow0 = (size_t)(slot * 64 + b) * 32;

  for (int kt = 0; kt < 704; kt += 32) {
    f32x4 s0 = (f32x4){0.f, 0.f, 0.f, 0.f}, s1 = s0;
    bf16x8 kf0 = *(const bf16x8*)(kbb + (size_t)((kt + li) * 64 + b) * 256 + h * 32 + g16 * 8);
    bf16x8 kf1 = *(const bf16x8*)(kbb + (size_t)((kt + 16 + li) * 64 + b) * 256 + h * 32 + g16 * 8);
    s0 = __builtin_amdgcn_mfma_f32_16x16x32_bf16(qfrag, kf0, s0, 0, 0, 0);
    s1 = __builtin_amdgcn_mfma_f32_16x16x32_bf16(qfrag, kf1, s1, 0, 0, 0);
    const float* rb = rel + (size_t)(qrow0 + g16 * 4) * 704 + kt;
#pragma unroll
    for (int r = 0; r < 4; ++r) {
      s0[r] += rb[(size_t)r * 704 + li];
      s1[r] += rb[(size_t)r * 704 + 16 + li];
    }
#pragma unroll
    for (int r = 0; r < 4; ++r) {
      float pm = fmaxf(s0[r], s1[r]);
      for (int m = 1; m < 16; m <<= 1) pm = fmaxf(pm, __shfl_xor(pm, m));
      float mn = fmaxf(m_run[r], pm);
      float corr = __expf(m_run[r] - mn);
      float p0 = __expf(s0[r] - mn);
      float p1 = __expf(s1[r] - mn);
      float ps = p0 + p1;
      for (int m = 1; m < 16; m <<= 1) ps += __shfl_xor(ps, m);
      l_run[r] = l_run[r] * corr + ps;
      m_run[r] = mn;
      o0[r] *= corr; o1[r] *= corr;
      int row = g16 * 4 + r;
      unsigned sw = (unsigned)((row & 7) << 4);
      *(ushort_t*)(myP + (((unsigned)(row * 64 + li * 2)) ^ sw)) = f2b(p0);
      *(ushort_t*)(myP + (((unsigned)(row * 64 + 32 + li * 2)) ^ sw)) = f2b(p1);
    }
    bf16x8 pa = *(const bf16x8*)(myP + (((unsigned)(li * 64 + g16 * 16)) ^ ((unsigned)((li & 7) << 4))));
    bf16x8 v0 = *(const bf16x8*)(vbt + (vrow0 + li) * 704 + kt + g16 * 8);
    bf16x8 v1 = *(const bf16x8*)(vbt + (vrow0 + 16 + li) * 704 + kt + g16 * 8);
    o0 = __builtin_amdgcn_mfma_f32_16x16x32_bf16(pa, v0, o0, 0, 0, 0);
    o1 = __builtin_amdgcn_mfma_f32_16x16x32_bf16(pa, v1, o1, 0, 0, 0);
  }
#pragma unroll
  for (int r = 0; r < 4; ++r) {
    float inv = 1.0f / l_run[r];
    int token = qrow0 + g16 * 4 + r;
    size_t orow = (size_t)(token * 64 + b) * 256 + h * 32;
    ao[orow + li] = f2b(o0[r] * inv);
    ao[orow + 16 + li] = f2b(o1[r] * inv);
  }
}

// ---------------------------------------------------------------- window relayout
// qw/kw: [z*64+b][l][cd] bf16 ; vwt: [z*64+b][cd][LPAD16] bf16 (l zero-padded)
template<int WS>
__global__ __launch_bounds__(256) void k_relay(const ushort_t* __restrict__ qbb,
    const ushort_t* __restrict__ kbb, const ushort_t* __restrict__ vbb,
    ushort_t* __restrict__ qw, ushort_t* __restrict__ kw, ushort_t* __restrict__ vwt,
    int hA, int hB) {
  constexpr int G = WS * WS;
  constexpr int M = WS - 1;
  constexpr int LW = (WS == 2) ? 1 : (WS == 4) ? 2 : 3;
  constexpr int NWIN = 704 / G;
  constexpr int CD = G * 32;
  constexpr int LPAD16 = (NWIN + 15) & ~15;
  const int tid = threadIdx.x;
  const int b = blockIdx.y, z = blockIdx.z;
  const int h = z ? hB : hA;
  const int shift = z ? (WS / 2) : 0;
  const size_t sl = (size_t)(z * 64 + b);
  const size_t qkb = sl * NWIN * CD;
  const size_t vb = sl * CD * LPAD16;
  for (int idx2 = tid; idx2 < 4 * (CD / 2); idx2 += 256) {
    int l = blockIdx.x * 4 + idx2 / (CD / 2);
    if (l >= NWIN) break;
    int idx = (idx2 % (CD / 2)) * 2;
    int cell = idx >> 5, e = idx & 31;
    int a = cell >> LW, c = cell & M;
    int tokv = tokf<WS>(l, a, c, shift);
    size_t so = ((size_t)(tokv * 64 + b)) * 256 + h * 32 + e;
    *(unsigned*)(qw + qkb + (size_t)l * CD + idx) = *(const unsigned*)(qbb + so);
    unsigned kv = *(const unsigned*)(kbb + so);
    *(unsigned*)(kw + qkb + (size_t)l * CD + idx) = kv;
    unsigned vv = *(const unsigned*)(vbb + so);
    vwt[vb + (size_t)idx * LPAD16 + l] = (ushort_t)(vv & 0xffffu);
    vwt[vb + (size_t)(idx + 1) * LPAD16 + l] = (ushort_t)(vv >> 16);
  }
  if (LPAD16 > NWIN && blockIdx.x == 0) {
    for (int idx = tid; idx < CD * (LPAD16 - NWIN); idx += 256) {
      int x = idx / (LPAD16 - NWIN);
      int pl = NWIN + idx % (LPAD16 - NWIN);
      vwt[vb + (size_t)x * LPAD16 + pl] = 0;
    }
  }
}

// ---------------------------------------------------------------- ws>1 attention (MFMA group-GEMM)
template<int WS, int NT>
__global__ __launch_bounds__(NT) void k_attnm(const ushort_t* __restrict__ qw,
    const ushort_t* __restrict__ kw, const ushort_t* __restrict__ vwt,
    const float* __restrict__ rel, ushort_t* __restrict__ ao, int hA, int hB) {
  constexpr int G = WS * WS;
  constexpr int M = WS - 1;
  constexpr int LW = (WS == 2) ? 1 : (WS == 4) ? 2 : 3;
  constexpr int NWIN = 704 / G;
  constexpr int CD = G * 32;
  constexpr int LPAD16 = (NWIN + 15) & ~15;
  constexpr int NTL = LPAD16 / 16;
  constexpr int NW = NT / 64;
  constexpr int GPW = G / NW;
  constexpr int TPW_S = GPW * NTL;
  constexpr int XT = CD / 16;
  constexpr int TPW_O = XT / NW;
  constexpr int PSTEPS = (G * LPAD16) / 32;
  constexpr int PSTR = G * LPAD16 + 8;
  constexpr float invG = 1.0f / (float)G;

  __shared__ ushort_t P_lds[16 * PSTR];
  __shared__ float redm[NW][16], reds[NW][16];

  const int tid = threadIdx.x;
  const int w = tid >> 6, lane = tid & 63, li = lane & 15, g16 = lane >> 4;
  const int i0 = blockIdx.x * 16;
  const int b = blockIdx.y, z = blockIdx.z;
  const int h = z ? hB : hA;
  const int shift = z ? (WS / 2) : 0;
  const size_t sl = (size_t)(z * 64 + b);
  const ushort_t* qs = qw + sl * NWIN * CD;
  const ushort_t* ksl = kw + sl * NWIN * CD;
  const ushort_t* vs = vwt + sl * CD * LPAD16;
  const int laneAoff = ((g16 >> 1) << 4) + ((g16 & 1) << 3);

  // ---------------- S phase
  f32x4 sreg[TPW_S];
#pragma unroll
  for (int jg = 0; jg < GPW; ++jg) {
    const int g = w * GPW + jg;
    const int p1 = g >> LW, q1 = g & M;
    const float msk = (wfun(p1, WS) * wfun(q1, WS) - 1.0f) * invG;
    bf16x8 af[(WS <= 4) ? G : 1];
    if constexpr (WS <= 4) {
#pragma unroll
      for (int ksi = 0; ksi < G; ++ksi) {
        int a = ksi >> LW, c = ksi & M;
        int scell = (((a + p1) & M) << LW) | ((c + q1) & M);
        af[ksi] = *(const bf16x8*)(qs + (size_t)(i0 + li) * CD + scell * 32 + g16 * 8);
      }
    }
#pragma unroll
    for (int jn = 0; jn < NTL; ++jn) {
      f32x4 acc = (f32x4){0.f, 0.f, 0.f, 0.f};
      const ushort_t* kbase = ksl + (size_t)(jn * 16 + li) * CD + g16 * 8;
#pragma unroll
      for (int ksi = 0; ksi < G; ++ksi) {
        bf16x8 bfr = *(const bf16x8*)(kbase + ksi * 32);
        bf16x8 afr;
        if constexpr (WS <= 4) {
          afr = af[ksi];
        } else {
          int a = ksi >> LW, c = ksi & M;
          int scell = (((a + p1) & M) << LW) | ((c + q1) & M);
          afr = *(const bf16x8*)(qs + (size_t)(i0 + li) * CD + scell * 32 + g16 * 8);
        }
        acc = __builtin_amdgcn_mfma_f32_16x16x32_bf16(afr, bfr, acc, 0, 0, 0);
      }
#pragma unroll
      for (int r = 0; r < 4; ++r) {
        int iloc = g16 * 4 + r, ig = i0 + iloc, l = jn * 16 + li;
        float s;
        if (ig < NWIN && l < NWIN)
          s = acc[r] * invG + msk + rel[(size_t)ig * 704 + l * G + g];
        else
          s = -3e38f;
        acc[r] = s;
      }
      sreg[jg * NTL + jn] = acc;
    }
  }

  // ---------------- softmax
  float pm[4] = {-3e38f, -3e38f, -3e38f, -3e38f};
#pragma unroll
  for (int t = 0; t < TPW_S; ++t)
#pragma unroll
    for (int r = 0; r < 4; ++r) pm[r] = fmaxf(pm[r], sreg[t][r]);
#pragma unroll
  for (int mm = 1; mm < 16; mm <<= 1)
#pragma unroll
    for (int r = 0; r < 4; ++r) pm[r] = fmaxf(pm[r], __shfl_xor(pm[r], mm));
  if (li == 0) {
#pragma unroll
    for (int r = 0; r < 4; ++r) redm[w][g16 * 4 + r] = pm[r];
  }
  __syncthreads();
  float mrow[4];
#pragma unroll
  for (int r = 0; r < 4; ++r) {
    float v = redm[0][g16 * 4 + r];
    for (int ww = 1; ww < NW; ++ww) v = fmaxf(v, redm[ww][g16 * 4 + r]);
    mrow[r] = v;
  }
  float ps[4] = {0.f, 0.f, 0.f, 0.f};
#pragma unroll
  for (int t = 0; t < TPW_S; ++t)
#pragma unroll
    for (int r = 0; r < 4; ++r) {
      float p = __expf(sreg[t][r] - mrow[r]);
      sreg[t][r] = p;
      ps[r] += p;
    }
#pragma unroll
  for (int mm = 1; mm < 16; mm <<= 1)
#pragma unroll
    for (int r = 0; r < 4; ++r) ps[r] += __shfl_xor(ps[r], mm);
  if (li == 0) {
#pragma unroll
    for (int r = 0; r < 4; ++r) reds[w][g16 * 4 + r] = ps[r];
  }
  __syncthreads();
  float inv4[4];
#pragma unroll
  for (int r = 0; r < 4; ++r) {
    float v = reds[0][g16 * 4 + r];
    for (int ww = 1; ww < NW; ++ww) v += reds[ww][g16 * 4 + r];
    inv4[r] = 1.0f / v;
  }
#pragma unroll
  for (int t = 0; t < TPW_S; ++t) {
    const int g = w * GPW + t / NTL;
    const int col = g * LPAD16 + (t % NTL) * 16 + li;
#pragma unroll
    for (int r = 0; r < 4; ++r)
      P_lds[(size_t)(g16 * 4 + r) * PSTR + col] = f2b(sreg[t][r] * inv4[r]);
  }
  __syncthreads();

  // ---------------- PV phase + scatter out
#pragma unroll
  for (int j = 0; j < TPW_O; ++j) {
    const int ot = w * TPW_O + j;
    const int oc = ot >> 1, oh16 = (ot & 1) << 4;
    const int a_o = oc >> LW, c_o = oc & M;
    f32x4 acc = (f32x4){0.f, 0.f, 0.f, 0.f};
#pragma unroll
    for (int p = 0; p < PSTEPS; ++p) {
      const int kc0 = 2 * p;
      const int g0 = kc0 / NTL, lb0 = kc0 % NTL;
      const int g1 = (kc0 + 1) / NTL, lb1 = (kc0 + 1) % NTL;
      const int p10 = g0 >> LW, q10 = g0 & M;
      const int p11 = g1 >> LW, q11 = g1 & M;
      int sc0 = (((a_o - p10) & M) << LW) | ((c_o - q10) & M);
      int sc1 = (((a_o - p11) & M) << LW) | ((c_o - q11) & M);
      int scl = (g16 < 2) ? sc0 : sc1;
      int lbl = (g16 < 2) ? lb0 : lb1;
      bf16x8 A = *(const bf16x8*)(P_lds + (size_t)li * PSTR + kc0 * 16 + laneAoff);
      bf16x8 B = *(const bf16x8*)(vs + (size_t)(scl * 32 + oh16 + li) * LPAD16 + lbl * 16 + ((g16 & 1) << 3));
      acc = __builtin_amdgcn_mfma_f32_16x16x32_bf16(A, B, acc, 0, 0, 0);
    }
#pragma unroll
    for (int r = 0; r < 4; ++r) {
      int ig = i0 + g16 * 4 + r;
      if (ig < NWIN) {
        int x = ot * 16 + li;
        int cell = x >> 5, e = x & 31;
        int a = cell >> LW, c = cell & M;
        int tokv = tokf<WS>(ig, a, c, shift);
        ao[((size_t)(tokv * 64 + b)) * 256 + h * 32 + e] = f2b(acc[r]);
      }
    }
  }
}

// ---------------------------------------------------------------- out-proj + residual + LN1 (MFMA)
__global__ __launch_bounds__(256) void k_projln(const ushort_t* __restrict__ ao,
    const ushort_t* __restrict__ Wt, const float* __restrict__ bout,
    const float* __restrict__ X0, const float* __restrict__ g,
    const float* __restrict__ be, float* __restrict__ x1, ushort_t* __restrict__ x1b) {
  const int tid = threadIdx.x;
  const int w = tid >> 6, lane = tid & 63, li = lane & 15, g16 = lane >> 4;
  const int m0 = blockIdx.x * 64;
  f32x4 acc[16];
#pragma unroll
  for (int t = 0; t < 16; ++t) acc[t] = (f32x4){0.f, 0.f, 0.f, 0.f};
  const ushort_t* arow = ao + (size_t)(m0 + w * 16 + li) * 256;
  for (int k0 = 0; k0 < 256; k0 += 32) {
    bf16x8 a = *(const bf16x8*)(arow + k0 + g16 * 8);
#pragma unroll
    for (int t = 0; t < 16; ++t) {
      bf16x8 bf = *(const bf16x8*)(Wt + (size_t)(t * 16 + li) * 256 + k0 + g16 * 8);
      acc[t] = __builtin_amdgcn_mfma_f32_16x16x32_bf16(a, bf, acc[t], 0, 0, 0);
    }
  }
  float s[4] = {0.f, 0.f, 0.f, 0.f}, q[4] = {0.f, 0.f, 0.f, 0.f};
#pragma unroll
  for (int t = 0; t < 16; ++t) {
    int col = t * 16 + li;
    float bb = bout[col];
#pragma unroll
    for (int r = 0; r < 4; ++r) {
      int row = m0 + w * 16 + g16 * 4 + r;
      float v = acc[t][r] + bb + X0[(size_t)row * 256 + col];
      acc[t][r] = v;
      s[r] += v; q[r] += v * v;
    }
  }
#pragma unroll
  for (int r = 0; r < 4; ++r) {
    float ss = s[r], qq = q[r];
    for (int m = 1; m < 16; m <<= 1) { ss += __shfl_xor(ss, m); qq += __shfl_xor(qq, m); }
    float mu = ss * (1.0f / 256.0f);
    float var = qq * (1.0f / 256.0f) - mu * mu;
    s[r] = mu; q[r] = rsqrtf(var + 1e-5f);
  }
#pragma unroll
  for (int t = 0; t < 16; ++t) {
    int col = t * 16 + li;
    float gv = g[col], bv = be[col];
#pragma unroll
    for (int r = 0; r < 4; ++r) {
      int row = m0 + w * 16 + g16 * 4 + r;
      float o = (acc[t][r] - s[r]) * q[r] * gv + bv;
      x1[(size_t)row * 256 + col] = o;
      x1b[(size_t)row * 256 + col] = f2b(o);
    }
  }
}

// ---------------------------------------------------------------- fused FFN + LN2 (bf16 MFMA)
__global__ __launch_bounds__(256) void k_ffn2(
    const ushort_t* __restrict__ x1b, const float* __restrict__ x1,
    const ushort_t* __restrict__ W1t, const float* __restrict__ b1,
    const ushort_t* __restrict__ W2t, const float* __restrict__ b2,
    const float* __restrict__ g, const float* __restrict__ be,
    float* __restrict__ out) {
  __shared__ ushort_t Hl[64 * 64];
  __shared__ float b1s[2048];
  __shared__ float b2s[256], gs[256], bs[256];
  const int tid = threadIdx.x;
  const int w = tid >> 6, l = tid & 63;
  const int li = l & 15, g16 = l >> 4;
  const int m0 = blockIdx.x * 64;
  for (int i = tid; i < 2048; i += 256) b1s[i] = b1[i];
  b2s[tid & 255] = b2[tid & 255];
  gs[tid & 255] = g[tid & 255];
  bs[tid & 255] = be[tid & 255];
  __syncthreads();

  f32x4 acc2[16];
#pragma unroll
  for (int i = 0; i < 16; ++i) acc2[i] = (f32x4){0.f, 0.f, 0.f, 0.f};
  const int arow = m0 + w * 16 + li;
  const ushort_t* aptr = x1b + (size_t)arow * 256 + g16 * 8;

  for (int ch = 0; ch < 32; ++ch) {
    f32x4 hacc[4];
#pragma unroll
    for (int f = 0; f < 4; ++f) hacc[f] = (f32x4){0.f, 0.f, 0.f, 0.f};
#pragma unroll
    for (int kk = 0; kk < 8; ++kk) {
      bf16x8 a = *(const bf16x8*)(aptr + kk * 32);
#pragma unroll
      for (int f = 0; f < 4; ++f) {
        const ushort_t* bp = W1t + (size_t)(ch * 64 + f * 16 + li) * 256 + kk * 32 + g16 * 8;
        bf16x8 bfr = *(const bf16x8*)bp;
        hacc[f] = __builtin_amdgcn_mfma_f32_16x16x32_bf16(a, bfr, hacc[f], 0, 0, 0);
      }
    }
#pragma unroll
    for (int f = 0; f < 4; ++f) {
      int col = f * 16 + li;
      float bb = b1s[ch * 64 + col];
#pragma unroll
      for (int r = 0; r < 4; ++r) {
        int row = w * 16 + g16 * 4 + r;
        float hv = fmaxf(hacc[f][r] + bb, 0.f);
        unsigned off = (unsigned)((row * 64 + col) * 2) ^ (unsigned)((row & 7) << 4);
        *(ushort_t*)((char*)Hl + off) = f2b(hv);
      }
    }
    __syncthreads();
#pragma unroll
    for (int ks = 0; ks < 2; ++ks) {
      int hrow = w * 16 + li;
      unsigned off = (unsigned)((hrow * 64 + ks * 32 + g16 * 8) * 2) ^ (unsigned)((hrow & 7) << 4);
      bf16x8 a = *(const bf16x8*)((char*)Hl + off);
#pragma unroll
      for (int nb = 0; nb < 16; ++nb) {
        const ushort_t* bp = W2t + (size_t)(nb * 16 + li) * 2048 + ch * 64 + ks * 32 + g16 * 8;
        bf16x8 bfr = *(const bf16x8*)bp;
        acc2[nb] = __builtin_amdgcn_mfma_f32_16x16x32_bf16(a, bfr, acc2[nb], 0, 0, 0);
      }
    }
    __syncthreads();
  }

  float s[4] = {0.f, 0.f, 0.f, 0.f}, q[4] = {0.f, 0.f, 0.f, 0.f};
#pragma unroll
  for (int nb = 0; nb < 16; ++nb) {
    int col = nb * 16 + li;
    float bb = b2s[col];
#pragma unroll
    for (int r = 0; r < 4; ++r) {
      int row = m0 + w * 16 + g16 * 4 + r;
      float v = acc2[nb][r] + bb + x1[(size_t)row * 256 + col];
      acc2[nb][r] = v;
      s[r] += v; q[r] += v * v;
    }
  }
#pragma unroll
  for (int r = 0; r < 4; ++r) {
    float ss = s[r], qq = q[r];
    for (int m = 1; m < 16; m <<= 1) { ss += __shfl_xor(ss, m); qq += __shfl_xor(qq, m); }
    float mu = ss * (1.0f / 256.0f);
    float var = qq * (1.0f / 256.0f) - mu * mu;
    s[r] = mu; q[r] = rsqrtf(var + 1e-5f);
  }
#pragma unroll
  for (int nb = 0; nb < 16; ++nb) {
    int col = nb * 16 + li;
    float gv = gs[col], bv = bs[col];
#pragma unroll
    for (int r = 0; r < 4; ++r) {
      int row = m0 + w * 16 + g16 * 4 + r;
      out[(size_t)row * 256 + col] = (acc2[nb][r] - s[r]) * q[r] * gv + bv;
    }
  }
}

// ---------------------------------------------------------------- launch
extern "C" void kernel_launch(void* const* d_in, const int* in_sizes, int n_in,
                              void* d_out, int out_size, void* d_ws, size_t ws_size,
                              hipStream_t stream) {
  const float* X    = (const float*)d_in[0];
  const float* Wqkv = (const float*)d_in[2];
  const float* bqkv = (const float*)d_in[3];
  const float* Wout = (const float*)d_in[4];
  const float* bout = (const float*)d_in[5];
  const float* W1   = (const float*)d_in[6];
  const float* b1   = (const float*)d_in[7];
  const float* W2   = (const float*)d_in[8];
  const float* b2   = (const float*)d_in[9];
  const float* g1   = (const float*)d_in[10];
  const float* be1  = (const float*)d_in[11];
  const float* g2   = (const float*)d_in[12];
  const float* be2  = (const float*)d_in[13];
  const float* rel1 = (const float*)d_in[14];
  const float* rel2 = (const float*)d_in[15];
  const float* rel4 = (const float*)d_in[16];
  const float* rel8 = (const float*)d_in[17];
  float* out = (float*)d_out;

  char* W = (char*)d_ws;
  ushort_t* qbb  = (ushort_t*)(W);                  // 23,068,672
  ushort_t* kbb  = (ushort_t*)(W + 23068672);       // 23,068,672
  ushort_t* vbb  = (ushort_t*)(W + 46137344);       // 23,068,672
  ushort_t* vbt  = (ushort_t*)(W + 69206016);       //  5,767,168
  ushort_t* ao   = (ushort_t*)(W + 74973184);       // 23,068,672
  const size_t F = 98041856;
  ushort_t* qw2  = (ushort_t*)(W + F);
  ushort_t* kw2  = (ushort_t*)(W + F + 5832704);
  ushort_t* vwt2 = (ushort_t*)(W + F + 11665408);
  ushort_t* qw4  = (ushort_t*)(W + F + 17432576);
  ushort_t* kw4  = (ushort_t*)(W + F + 23265280);
  ushort_t* vwt4 = (ushort_t*)(W + F + 29097984);
  ushort_t* qw8  = (ushort_t*)(W + F + 35389440);
  ushort_t* kw8  = (ushort_t*)(W + F + 41222144);
  ushort_t* vwt8 = (ushort_t*)(W + F + 47054848);
  ushort_t* Wqkvt= (ushort_t*)(W + F + 55443456);   //   393,216
  ushort_t* Woutt= (ushort_t*)(W + F + 55836672);   //   131,072
  ushort_t* W1t  = (ushort_t*)(W + F + 55967744);   // 1,048,576
  ushort_t* W2t  = (ushort_t*)(W + F + 57016320);   // 1,048,576
  float*    x1   = (float*)(W);                     // reuse qbb+kbb after attention
  ushort_t* x1b  = (ushort_t*)(W + 46137344);       // reuse vbb after relays

  k_cvtw<<<dim3(8, 24), 256, 0, stream>>>(Wqkv, Wqkvt, 256, 768);
  k_cvtw<<<dim3(8, 8),  256, 0, stream>>>(Wout, Woutt, 256, 256);
  k_cvtw<<<dim3(8, 64), 256, 0, stream>>>(W1, W1t, 256, 2048);
  k_cvtw<<<dim3(64, 8), 256, 0, stream>>>(W2, W2t, 2048, 256);
  k_qkv2<<<dim3(704, 3), 256, 0, stream>>>(X, Wqkvt, bqkv, qbb, kbb, vbb, vbt);
  k_relay<2><<<dim3(44, 64, 2), 256, 0, stream>>>(qbb, kbb, vbb, qw2, kw2, vwt2, 1, 5);
  k_relay<4><<<dim3(11, 64, 2), 256, 0, stream>>>(qbb, kbb, vbb, qw4, kw4, vwt4, 2, 6);
  k_relay<8><<<dim3(3, 64, 2),  256, 0, stream>>>(qbb, kbb, vbb, qw8, kw8, vwt8, 3, 7);
  k_attn1m<<<dim3(11, 64, 2), 256, 0, stream>>>(qbb, kbb, vbt, rel1, ao);
  k_attnm<2, 256><<<dim3(11, 64, 2), 256, 0, stream>>>(qw2, kw2, vwt2, rel2, ao, 1, 5);
  k_attnm<4, 256><<<dim3(3, 64, 2),  256, 0, stream>>>(qw4, kw4, vwt4, rel4, ao, 2, 6);
  k_attnm<8, 512><<<dim3(1, 64, 2),  512, 0, stream>>>(qw8, kw8, vwt8, rel8, ao, 3, 7);
  k_projln<<<dim3(704), 256, 0, stream>>>(ao, Woutt, bout, X, g1, be1, x1, x1b);
  k_ffn2<<<dim3(704), 256, 0, stream>>>(x1b, x1, W1t, b1, W2t, b2, g2, be2, out);
}

// Round 5
// 1014.247 us; speedup vs baseline: 9.5836x; 2.0455x over previous
//
#include <hip/hip_runtime.h>
#include <hip/hip_bf16.h>
#include <math.h>

#define L_ALL 704
#define NB 64
#define DM 256
#define HD 32
#define M_TOT (L_ALL*NB)
#define Q_SCALE 0.17677669529663687f

typedef __attribute__((ext_vector_type(8))) short bf16x8;
typedef __attribute__((ext_vector_type(4))) float f32x4;
typedef unsigned short ushort_t;

static __device__ __forceinline__ unsigned short f2b(float x) {
  __hip_bfloat16 h = __float2bfloat16(x);
  return *reinterpret_cast<unsigned short*>(&h);
}

__device__ __forceinline__ float wfun(int t, int ws) {
  float f = (float)t / (float)ws;
  return f > 0.5f ? f : 1.0f - f;
}

template<int WS>
__device__ __forceinline__ int tokf(int i, int a, int c, int shift) {
  constexpr int NW8 = 8 / WS;
  constexpr int N1 = NW8 * NW8;
  constexpr int NW24 = 24 / WS;
  if (i < 2 * N1) {
    int fr = i / N1, li2 = i % N1;
    int wi = li2 / NW8, wj = li2 % NW8;
    return fr * 64 + (wi * WS + a) * 8 + (wj * WS + c);
  }
  int ls = i - 2 * N1;
  int wi = ls / NW24, wj = ls % NW24;
  int r = (wi * WS + a + shift) % 24;
  int cc = (wj * WS + c + shift) % 24;
  return 128 + r * 24 + cc;
}

static __device__ __forceinline__ void gl16(const void* g, void* l) {
  __builtin_amdgcn_global_load_lds(
      (const __attribute__((address_space(1))) unsigned*)g,
      (__attribute__((address_space(3))) unsigned*)l, 16, 0, 0);
}

// ---------------------------------------------------------------- weight convert+transpose
__global__ __launch_bounds__(256) void k_cvtw(const float* __restrict__ src,
    ushort_t* __restrict__ dst, int R, int C) {
  __shared__ float tile[32][33];
  const int r0 = blockIdx.x * 32, c0 = blockIdx.y * 32;
  const int tr = threadIdx.x >> 5, tc = threadIdx.x & 31;
#pragma unroll
  for (int i = 0; i < 4; ++i)
    tile[tr + i * 8][tc] = src[(size_t)(r0 + tr + i * 8) * C + c0 + tc];
  __syncthreads();
#pragma unroll
  for (int i = 0; i < 4; ++i)
    dst[(size_t)(c0 + tr + i * 8) * R + r0 + tc] = f2b(tile[tc][tr + i * 8]);
}

// ---------------------------------------------------------------- FFN weight pack (swizzled LDS images)
// Wc: 32 chunks x 65536B. chunk ch: [0,32768) W1 image, [32768,65536) W2 image.
// W1 image: byte ((hr*512 + k*2) ^ ((hr&7)<<4)) = bf16(W1[k][ch*64+hr])
__global__ __launch_bounds__(256) void k_prepw1(const float* __restrict__ W1,
    char* __restrict__ Wc) {
  int t = blockIdx.x * 256 + threadIdx.x;         // 524288
  int k = t >> 11, n = t & 2047;
  int ch = n >> 6, hr = n & 63;
  unsigned off = (unsigned)((hr * 512 + k * 2) ^ ((hr & 7) << 4));
  *(ushort_t*)(Wc + (size_t)ch * 65536 + off) = f2b(W1[(size_t)k * 2048 + n]);
}
// W2 image: byte 32768 + ((n*128 + kk*2) ^ ((n&7)<<4)) = bf16(W2[ch*64+kk][n])
__global__ __launch_bounds__(256) void k_prepw2(const float* __restrict__ W2,
    char* __restrict__ Wc) {
  int t = blockIdx.x * 256 + threadIdx.x;         // 524288
  int k = t >> 8, n = t & 255;
  int ch = k >> 6, kk = k & 63;
  unsigned off = 32768u + (unsigned)((n * 128 + kk * 2) ^ ((n & 7) << 4));
  *(ushort_t*)(Wc + (size_t)ch * 65536 + off) = f2b(W2[(size_t)k * 256 + n]);
}

// ---------------------------------------------------------------- QKV GEMM (bf16 MFMA)
__global__ __launch_bounds__(256) void k_qkv2(const float* __restrict__ X,
    const ushort_t* __restrict__ Wt, const float* __restrict__ bias,
    ushort_t* __restrict__ qbb, ushort_t* __restrict__ kbb,
    ushort_t* __restrict__ vbb, ushort_t* __restrict__ vbt) {
  const int tid = threadIdx.x;
  const int w = tid >> 6, lane = tid & 63, li = lane & 15, g16 = lane >> 4;
  const int m0 = blockIdx.x * 64;
  const int sec = blockIdx.y;
  f32x4 acc[16];
#pragma unroll
  for (int t = 0; t < 16; ++t) acc[t] = (f32x4){0.f, 0.f, 0.f, 0.f};
  const float* arow = X + (size_t)(m0 + w * 16 + li) * 256;
  for (int k0 = 0; k0 < 256; k0 += 32) {
    float4 xa = *(const float4*)(arow + k0 + g16 * 8);
    float4 xb = *(const float4*)(arow + k0 + g16 * 8 + 4);
    bf16x8 a;
    a[0] = f2b(xa.x); a[1] = f2b(xa.y); a[2] = f2b(xa.z); a[3] = f2b(xa.w);
    a[4] = f2b(xb.x); a[5] = f2b(xb.y); a[6] = f2b(xb.z); a[7] = f2b(xb.w);
#pragma unroll
    for (int t = 0; t < 16; ++t) {
      const ushort_t* bp = Wt + (size_t)(sec * 256 + t * 16 + li) * 256 + k0 + g16 * 8;
      bf16x8 bf = *(const bf16x8*)bp;
      acc[t] = __builtin_amdgcn_mfma_f32_16x16x32_bf16(a, bf, acc[t], 0, 0, 0);
    }
  }
#pragma unroll
  for (int t = 0; t < 16; ++t) {
    int col = sec * 256 + t * 16 + li;
    float bv = bias[col];
    int c255 = col & 255;
    int hh = c255 >> 5, e = c255 & 31;
#pragma unroll
    for (int r = 0; r < 4; ++r) {
      int row = m0 + w * 16 + g16 * 4 + r;
      float v = acc[t][r] + bv;
      size_t di = (size_t)row * 256 + c255;
      if (sec == 0)      qbb[di] = f2b(v * Q_SCALE);
      else if (sec == 1) kbb[di] = f2b(v);
      else {
        vbb[di] = f2b(v);
        if ((hh & 3) == 0) {
          int slot = hh >> 2;
          int tok = row >> 6, b = row & 63;
          vbt[((size_t)(slot * 64 + b) * 32 + e) * 704 + tok] = f2b(v);
        }
      }
    }
  }
}

// ---------------------------------------------------------------- ws=1 attention (MFMA flash)
__global__ __launch_bounds__(256) void k_attn1m(const ushort_t* __restrict__ qbb,
    const ushort_t* __restrict__ kbb, const ushort_t* __restrict__ vbt,
    const float* __restrict__ rel, ushort_t* __restrict__ ao) {
  __shared__ ushort_t P_lds[4 * 512];
  const int tid = threadIdx.x;
  const int w = tid >> 6, lane = tid & 63, li = lane & 15, g16 = lane >> 4;
  const int b = blockIdx.y;
  const int h = blockIdx.z ? 4 : 0;
  const int slot = blockIdx.z;
  const int qrow0 = blockIdx.x * 64 + w * 16;
  char* myP = (char*)P_lds + w * 1024;

  const bf16x8 qfrag = *(const bf16x8*)(qbb +
      (size_t)((qrow0 + li) * 64 + b) * 256 + h * 32 + g16 * 8);
  f32x4 o0 = (f32x4){0.f, 0.f, 0.f, 0.f}, o1 = o0;
  float m_run[4] = {-1e30f, -1e30f, -1e30f, -1e30f};
  float l_run[4] = {0.f, 0.f, 0.f, 0.f};

  const size_t vrow0 = (size_t)(slot * 64 + b) * 32;

  for (int kt = 0; kt < 704; kt += 32) {
    f32x4 s0 = (f32x4){0.f, 0.f, 0.f, 0.f}, s1 = s0;
    bf16x8 kf0 = *(const bf16x8*)(kbb + (size_t)((kt + li) * 64 + b) * 256 + h * 32 + g16 * 8);
    bf16x8 kf1 = *(const bf16x8*)(kbb + (size_t)((kt + 16 + li) * 64 + b) * 256 + h * 32 + g16 * 8);
    s0 = __builtin_amdgcn_mfma_f32_16x16x32_bf16(qfrag, kf0, s0, 0, 0, 0);
    s1 = __builtin_amdgcn_mfma_f32_16x16x32_bf16(qfrag, kf1, s1, 0, 0, 0);
    const float* rb = rel + (size_t)(qrow0 + g16 * 4) * 704 + kt;
#pragma unroll
    for (int r = 0; r < 4; ++r) {
      s0[r] += rb[(size_t)r * 704 + li];
      s1[r] += rb[(size_t)r * 704 + 16 + li];
    }
#pragma unroll
    for (int r = 0; r < 4; ++r) {
      float pm = fmaxf(s0[r], s1[r]);
      for (int m = 1; m < 16; m <<= 1) pm = fmaxf(pm, __shfl_xor(pm, m));
      float mn = fmaxf(m_run[r], pm);
      float corr = __expf(m_run[r] - mn);
      float p0 = __expf(s0[r] - mn);
      float p1 = __expf(s1[r] - mn);
      float ps = p0 + p1;
      for (int m = 1; m < 16; m <<= 1) ps += __shfl_xor(ps, m);
      l_run[r] = l_run[r] * corr + ps;
      m_run[r] = mn;
      o0[r] *= corr; o1[r] *= corr;
      int row = g16 * 4 + r;
      unsigned sw = (unsigned)((row & 7) << 4);
      *(ushort_t*)(myP + (((unsigned)(row * 64 + li * 2)) ^ sw)) = f2b(p0);
      *(ushort_t*)(myP + (((unsigned)(row * 64 + 32 + li * 2)) ^ sw)) = f2b(p1);
    }
    bf16x8 pa = *(const bf16x8*)(myP + (((unsigned)(li * 64 + g16 * 16)) ^ ((unsigned)((li & 7) << 4))));
    bf16x8 v0 = *(const bf16x8*)(vbt + (vrow0 + li) * 704 + kt + g16 * 8);
    bf16x8 v1 = *(const bf16x8*)(vbt + (vrow0 + 16 + li) * 704 + kt + g16 * 8);
    o0 = __builtin_amdgcn_mfma_f32_16x16x32_bf16(pa, v0, o0, 0, 0, 0);
    o1 = __builtin_amdgcn_mfma_f32_16x16x32_bf16(pa, v1, o1, 0, 0, 0);
  }
#pragma unroll
  for (int r = 0; r < 4; ++r) {
    float inv = 1.0f / l_run[r];
    int token = qrow0 + g16 * 4 + r;
    size_t orow = (size_t)(token * 64 + b) * 256 + h * 32;
    ao[orow + li] = f2b(o0[r] * inv);
    ao[orow + 16 + li] = f2b(o1[r] * inv);
  }
}

// ---------------------------------------------------------------- window relayout
template<int WS>
__global__ __launch_bounds__(256) void k_relay(const ushort_t* __restrict__ qbb,
    const ushort_t* __restrict__ kbb, const ushort_t* __restrict__ vbb,
    ushort_t* __restrict__ qw, ushort_t* __restrict__ kw, ushort_t* __restrict__ vwt,
    int hA, int hB) {
  constexpr int G = WS * WS;
  constexpr int M = WS - 1;
  constexpr int LW = (WS == 2) ? 1 : (WS == 4) ? 2 : 3;
  constexpr int NWIN = 704 / G;
  constexpr int CD = G * 32;
  constexpr int LPAD16 = (NWIN + 15) & ~15;
  const int tid = threadIdx.x;
  const int b = blockIdx.y, z = blockIdx.z;
  const int h = z ? hB : hA;
  const int shift = z ? (WS / 2) : 0;
  const size_t sl = (size_t)(z * 64 + b);
  const size_t qkb = sl * NWIN * CD;
  const size_t vb = sl * CD * LPAD16;
  for (int idx2 = tid; idx2 < 4 * (CD / 2); idx2 += 256) {
    int l = blockIdx.x * 4 + idx2 / (CD / 2);
    if (l >= NWIN) break;
    int idx = (idx2 % (CD / 2)) * 2;
    int cell = idx >> 5, e = idx & 31;
    int a = cell >> LW, c = cell & M;
    int tokv = tokf<WS>(l, a, c, shift);
    size_t so = ((size_t)(tokv * 64 + b)) * 256 + h * 32 + e;
    *(unsigned*)(qw + qkb + (size_t)l * CD + idx) = *(const unsigned*)(qbb + so);
    unsigned kv = *(const unsigned*)(kbb + so);
    *(unsigned*)(kw + qkb + (size_t)l * CD + idx) = kv;
    unsigned vv = *(const unsigned*)(vbb + so);
    vwt[vb + (size_t)idx * LPAD16 + l] = (ushort_t)(vv & 0xffffu);
    vwt[vb + (size_t)(idx + 1) * LPAD16 + l] = (ushort_t)(vv >> 16);
  }
  if (LPAD16 > NWIN && blockIdx.x == 0) {
    for (int idx = tid; idx < CD * (LPAD16 - NWIN); idx += 256) {
      int x = idx / (LPAD16 - NWIN);
      int pl = NWIN + idx % (LPAD16 - NWIN);
      vwt[vb + (size_t)x * LPAD16 + pl] = 0;
    }
  }
}

// ---------------------------------------------------------------- ws>1 attention (MFMA group-GEMM)
template<int WS, int NT>
__global__ __launch_bounds__(NT) void k_attnm(const ushort_t* __restrict__ qw,
    const ushort_t* __restrict__ kw, const ushort_t* __restrict__ vwt,
    const float* __restrict__ rel, ushort_t* __restrict__ ao, int hA, int hB) {
  constexpr int G = WS * WS;
  constexpr int M = WS - 1;
  constexpr int LW = (WS == 2) ? 1 : (WS == 4) ? 2 : 3;
  constexpr int NWIN = 704 / G;
  constexpr int CD = G * 32;
  constexpr int LPAD16 = (NWIN + 15) & ~15;
  constexpr int NTL = LPAD16 / 16;
  constexpr int NW = NT / 64;
  constexpr int GPW = G / NW;
  constexpr int TPW_S = GPW * NTL;
  constexpr int XT = CD / 16;
  constexpr int TPW_O = XT / NW;
  constexpr int PSTEPS = (G * LPAD16) / 32;
  constexpr int PSTR = G * LPAD16 + 8;
  constexpr float invG = 1.0f / (float)G;

  __shared__ ushort_t P_lds[16 * PSTR];
  __shared__ float redm[NW][16], reds[NW][16];

  const int tid = threadIdx.x;
  const int w = tid >> 6, lane = tid & 63, li = lane & 15, g16 = lane >> 4;
  const int i0 = blockIdx.x * 16;
  const int b = blockIdx.y, z = blockIdx.z;
  const int h = z ? hB : hA;
  const int shift = z ? (WS / 2) : 0;
  const size_t sl = (size_t)(z * 64 + b);
  const ushort_t* qs = qw + sl * NWIN * CD;
  const ushort_t* ksl = kw + sl * NWIN * CD;
  const ushort_t* vs = vwt + sl * CD * LPAD16;
  const int laneAoff = ((g16 >> 1) << 4) + ((g16 & 1) << 3);

  // ---------------- S phase
  f32x4 sreg[TPW_S];
#pragma unroll
  for (int jg = 0; jg < GPW; ++jg) {
    const int g = w * GPW + jg;
    const int p1 = g >> LW, q1 = g & M;
    const float msk = (wfun(p1, WS) * wfun(q1, WS) - 1.0f) * invG;
    bf16x8 af[(WS <= 4) ? G : 1];
    if constexpr (WS <= 4) {
#pragma unroll
      for (int ksi = 0; ksi < G; ++ksi) {
        int a = ksi >> LW, c = ksi & M;
        int scell = (((a + p1) & M) << LW) | ((c + q1) & M);
        af[ksi] = *(const bf16x8*)(qs + (size_t)(i0 + li) * CD + scell * 32 + g16 * 8);
      }
    }
#pragma unroll
    for (int jn = 0; jn < NTL; ++jn) {
      f32x4 acc = (f32x4){0.f, 0.f, 0.f, 0.f};
      const ushort_t* kbase = ksl + (size_t)(jn * 16 + li) * CD + g16 * 8;
#pragma unroll
      for (int ksi = 0; ksi < G; ++ksi) {
        bf16x8 bfr = *(const bf16x8*)(kbase + ksi * 32);
        bf16x8 afr;
        if constexpr (WS <= 4) {
          afr = af[ksi];
        } else {
          int a = ksi >> LW, c = ksi & M;
          int scell = (((a + p1) & M) << LW) | ((c + q1) & M);
          afr = *(const bf16x8*)(qs + (size_t)(i0 + li) * CD + scell * 32 + g16 * 8);
        }
        acc = __builtin_amdgcn_mfma_f32_16x16x32_bf16(afr, bfr, acc, 0, 0, 0);
      }
#pragma unroll
      for (int r = 0; r < 4; ++r) {
        int iloc = g16 * 4 + r, ig = i0 + iloc, l = jn * 16 + li;
        float s;
        if (ig < NWIN && l < NWIN)
          s = acc[r] * invG + msk + rel[(size_t)ig * 704 + l * G + g];
        else
          s = -3e38f;
        acc[r] = s;
      }
      sreg[jg * NTL + jn] = acc;
    }
  }

  // ---------------- softmax
  float pm[4] = {-3e38f, -3e38f, -3e38f, -3e38f};
#pragma unroll
  for (int t = 0; t < TPW_S; ++t)
#pragma unroll
    for (int r = 0; r < 4; ++r) pm[r] = fmaxf(pm[r], sreg[t][r]);
#pragma unroll
  for (int mm = 1; mm < 16; mm <<= 1)
#pragma unroll
    for (int r = 0; r < 4; ++r) pm[r] = fmaxf(pm[r], __shfl_xor(pm[r], mm));
  if (li == 0) {
#pragma unroll
    for (int r = 0; r < 4; ++r) redm[w][g16 * 4 + r] = pm[r];
  }
  __syncthreads();
  float mrow[4];
#pragma unroll
  for (int r = 0; r < 4; ++r) {
    float v = redm[0][g16 * 4 + r];
    for (int ww = 1; ww < NW; ++ww) v = fmaxf(v, redm[ww][g16 * 4 + r]);
    mrow[r] = v;
  }
  float ps[4] = {0.f, 0.f, 0.f, 0.f};
#pragma unroll
  for (int t = 0; t < TPW_S; ++t)
#pragma unroll
    for (int r = 0; r < 4; ++r) {
      float p = __expf(sreg[t][r] - mrow[r]);
      sreg[t][r] = p;
      ps[r] += p;
    }
#pragma unroll
  for (int mm = 1; mm < 16; mm <<= 1)
#pragma unroll
    for (int r = 0; r < 4; ++r) ps[r] += __shfl_xor(ps[r], mm);
  if (li == 0) {
#pragma unroll
    for (int r = 0; r < 4; ++r) reds[w][g16 * 4 + r] = ps[r];
  }
  __syncthreads();
  float inv4[4];
#pragma unroll
  for (int r = 0; r < 4; ++r) {
    float v = reds[0][g16 * 4 + r];
    for (int ww = 1; ww < NW; ++ww) v += reds[ww][g16 * 4 + r];
    inv4[r] = 1.0f / v;
  }
#pragma unroll
  for (int t = 0; t < TPW_S; ++t) {
    const int g = w * GPW + t / NTL;
    const int col = g * LPAD16 + (t % NTL) * 16 + li;
#pragma unroll
    for (int r = 0; r < 4; ++r)
      P_lds[(size_t)(g16 * 4 + r) * PSTR + col] = f2b(sreg[t][r] * inv4[r]);
  }
  __syncthreads();

  // ---------------- PV phase + scatter out
#pragma unroll
  for (int j = 0; j < TPW_O; ++j) {
    const int ot = w * TPW_O + j;
    const int oc = ot >> 1, oh16 = (ot & 1) << 4;
    const int a_o = oc >> LW, c_o = oc & M;
    f32x4 acc = (f32x4){0.f, 0.f, 0.f, 0.f};
#pragma unroll
    for (int p = 0; p < PSTEPS; ++p) {
      const int kc0 = 2 * p;
      const int g0 = kc0 / NTL, lb0 = kc0 % NTL;
      const int g1 = (kc0 + 1) / NTL, lb1 = (kc0 + 1) % NTL;
      const int p10 = g0 >> LW, q10 = g0 & M;
      const int p11 = g1 >> LW, q11 = g1 & M;
      int sc0 = (((a_o - p10) & M) << LW) | ((c_o - q10) & M);
      int sc1 = (((a_o - p11) & M) << LW) | ((c_o - q11) & M);
      int scl = (g16 < 2) ? sc0 : sc1;
      int lbl = (g16 < 2) ? lb0 : lb1;
      bf16x8 A = *(const bf16x8*)(P_lds + (size_t)li * PSTR + kc0 * 16 + laneAoff);
      bf16x8 B = *(const bf16x8*)(vs + (size_t)(scl * 32 + oh16 + li) * LPAD16 + lbl * 16 + ((g16 & 1) << 3));
      acc = __builtin_amdgcn_mfma_f32_16x16x32_bf16(A, B, acc, 0, 0, 0);
    }
#pragma unroll
    for (int r = 0; r < 4; ++r) {
      int ig = i0 + g16 * 4 + r;
      if (ig < NWIN) {
        int x = ot * 16 + li;
        int cell = x >> 5, e = x & 31;
        int a = cell >> LW, c = cell & M;
        int tokv = tokf<WS>(ig, a, c, shift);
        ao[((size_t)(tokv * 64 + b)) * 256 + h * 32 + e] = f2b(acc[r]);
      }
    }
  }
}

// ---------------------------------------------------------------- out-proj + residual + LN1 (MFMA)
__global__ __launch_bounds__(256) void k_projln(const ushort_t* __restrict__ ao,
    const ushort_t* __restrict__ Wt, const float* __restrict__ bout,
    const float* __restrict__ X0, const float* __restrict__ g,
    const float* __restrict__ be, float* __restrict__ x1, ushort_t* __restrict__ x1b) {
  const int tid = threadIdx.x;
  const int w = tid >> 6, lane = tid & 63, li = lane & 15, g16 = lane >> 4;
  const int m0 = blockIdx.x * 64;
  f32x4 acc[16];
#pragma unroll
  for (int t = 0; t < 16; ++t) acc[t] = (f32x4){0.f, 0.f, 0.f, 0.f};
  const ushort_t* arow = ao + (size_t)(m0 + w * 16 + li) * 256;
  for (int k0 = 0; k0 < 256; k0 += 32) {
    bf16x8 a = *(const bf16x8*)(arow + k0 + g16 * 8);
#pragma unroll
    for (int t = 0; t < 16; ++t) {
      bf16x8 bf = *(const bf16x8*)(Wt + (size_t)(t * 16 + li) * 256 + k0 + g16 * 8);
      acc[t] = __builtin_amdgcn_mfma_f32_16x16x32_bf16(a, bf, acc[t], 0, 0, 0);
    }
  }
  float s[4] = {0.f, 0.f, 0.f, 0.f}, q[4] = {0.f, 0.f, 0.f, 0.f};
#pragma unroll
  for (int t = 0; t < 16; ++t) {
    int col = t * 16 + li;
    float bb = bout[col];
#pragma unroll
    for (int r = 0; r < 4; ++r) {
      int row = m0 + w * 16 + g16 * 4 + r;
      float v = acc[t][r] + bb + X0[(size_t)row * 256 + col];
      acc[t][r] = v;
      s[r] += v; q[r] += v * v;
    }
  }
#pragma unroll
  for (int r = 0; r < 4; ++r) {
    float ss = s[r], qq = q[r];
    for (int m = 1; m < 16; m <<= 1) { ss += __shfl_xor(ss, m); qq += __shfl_xor(qq, m); }
    float mu = ss * (1.0f / 256.0f);
    float var = qq * (1.0f / 256.0f) - mu * mu;
    s[r] = mu; q[r] = rsqrtf(var + 1e-5f);
  }
#pragma unroll
  for (int t = 0; t < 16; ++t) {
    int col = t * 16 + li;
    float gv = g[col], bv = be[col];
#pragma unroll
    for (int r = 0; r < 4; ++r) {
      int row = m0 + w * 16 + g16 * 4 + r;
      float o = (acc[t][r] - s[r]) * q[r] * gv + bv;
      x1[(size_t)row * 256 + col] = o;
      x1b[(size_t)row * 256 + col] = f2b(o);
    }
  }
}

// ---------------------------------------------------------------- fused FFN + LN2 (staged-LDS MFMA)
// 128 rows/block, 8 waves. Wc: 32 chunks of 64KB pre-swizzled weight images.
__global__ __launch_bounds__(512, 2) void k_ffn3(
    const ushort_t* __restrict__ x1b, const float* __restrict__ x1,
    const char* __restrict__ Wc, const float* __restrict__ b1,
    const float* __restrict__ b2, const float* __restrict__ g,
    const float* __restrict__ be, float* __restrict__ out) {
  __shared__ char wbuf[2][65536];
  __shared__ char Hl[16384];
  const int tid = threadIdx.x;
  const int w = tid >> 6, lane = tid & 63, li = lane & 15, g16 = lane >> 4;
  const int m0 = blockIdx.x * 128;

  // A fragments for GEMM1 (full K=256), held in registers
  bf16x8 afrag[8];
  const ushort_t* aptr = x1b + (size_t)(m0 + w * 16 + li) * 256 + g16 * 8;
#pragma unroll
  for (int kk = 0; kk < 8; ++kk) afrag[kk] = *(const bf16x8*)(aptr + kk * 32);

  f32x4 acc2[16];
#pragma unroll
  for (int i = 0; i < 16; ++i) acc2[i] = (f32x4){0.f, 0.f, 0.f, 0.f};

  // prologue: stage chunk 0
#pragma unroll
  for (int s = 0; s < 8; ++s) {
    int off = (tid + s * 512) * 16;
    gl16(Wc + off, &wbuf[0][0] + off);
  }
  __syncthreads();

  for (int ch = 0; ch < 32; ++ch) {
    const int cur = ch & 1;
    if (ch + 1 < 32) {
      const char* gsrc = Wc + (size_t)(ch + 1) * 65536;
#pragma unroll
      for (int s = 0; s < 8; ++s) {
        int off = (tid + s * 512) * 16;
        gl16(gsrc + off, &wbuf[cur ^ 1][0] + off);
      }
    }
    // ---- GEMM1: H[128][64] = relu(x1b @ W1chunk + b1)
    f32x4 hacc[4];
#pragma unroll
    for (int f = 0; f < 4; ++f) hacc[f] = (f32x4){0.f, 0.f, 0.f, 0.f};
#pragma unroll
    for (int kk = 0; kk < 8; ++kk) {
#pragma unroll
      for (int f = 0; f < 4; ++f) {
        int row = f * 16 + li;
        unsigned off = (unsigned)((row * 512 + kk * 64 + g16 * 16)) ^ (unsigned)((row & 7) << 4);
        bf16x8 bfr = *(const bf16x8*)(&wbuf[cur][0] + off);
        hacc[f] = __builtin_amdgcn_mfma_f32_16x16x32_bf16(afrag[kk], bfr, hacc[f], 0, 0, 0);
      }
    }
#pragma unroll
    for (int f = 0; f < 4; ++f) {
      int col = f * 16 + li;
      float bb = b1[ch * 64 + col];
#pragma unroll
      for (int r = 0; r < 4; ++r) {
        int row = w * 16 + g16 * 4 + r;
        unsigned off = (unsigned)((row * 128 + col * 2)) ^ (unsigned)((row & 7) << 4);
        *(ushort_t*)(Hl + off) = f2b(fmaxf(hacc[f][r] + bb, 0.f));
      }
    }
    __syncthreads();   // H visible
    // ---- GEMM2: acc2 += H @ W2chunk
#pragma unroll
    for (int ks = 0; ks < 2; ++ks) {
      int hrow = w * 16 + li;
      unsigned aoff = (unsigned)((hrow * 128 + ks * 64 + g16 * 16)) ^ (unsigned)((hrow & 7) << 4);
      bf16x8 a = *(const bf16x8*)(Hl + aoff);
#pragma unroll
      for (int t = 0; t < 16; ++t) {
        int n = t * 16 + li;
        unsigned boff = 32768u + ((unsigned)((n * 128 + ks * 64 + g16 * 16)) ^ (unsigned)((n & 7) << 4));
        bf16x8 bfr = *(const bf16x8*)(&wbuf[cur][0] + boff);
        acc2[t] = __builtin_amdgcn_mfma_f32_16x16x32_bf16(a, bfr, acc2[t], 0, 0, 0);
      }
    }
    __syncthreads();   // H consumed; next-chunk stage drained (vmcnt in barrier)
  }

  // ---- epilogue: +b2 +residual, LN2
  float s[4] = {0.f, 0.f, 0.f, 0.f}, q[4] = {0.f, 0.f, 0.f, 0.f};
#pragma unroll
  for (int t = 0; t < 16; ++t) {
    int col = t * 16 + li;
    float bb = b2[col];
#pragma unroll
    for (int r = 0; r < 4; ++r) {
      int row = m0 + w * 16 + g16 * 4 + r;
      float v = acc2[t][r] + bb + x1[(size_t)row * 256 + col];
      acc2[t][r] = v;
      s[r] += v; q[r] += v * v;
    }
  }
#pragma unroll
  for (int r = 0; r < 4; ++r) {
    float ss = s[r], qq = q[r];
    for (int m = 1; m < 16; m <<= 1) { ss += __shfl_xor(ss, m); qq += __shfl_xor(qq, m); }
    float mu = ss * (1.0f / 256.0f);
    float var = qq * (1.0f / 256.0f) - mu * mu;
    s[r] = mu; q[r] = rsqrtf(var + 1e-5f);
  }
#pragma unroll
  for (int t = 0; t < 16; ++t) {
    int col = t * 16 + li;
    float gv = g[col], bv = be[col];
#pragma unroll
    for (int r = 0; r < 4; ++r) {
      int row = m0 + w * 16 + g16 * 4 + r;
      out[(size_t)row * 256 + col] = (acc2[t][r] - s[r]) * q[r] * gv + bv;
    }
  }
}

// ---------------------------------------------------------------- launch
extern "C" void kernel_launch(void* const* d_in, const int* in_sizes, int n_in,
                              void* d_out, int out_size, void* d_ws, size_t ws_size,
                              hipStream_t stream) {
  const float* X    = (const float*)d_in[0];
  const float* Wqkv = (const float*)d_in[2];
  const float* bqkv = (const float*)d_in[3];
  const float* Wout = (const float*)d_in[4];
  const float* bout = (const float*)d_in[5];
  const float* W1   = (const float*)d_in[6];
  const float* b1   = (const float*)d_in[7];
  const float* W2   = (const float*)d_in[8];
  const float* b2   = (const float*)d_in[9];
  const float* g1   = (const float*)d_in[10];
  const float* be1  = (const float*)d_in[11];
  const float* g2   = (const float*)d_in[12];
  const float* be2  = (const float*)d_in[13];
  const float* rel1 = (const float*)d_in[14];
  const float* rel2 = (const float*)d_in[15];
  const float* rel4 = (const float*)d_in[16];
  const float* rel8 = (const float*)d_in[17];
  float* out = (float*)d_out;

  char* W = (char*)d_ws;
  ushort_t* qbb  = (ushort_t*)(W);                  // 23,068,672
  ushort_t* kbb  = (ushort_t*)(W + 23068672);       // 23,068,672
  ushort_t* vbb  = (ushort_t*)(W + 46137344);       // 23,068,672
  ushort_t* vbt  = (ushort_t*)(W + 69206016);       //  5,767,168
  ushort_t* ao   = (ushort_t*)(W + 74973184);       // 23,068,672
  const size_t F = 98041856;
  ushort_t* qw2  = (ushort_t*)(W + F);
  ushort_t* kw2  = (ushort_t*)(W + F + 5832704);
  ushort_t* vwt2 = (ushort_t*)(W + F + 11665408);
  ushort_t* qw4  = (ushort_t*)(W + F + 17432576);
  ushort_t* kw4  = (ushort_t*)(W + F + 23265280);
  ushort_t* vwt4 = (ushort_t*)(W + F + 29097984);
  ushort_t* qw8  = (ushort_t*)(W + F + 35389440);
  ushort_t* kw8  = (ushort_t*)(W + F + 41222144);
  ushort_t* vwt8 = (ushort_t*)(W + F + 47054848);
  ushort_t* Wqkvt= (ushort_t*)(W + F + 55443456);   //   393,216
  ushort_t* Woutt= (ushort_t*)(W + F + 55836672);   //   131,072
  char*     Wc   = (char*)    (W + F + 55967744);   // 2,097,152
  float*    x1   = (float*)(W);                     // reuse qbb+kbb after attention
  ushort_t* x1b  = (ushort_t*)(W + 46137344);       // reuse vbb after relays

  k_cvtw<<<dim3(8, 24), 256, 0, stream>>>(Wqkv, Wqkvt, 256, 768);
  k_cvtw<<<dim3(8, 8),  256, 0, stream>>>(Wout, Woutt, 256, 256);
  k_prepw1<<<dim3(2048), 256, 0, stream>>>(W1, Wc);
  k_prepw2<<<dim3(2048), 256, 0, stream>>>(W2, Wc);
  k_qkv2<<<dim3(704, 3), 256, 0, stream>>>(X, Wqkvt, bqkv, qbb, kbb, vbb, vbt);
  k_relay<2><<<dim3(44, 64, 2), 256, 0, stream>>>(qbb, kbb, vbb, qw2, kw2, vwt2, 1, 5);
  k_relay<4><<<dim3(11, 64, 2), 256, 0, stream>>>(qbb, kbb, vbb, qw4, kw4, vwt4, 2, 6);
  k_relay<8><<<dim3(3, 64, 2),  256, 0, stream>>>(qbb, kbb, vbb, qw8, kw8, vwt8, 3, 7);
  k_attn1m<<<dim3(11, 64, 2), 256, 0, stream>>>(qbb, kbb, vbt, rel1, ao);
  k_attnm<2, 256><<<dim3(11, 64, 2), 256, 0, stream>>>(qw2, kw2, vwt2, rel2, ao, 1, 5);
  k_attnm<4, 256><<<dim3(3, 64, 2),  256, 0, stream>>>(qw4, kw4, vwt4, rel4, ao, 2, 6);
  k_attnm<8, 512><<<dim3(1, 64, 2),  512, 0, stream>>>(qw8, kw8, vwt8, rel8, ao, 3, 7);
  k_projln<<<dim3(704), 256, 0, stream>>>(ao, Woutt, bout, X, g1, be1, x1, x1b);
  k_ffn3<<<dim3(352), 512, 0, stream>>>(x1b, x1, Wc, b1, b2, g2, be2, out);
}

// Round 6
// 912.507 us; speedup vs baseline: 10.6521x; 1.1115x over previous
//
#include <hip/hip_runtime.h>
#include <hip/hip_bf16.h>
#include <math.h>

#define L_ALL 704
#define NB 64
#define DM 256
#define HD 32
#define M_TOT (L_ALL*NB)
#define Q_SCALE 0.17677669529663687f

typedef __attribute__((ext_vector_type(8))) short bf16x8;
typedef __attribute__((ext_vector_type(4))) float f32x4;
typedef unsigned short ushort_t;

static __device__ __forceinline__ unsigned short f2b(float x) {
  __hip_bfloat16 h = __float2bfloat16(x);
  return *reinterpret_cast<unsigned short*>(&h);
}

__device__ __forceinline__ float wfun(int t, int ws) {
  float f = (float)t / (float)ws;
  return f > 0.5f ? f : 1.0f - f;
}

template<int WS>
__device__ __forceinline__ int tokf(int i, int a, int c, int shift) {
  constexpr int NW8 = 8 / WS;
  constexpr int N1 = NW8 * NW8;
  constexpr int NW24 = 24 / WS;
  if (i < 2 * N1) {
    int fr = i / N1, li2 = i % N1;
    int wi = li2 / NW8, wj = li2 % NW8;
    return fr * 64 + (wi * WS + a) * 8 + (wj * WS + c);
  }
  int ls = i - 2 * N1;
  int wi = ls / NW24, wj = ls % NW24;
  int r = (wi * WS + a + shift) % 24;
  int cc = (wj * WS + c + shift) % 24;
  return 128 + r * 24 + cc;
}

static __device__ __forceinline__ void gl16(const void* g, void* l) {
  __builtin_amdgcn_global_load_lds(
      (const __attribute__((address_space(1))) unsigned*)g,
      (__attribute__((address_space(3))) unsigned*)l, 16, 0, 0);
}

// ---------------------------------------------------------------- weight convert+transpose
__global__ __launch_bounds__(256) void k_cvtw(const float* __restrict__ src,
    ushort_t* __restrict__ dst, int R, int C) {
  __shared__ float tile[32][33];
  const int r0 = blockIdx.x * 32, c0 = blockIdx.y * 32;
  const int tr = threadIdx.x >> 5, tc = threadIdx.x & 31;
#pragma unroll
  for (int i = 0; i < 4; ++i)
    tile[tr + i * 8][tc] = src[(size_t)(r0 + tr + i * 8) * C + c0 + tc];
  __syncthreads();
#pragma unroll
  for (int i = 0; i < 4; ++i)
    dst[(size_t)(c0 + tr + i * 8) * R + r0 + tc] = f2b(tile[tc][tr + i * 8]);
}

// ---------------------------------------------------------------- FFN weight pack (swizzled LDS images)
__global__ __launch_bounds__(256) void k_prepw1(const float* __restrict__ W1,
    char* __restrict__ Wc) {
  int t = blockIdx.x * 256 + threadIdx.x;
  int k = t >> 11, n = t & 2047;
  int ch = n >> 6, hr = n & 63;
  unsigned off = (unsigned)((hr * 512 + k * 2) ^ ((hr & 7) << 4));
  *(ushort_t*)(Wc + (size_t)ch * 65536 + off) = f2b(W1[(size_t)k * 2048 + n]);
}
__global__ __launch_bounds__(256) void k_prepw2(const float* __restrict__ W2,
    char* __restrict__ Wc) {
  int t = blockIdx.x * 256 + threadIdx.x;
  int k = t >> 8, n = t & 255;
  int ch = k >> 6, kk = k & 63;
  unsigned off = 32768u + (unsigned)((n * 128 + kk * 2) ^ ((n & 7) << 4));
  *(ushort_t*)(Wc + (size_t)ch * 65536 + off) = f2b(W2[(size_t)k * 256 + n]);
}

// ---------------------------------------------------------------- QKV GEMM (bf16 MFMA)
__global__ __launch_bounds__(256) void k_qkv2(const float* __restrict__ X,
    const ushort_t* __restrict__ Wt, const float* __restrict__ bias,
    ushort_t* __restrict__ qbb, ushort_t* __restrict__ kbb,
    ushort_t* __restrict__ vbb, ushort_t* __restrict__ vbt) {
  const int tid = threadIdx.x;
  const int w = tid >> 6, lane = tid & 63, li = lane & 15, g16 = lane >> 4;
  const int m0 = blockIdx.x * 64;
  const int sec = blockIdx.y;
  f32x4 acc[16];
#pragma unroll
  for (int t = 0; t < 16; ++t) acc[t] = (f32x4){0.f, 0.f, 0.f, 0.f};
  const float* arow = X + (size_t)(m0 + w * 16 + li) * 256;
  for (int k0 = 0; k0 < 256; k0 += 32) {
    float4 xa = *(const float4*)(arow + k0 + g16 * 8);
    float4 xb = *(const float4*)(arow + k0 + g16 * 8 + 4);
    bf16x8 a;
    a[0] = f2b(xa.x); a[1] = f2b(xa.y); a[2] = f2b(xa.z); a[3] = f2b(xa.w);
    a[4] = f2b(xb.x); a[5] = f2b(xb.y); a[6] = f2b(xb.z); a[7] = f2b(xb.w);
#pragma unroll
    for (int t = 0; t < 16; ++t) {
      const ushort_t* bp = Wt + (size_t)(sec * 256 + t * 16 + li) * 256 + k0 + g16 * 8;
      bf16x8 bf = *(const bf16x8*)bp;
      acc[t] = __builtin_amdgcn_mfma_f32_16x16x32_bf16(a, bf, acc[t], 0, 0, 0);
    }
  }
#pragma unroll
  for (int t = 0; t < 16; ++t) {
    int col = sec * 256 + t * 16 + li;
    float bv = bias[col];
    int c255 = col & 255;
    int hh = c255 >> 5, e = c255 & 31;
#pragma unroll
    for (int r = 0; r < 4; ++r) {
      int row = m0 + w * 16 + g16 * 4 + r;
      float v = acc[t][r] + bv;
      size_t di = (size_t)row * 256 + c255;
      if (sec == 0)      qbb[di] = f2b(v * Q_SCALE);
      else if (sec == 1) kbb[di] = f2b(v);
      else {
        vbb[di] = f2b(v);
        if ((hh & 3) == 0) {
          int slot = hh >> 2;
          int tok = row >> 6, b = row & 63;
          vbt[((size_t)(slot * 64 + b) * 32 + e) * 704 + tok] = f2b(v);
        }
      }
    }
  }
}

// ---------------------------------------------------------------- ws=1 attention (MFMA flash)
__global__ __launch_bounds__(256) void k_attn1m(const ushort_t* __restrict__ qbb,
    const ushort_t* __restrict__ kbb, const ushort_t* __restrict__ vbt,
    const float* __restrict__ rel, ushort_t* __restrict__ ao) {
  __shared__ ushort_t P_lds[4 * 512];
  const int tid = threadIdx.x;
  const int w = tid >> 6, lane = tid & 63, li = lane & 15, g16 = lane >> 4;
  const int b = blockIdx.y;
  const int h = blockIdx.z ? 4 : 0;
  const int slot = blockIdx.z;
  const int qrow0 = blockIdx.x * 64 + w * 16;
  char* myP = (char*)P_lds + w * 1024;

  const bf16x8 qfrag = *(const bf16x8*)(qbb +
      (size_t)((qrow0 + li) * 64 + b) * 256 + h * 32 + g16 * 8);
  f32x4 o0 = (f32x4){0.f, 0.f, 0.f, 0.f}, o1 = o0;
  float m_run[4] = {-1e30f, -1e30f, -1e30f, -1e30f};
  float l_run[4] = {0.f, 0.f, 0.f, 0.f};

  const size_t vrow0 = (size_t)(slot * 64 + b) * 32;

  for (int kt = 0; kt < 704; kt += 32) {
    f32x4 s0 = (f32x4){0.f, 0.f, 0.f, 0.f}, s1 = s0;
    bf16x8 kf0 = *(const bf16x8*)(kbb + (size_t)((kt + li) * 64 + b) * 256 + h * 32 + g16 * 8);
    bf16x8 kf1 = *(const bf16x8*)(kbb + (size_t)((kt + 16 + li) * 64 + b) * 256 + h * 32 + g16 * 8);
    s0 = __builtin_amdgcn_mfma_f32_16x16x32_bf16(qfrag, kf0, s0, 0, 0, 0);
    s1 = __builtin_amdgcn_mfma_f32_16x16x32_bf16(qfrag, kf1, s1, 0, 0, 0);
    const float* rb = rel + (size_t)(qrow0 + g16 * 4) * 704 + kt;
#pragma unroll
    for (int r = 0; r < 4; ++r) {
      s0[r] += rb[(size_t)r * 704 + li];
      s1[r] += rb[(size_t)r * 704 + 16 + li];
    }
#pragma unroll
    for (int r = 0; r < 4; ++r) {
      float pm = fmaxf(s0[r], s1[r]);
      for (int m = 1; m < 16; m <<= 1) pm = fmaxf(pm, __shfl_xor(pm, m));
      float mn = fmaxf(m_run[r], pm);
      float corr = __expf(m_run[r] - mn);
      float p0 = __expf(s0[r] - mn);
      float p1 = __expf(s1[r] - mn);
      float ps = p0 + p1;
      for (int m = 1; m < 16; m <<= 1) ps += __shfl_xor(ps, m);
      l_run[r] = l_run[r] * corr + ps;
      m_run[r] = mn;
      o0[r] *= corr; o1[r] *= corr;
      int row = g16 * 4 + r;
      unsigned sw = (unsigned)((row & 7) << 4);
      *(ushort_t*)(myP + (((unsigned)(row * 64 + li * 2)) ^ sw)) = f2b(p0);
      *(ushort_t*)(myP + (((unsigned)(row * 64 + 32 + li * 2)) ^ sw)) = f2b(p1);
    }
    bf16x8 pa = *(const bf16x8*)(myP + (((unsigned)(li * 64 + g16 * 16)) ^ ((unsigned)((li & 7) << 4))));
    bf16x8 v0 = *(const bf16x8*)(vbt + (vrow0 + li) * 704 + kt + g16 * 8);
    bf16x8 v1 = *(const bf16x8*)(vbt + (vrow0 + 16 + li) * 704 + kt + g16 * 8);
    o0 = __builtin_amdgcn_mfma_f32_16x16x32_bf16(pa, v0, o0, 0, 0, 0);
    o1 = __builtin_amdgcn_mfma_f32_16x16x32_bf16(pa, v1, o1, 0, 0, 0);
  }
#pragma unroll
  for (int r = 0; r < 4; ++r) {
    float inv = 1.0f / l_run[r];
    int token = qrow0 + g16 * 4 + r;
    size_t orow = (size_t)(token * 64 + b) * 256 + h * 32;
    ao[orow + li] = f2b(o0[r] * inv);
    ao[orow + 16 + li] = f2b(o1[r] * inv);
  }
}

// ---------------------------------------------------------------- window relayout
template<int WS>
__global__ __launch_bounds__(256) void k_relay(const ushort_t* __restrict__ qbb,
    const ushort_t* __restrict__ kbb, const ushort_t* __restrict__ vbb,
    ushort_t* __restrict__ qw, ushort_t* __restrict__ kw, ushort_t* __restrict__ vwt,
    int hA, int hB) {
  constexpr int G = WS * WS;
  constexpr int M = WS - 1;
  constexpr int LW = (WS == 2) ? 1 : (WS == 4) ? 2 : 3;
  constexpr int NWIN = 704 / G;
  constexpr int CD = G * 32;
  constexpr int LPAD16 = (NWIN + 15) & ~15;
  const int tid = threadIdx.x;
  const int b = blockIdx.y, z = blockIdx.z;
  const int h = z ? hB : hA;
  const int shift = z ? (WS / 2) : 0;
  const size_t sl = (size_t)(z * 64 + b);
  const size_t qkb = sl * NWIN * CD;
  const size_t vb = sl * CD * LPAD16;
  for (int idx2 = tid; idx2 < 4 * (CD / 2); idx2 += 256) {
    int l = blockIdx.x * 4 + idx2 / (CD / 2);
    if (l >= NWIN) break;
    int idx = (idx2 % (CD / 2)) * 2;
    int cell = idx >> 5, e = idx & 31;
    int a = cell >> LW, c = cell & M;
    int tokv = tokf<WS>(l, a, c, shift);
    size_t so = ((size_t)(tokv * 64 + b)) * 256 + h * 32 + e;
    *(unsigned*)(qw + qkb + (size_t)l * CD + idx) = *(const unsigned*)(qbb + so);
    unsigned kv = *(const unsigned*)(kbb + so);
    *(unsigned*)(kw + qkb + (size_t)l * CD + idx) = kv;
    unsigned vv = *(const unsigned*)(vbb + so);
    vwt[vb + (size_t)idx * LPAD16 + l] = (ushort_t)(vv & 0xffffu);
    vwt[vb + (size_t)(idx + 1) * LPAD16 + l] = (ushort_t)(vv >> 16);
  }
  if (LPAD16 > NWIN && blockIdx.x == 0) {
    for (int idx = tid; idx < CD * (LPAD16 - NWIN); idx += 256) {
      int x = idx / (LPAD16 - NWIN);
      int pl = NWIN + idx % (LPAD16 - NWIN);
      vwt[vb + (size_t)x * LPAD16 + pl] = 0;
    }
  }
}

// ---------------------------------------------------------------- ws>1 attention (LDS-staged MFMA group-GEMM)
template<int WS, int NT>
__global__ __launch_bounds__(NT) void k_attnm(const ushort_t* __restrict__ qw,
    const ushort_t* __restrict__ kw, const ushort_t* __restrict__ vwt,
    const float* __restrict__ rel, ushort_t* __restrict__ ao, int hA, int hB) {
  constexpr int G = WS * WS;
  constexpr int M = WS - 1;
  constexpr int LW = (WS == 2) ? 1 : (WS == 4) ? 2 : 3;
  constexpr int NWIN = 704 / G;
  constexpr int CD = G * 32;
  constexpr int LPAD16 = (NWIN + 15) & ~15;
  constexpr int NTL = LPAD16 / 16;
  constexpr int NW = NT / 64;
  constexpr int GPW = G / NW;
  constexpr int TPW_S = GPW * NTL;
  constexpr int XT = CD / 16;
  constexpr int TPW_O = XT / NW;
  constexpr int PSTEPS = (G * LPAD16) / 32;
  constexpr int PSTR = G * LPAD16 + 8;
  constexpr float invG = 1.0f / (float)G;
  constexpr bool KQV_FULL = (WS <= 4);
  constexpr int CDP = CD + 8;              // padded row stride (shorts)
  constexpr int LP  = LPAD16 + 8;          // padded V row stride (shorts)
  constexpr int KROWS = NTL * 16;          // ws2:176 ws4:48

  // LDS layout (bytes)
  constexpr int QS_B = 16 * CDP * 2;
  constexpr int KS_B = KQV_FULL ? (KROWS * CDP * 2) : 0;
  constexpr int VS_B = CD * LP * 2;
  constexpr int OFF_K = 0;
  constexpr int OFF_Q = KQV_FULL ? KS_B : 0;
  constexpr int OFF_V = KQV_FULL ? (KS_B + QS_B) : 0;  // ws8: V overlays Q after S
  constexpr int OFF_P = KQV_FULL ? (KS_B + QS_B + VS_B)
                                 : ((QS_B > VS_B) ? QS_B : VS_B);
  constexpr int TOT_B = OFF_P + 16 * PSTR * 2;
  __shared__ __align__(16) char smem[TOT_B];
  __shared__ float redm[NW][16], reds[NW][16];

  const int tid = threadIdx.x;
  const int w = tid >> 6, lane = tid & 63, li = lane & 15, g16 = lane >> 4;
  const int i0 = blockIdx.x * 16;
  const int b = blockIdx.y, z = blockIdx.z;
  const int h = z ? hB : hA;
  const int shift = z ? (WS / 2) : 0;
  const size_t sl = (size_t)(z * 64 + b);
  const ushort_t* qs_g = qw + sl * NWIN * CD;
  const ushort_t* ks_g = kw + sl * NWIN * CD;
  const ushort_t* vs_g = vwt + sl * CD * LPAD16;
  ushort_t* Ks = (ushort_t*)(smem + OFF_K);
  ushort_t* Qs = (ushort_t*)(smem + OFF_Q);
  ushort_t* Vs = (ushort_t*)(smem + OFF_V);
  ushort_t* Pl = (ushort_t*)(smem + OFF_P);
  const int laneAoff = ((g16 >> 1) << 4) + ((g16 & 1) << 3);

  // ---------------- stage Q tile (+ K, V for ws<=4)
  {
    const ushort_t* src = qs_g + (size_t)i0 * CD;
    for (int v = tid; v < 16 * CD / 8; v += NT) {
      int row = (v * 8) / CD, col = (v * 8) % CD;
      uint4 d = *(const uint4*)(src + (size_t)v * 8);
      *(uint4*)(Qs + row * CDP + col) = d;
    }
  }
  if constexpr (KQV_FULL) {
    for (int v = tid; v < NWIN * CD / 8; v += NT) {
      int row = (v * 8) / CD, col = (v * 8) % CD;
      uint4 d = *(const uint4*)(ks_g + (size_t)v * 8);
      *(uint4*)(Ks + row * CDP + col) = d;
    }
    for (int v = tid; v < CD * LPAD16 / 8; v += NT) {
      int row = (v * 8) / LPAD16, col = (v * 8) % LPAD16;
      uint4 d = *(const uint4*)(vs_g + (size_t)v * 8);
      *(uint4*)(Vs + row * LP + col) = d;
    }
  }
  __syncthreads();

  // ---------------- S phase
  f32x4 sreg[TPW_S];
#pragma unroll
  for (int jg = 0; jg < GPW; ++jg) {
    const int g = w * GPW + jg;
    const int p1 = g >> LW, q1 = g & M;
    const float msk = (wfun(p1, WS) * wfun(q1, WS) - 1.0f) * invG;
#pragma unroll
    for (int jn = 0; jn < NTL; ++jn) {
      f32x4 acc = (f32x4){0.f, 0.f, 0.f, 0.f};
#pragma unroll
      for (int ksi = 0; ksi < G; ++ksi) {
        int a = ksi >> LW, c = ksi & M;
        int scell = (((a + p1) & M) << LW) | ((c + q1) & M);
        bf16x8 afr = *(const bf16x8*)(Qs + li * CDP + scell * 32 + g16 * 8);
        bf16x8 bfr;
        if constexpr (KQV_FULL)
          bfr = *(const bf16x8*)(Ks + (jn * 16 + li) * CDP + ksi * 32 + g16 * 8);
        else
          bfr = *(const bf16x8*)(ks_g + (size_t)(jn * 16 + li) * CD + ksi * 32 + g16 * 8);
        acc = __builtin_amdgcn_mfma_f32_16x16x32_bf16(afr, bfr, acc, 0, 0, 0);
      }
#pragma unroll
      for (int r = 0; r < 4; ++r) {
        int iloc = g16 * 4 + r, ig = i0 + iloc, l = jn * 16 + li;
        float s;
        if (ig < NWIN && l < NWIN)
          s = acc[r] * invG + msk + rel[(size_t)ig * 704 + l * G + g];
        else
          s = -3e38f;
        acc[r] = s;
      }
      sreg[jg * NTL + jn] = acc;
    }
  }

  // ---------------- softmax
  float pm[4] = {-3e38f, -3e38f, -3e38f, -3e38f};
#pragma unroll
  for (int t = 0; t < TPW_S; ++t)
#pragma unroll
    for (int r = 0; r < 4; ++r) pm[r] = fmaxf(pm[r], sreg[t][r]);
#pragma unroll
  for (int mm = 1; mm < 16; mm <<= 1)
#pragma unroll
    for (int r = 0; r < 4; ++r) pm[r] = fmaxf(pm[r], __shfl_xor(pm[r], mm));
  if (li == 0) {
#pragma unroll
    for (int r = 0; r < 4; ++r) redm[w][g16 * 4 + r] = pm[r];
  }
  __syncthreads();
  float mrow[4];
#pragma unroll
  for (int r = 0; r < 4; ++r) {
    float v = redm[0][g16 * 4 + r];
    for (int ww = 1; ww < NW; ++ww) v = fmaxf(v, redm[ww][g16 * 4 + r]);
    mrow[r] = v;
  }
  float ps[4] = {0.f, 0.f, 0.f, 0.f};
#pragma unroll
  for (int t = 0; t < TPW_S; ++t)
#pragma unroll
    for (int r = 0; r < 4; ++r) {
      float p = __expf(sreg[t][r] - mrow[r]);
      sreg[t][r] = p;
      ps[r] += p;
    }
#pragma unroll
  for (int mm = 1; mm < 16; mm <<= 1)
#pragma unroll
    for (int r = 0; r < 4; ++r) ps[r] += __shfl_xor(ps[r], mm);
  if (li == 0) {
#pragma unroll
    for (int r = 0; r < 4; ++r) reds[w][g16 * 4 + r] = ps[r];
  }
  __syncthreads();
  float inv4[4];
#pragma unroll
  for (int r = 0; r < 4; ++r) {
    float v = reds[0][g16 * 4 + r];
    for (int ww = 1; ww < NW; ++ww) v += reds[ww][g16 * 4 + r];
    inv4[r] = 1.0f / v;
  }
#pragma unroll
  for (int t = 0; t < TPW_S; ++t) {
    const int g = w * GPW + t / NTL;
    const int col = g * LPAD16 + (t % NTL) * 16 + li;
#pragma unroll
    for (int r = 0; r < 4; ++r)
      Pl[(size_t)(g16 * 4 + r) * PSTR + col] = f2b(sreg[t][r] * inv4[r]);
  }
  __syncthreads();   // P visible; all Q reads complete

  if constexpr (!KQV_FULL) {
    // stage V into the (dead) Q region
    for (int v = tid; v < CD * LPAD16 / 8; v += NT) {
      int row = (v * 8) / LPAD16, col = (v * 8) % LPAD16;
      uint4 d = *(const uint4*)(vs_g + (size_t)v * 8);
      *(uint4*)(Vs + row * LP + col) = d;
    }
    __syncthreads();
  }

  // ---------------- PV phase (k-outer, A reused across col-tiles) + scatter
  f32x4 oacc[TPW_O];
#pragma unroll
  for (int j = 0; j < TPW_O; ++j) oacc[j] = (f32x4){0.f, 0.f, 0.f, 0.f};
  for (int p = 0; p < PSTEPS; ++p) {
    const int kc0 = 2 * p;
    const int g0 = kc0 / NTL, lb0 = kc0 % NTL;
    const int g1 = (kc0 + 1) / NTL, lb1 = (kc0 + 1) % NTL;
    const int p10 = g0 >> LW, q10 = g0 & M;
    const int p11 = g1 >> LW, q11 = g1 & M;
    bf16x8 A = *(const bf16x8*)(Pl + (size_t)li * PSTR + kc0 * 16 + laneAoff);
#pragma unroll
    for (int j = 0; j < TPW_O; ++j) {
      const int ot = w * TPW_O + j;
      const int oc = ot >> 1, oh16 = (ot & 1) << 4;
      const int a_o = oc >> LW, c_o = oc & M;
      int sc0 = (((a_o - p10) & M) << LW) | ((c_o - q10) & M);
      int sc1 = (((a_o - p11) & M) << LW) | ((c_o - q11) & M);
      int scl = (g16 < 2) ? sc0 : sc1;
      int lbl = (g16 < 2) ? lb0 : lb1;
      bf16x8 B = *(const bf16x8*)(Vs + (size_t)(scl * 32 + oh16 + li) * LP + lbl * 16 + ((g16 & 1) << 3));
      oacc[j] = __builtin_amdgcn_mfma_f32_16x16x32_bf16(A, B, oacc[j], 0, 0, 0);
    }
  }
#pragma unroll
  for (int j = 0; j < TPW_O; ++j) {
    const int ot = w * TPW_O + j;
#pragma unroll
    for (int r = 0; r < 4; ++r) {
      int ig = i0 + g16 * 4 + r;
      if (ig < NWIN) {
        int x = ot * 16 + li;
        int cell = x >> 5, e = x & 31;
        int a = cell >> LW, c = cell & M;
        int tokv = tokf<WS>(ig, a, c, shift);
        ao[((size_t)(tokv * 64 + b)) * 256 + h * 32 + e] = f2b(oacc[j][r]);
      }
    }
  }
}

// ---------------------------------------------------------------- out-proj + residual + LN1 (MFMA)
__global__ __launch_bounds__(256) void k_projln(const ushort_t* __restrict__ ao,
    const ushort_t* __restrict__ Wt, const float* __restrict__ bout,
    const float* __restrict__ X0, const float* __restrict__ g,
    const float* __restrict__ be, float* __restrict__ x1, ushort_t* __restrict__ x1b) {
  const int tid = threadIdx.x;
  const int w = tid >> 6, lane = tid & 63, li = lane & 15, g16 = lane >> 4;
  const int m0 = blockIdx.x * 64;
  f32x4 acc[16];
#pragma unroll
  for (int t = 0; t < 16; ++t) acc[t] = (f32x4){0.f, 0.f, 0.f, 0.f};
  const ushort_t* arow = ao + (size_t)(m0 + w * 16 + li) * 256;
  for (int k0 = 0; k0 < 256; k0 += 32) {
    bf16x8 a = *(const bf16x8*)(arow + k0 + g16 * 8);
#pragma unroll
    for (int t = 0; t < 16; ++t) {
      bf16x8 bf = *(const bf16x8*)(Wt + (size_t)(t * 16 + li) * 256 + k0 + g16 * 8);
      acc[t] = __builtin_amdgcn_mfma_f32_16x16x32_bf16(a, bf, acc[t], 0, 0, 0);
    }
  }
  float s[4] = {0.f, 0.f, 0.f, 0.f}, q[4] = {0.f, 0.f, 0.f, 0.f};
#pragma unroll
  for (int t = 0; t < 16; ++t) {
    int col = t * 16 + li;
    float bb = bout[col];
#pragma unroll
    for (int r = 0; r < 4; ++r) {
      int row = m0 + w * 16 + g16 * 4 + r;
      float v = acc[t][r] + bb + X0[(size_t)row * 256 + col];
      acc[t][r] = v;
      s[r] += v; q[r] += v * v;
    }
  }
#pragma unroll
  for (int r = 0; r < 4; ++r) {
    float ss = s[r], qq = q[r];
    for (int m = 1; m < 16; m <<= 1) { ss += __shfl_xor(ss, m); qq += __shfl_xor(qq, m); }
    float mu = ss * (1.0f / 256.0f);
    float var = qq * (1.0f / 256.0f) - mu * mu;
    s[r] = mu; q[r] = rsqrtf(var + 1e-5f);
  }
#pragma unroll
  for (int t = 0; t < 16; ++t) {
    int col = t * 16 + li;
    float gv = g[col], bv = be[col];
#pragma unroll
    for (int r = 0; r < 4; ++r) {
      int row = m0 + w * 16 + g16 * 4 + r;
      float o = (acc[t][r] - s[r]) * q[r] * gv + bv;
      x1[(size_t)row * 256 + col] = o;
      x1b[(size_t)row * 256 + col] = f2b(o);
    }
  }
}

// ---------------------------------------------------------------- fused FFN + LN2 (staged-LDS MFMA)
__global__ __launch_bounds__(512, 2) void k_ffn3(
    const ushort_t* __restrict__ x1b, const float* __restrict__ x1,
    const char* __restrict__ Wc, const float* __restrict__ b1,
    const float* __restrict__ b2, const float* __restrict__ g,
    const float* __restrict__ be, float* __restrict__ out) {
  __shared__ char wbuf[2][65536];
  __shared__ char Hl[16384];
  const int tid = threadIdx.x;
  const int w = tid >> 6, lane = tid & 63, li = lane & 15, g16 = lane >> 4;
  const int m0 = blockIdx.x * 128;

  bf16x8 afrag[8];
  const ushort_t* aptr = x1b + (size_t)(m0 + w * 16 + li) * 256 + g16 * 8;
#pragma unroll
  for (int kk = 0; kk < 8; ++kk) afrag[kk] = *(const bf16x8*)(aptr + kk * 32);

  f32x4 acc2[16];
#pragma unroll
  for (int i = 0; i < 16; ++i) acc2[i] = (f32x4){0.f, 0.f, 0.f, 0.f};

#pragma unroll
  for (int s = 0; s < 8; ++s) {
    int off = (tid + s * 512) * 16;
    gl16(Wc + off, &wbuf[0][0] + off);
  }
  __syncthreads();

  for (int ch = 0; ch < 32; ++ch) {
    const int cur = ch & 1;
    if (ch + 1 < 32) {
      const char* gsrc = Wc + (size_t)(ch + 1) * 65536;
#pragma unroll
      for (int s = 0; s < 8; ++s) {
        int off = (tid + s * 512) * 16;
        gl16(gsrc + off, &wbuf[cur ^ 1][0] + off);
      }
    }
    f32x4 hacc[4];
#pragma unroll
    for (int f = 0; f < 4; ++f) hacc[f] = (f32x4){0.f, 0.f, 0.f, 0.f};
#pragma unroll
    for (int kk = 0; kk < 8; ++kk) {
#pragma unroll
      for (int f = 0; f < 4; ++f) {
        int row = f * 16 + li;
        unsigned off = (unsigned)((row * 512 + kk * 64 + g16 * 16)) ^ (unsigned)((row & 7) << 4);
        bf16x8 bfr = *(const bf16x8*)(&wbuf[cur][0] + off);
        hacc[f] = __builtin_amdgcn_mfma_f32_16x16x32_bf16(afrag[kk], bfr, hacc[f], 0, 0, 0);
      }
    }
#pragma unroll
    for (int f = 0; f < 4; ++f) {
      int col = f * 16 + li;
      float bb = b1[ch * 64 + col];
#pragma unroll
      for (int r = 0; r < 4; ++r) {
        int row = w * 16 + g16 * 4 + r;
        unsigned off = (unsigned)((row * 128 + col * 2)) ^ (unsigned)((row & 7) << 4);
        *(ushort_t*)(Hl + off) = f2b(fmaxf(hacc[f][r] + bb, 0.f));
      }
    }
    __syncthreads();
#pragma unroll
    for (int ks = 0; ks < 2; ++ks) {
      int hrow = w * 16 + li;
      unsigned aoff = (unsigned)((hrow * 128 + ks * 64 + g16 * 16)) ^ (unsigned)((hrow & 7) << 4);
      bf16x8 a = *(const bf16x8*)(Hl + aoff);
#pragma unroll
      for (int t = 0; t < 16; ++t) {
        int n = t * 16 + li;
        unsigned boff = 32768u + ((unsigned)((n * 128 + ks * 64 + g16 * 16)) ^ (unsigned)((n & 7) << 4));
        bf16x8 bfr = *(const bf16x8*)(&wbuf[cur][0] + boff);
        acc2[t] = __builtin_amdgcn_mfma_f32_16x16x32_bf16(a, bfr, acc2[t], 0, 0, 0);
      }
    }
    __syncthreads();
  }

  float s[4] = {0.f, 0.f, 0.f, 0.f}, q[4] = {0.f, 0.f, 0.f, 0.f};
#pragma unroll
  for (int t = 0; t < 16; ++t) {
    int col = t * 16 + li;
    float bb = b2[col];
#pragma unroll
    for (int r = 0; r < 4; ++r) {
      int row = m0 + w * 16 + g16 * 4 + r;
      float v = acc2[t][r] + bb + x1[(size_t)row * 256 + col];
      acc2[t][r] = v;
      s[r] += v; q[r] += v * v;
    }
  }
#pragma unroll
  for (int r = 0; r < 4; ++r) {
    float ss = s[r], qq = q[r];
    for (int m = 1; m < 16; m <<= 1) { ss += __shfl_xor(ss, m); qq += __shfl_xor(qq, m); }
    float mu = ss * (1.0f / 256.0f);
    float var = qq * (1.0f / 256.0f) - mu * mu;
    s[r] = mu; q[r] = rsqrtf(var + 1e-5f);
  }
#pragma unroll
  for (int t = 0; t < 16; ++t) {
    int col = t * 16 + li;
    float gv = g[col], bv = be[col];
#pragma unroll
    for (int r = 0; r < 4; ++r) {
      int row = m0 + w * 16 + g16 * 4 + r;
      out[(size_t)row * 256 + col] = (acc2[t][r] - s[r]) * q[r] * gv + bv;
    }
  }
}

// ---------------------------------------------------------------- launch
extern "C" void kernel_launch(void* const* d_in, const int* in_sizes, int n_in,
                              void* d_out, int out_size, void* d_ws, size_t ws_size,
                              hipStream_t stream) {
  const float* X    = (const float*)d_in[0];
  const float* Wqkv = (const float*)d_in[2];
  const float* bqkv = (const float*)d_in[3];
  const float* Wout = (const float*)d_in[4];
  const float* bout = (const float*)d_in[5];
  const float* W1   = (const float*)d_in[6];
  const float* b1   = (const float*)d_in[7];
  const float* W2   = (const float*)d_in[8];
  const float* b2   = (const float*)d_in[9];
  const float* g1   = (const float*)d_in[10];
  const float* be1  = (const float*)d_in[11];
  const float* g2   = (const float*)d_in[12];
  const float* be2  = (const float*)d_in[13];
  const float* rel1 = (const float*)d_in[14];
  const float* rel2 = (const float*)d_in[15];
  const float* rel4 = (const float*)d_in[16];
  const float* rel8 = (const float*)d_in[17];
  float* out = (float*)d_out;

  char* W = (char*)d_ws;
  ushort_t* qbb  = (ushort_t*)(W);                  // 23,068,672
  ushort_t* kbb  = (ushort_t*)(W + 23068672);       // 23,068,672
  ushort_t* vbb  = (ushort_t*)(W + 46137344);       // 23,068,672
  ushort_t* vbt  = (ushort_t*)(W + 69206016);       //  5,767,168
  ushort_t* ao   = (ushort_t*)(W + 74973184);       // 23,068,672
  const size_t F = 98041856;
  ushort_t* qw2  = (ushort_t*)(W + F);
  ushort_t* kw2  = (ushort_t*)(W + F + 5832704);
  ushort_t* vwt2 = (ushort_t*)(W + F + 11665408);
  ushort_t* qw4  = (ushort_t*)(W + F + 17432576);
  ushort_t* kw4  = (ushort_t*)(W + F + 23265280);
  ushort_t* vwt4 = (ushort_t*)(W + F + 29097984);
  ushort_t* qw8  = (ushort_t*)(W + F + 35389440);
  ushort_t* kw8  = (ushort_t*)(W + F + 41222144);
  ushort_t* vwt8 = (ushort_t*)(W + F + 47054848);
  ushort_t* Wqkvt= (ushort_t*)(W + F + 55443456);   //   393,216
  ushort_t* Woutt= (ushort_t*)(W + F + 55836672);   //   131,072
  char*     Wc   = (char*)    (W + F + 55967744);   // 2,097,152
  float*    x1   = (float*)(W);                     // reuse qbb+kbb after attention
  ushort_t* x1b  = (ushort_t*)(W + 46137344);       // reuse vbb after relays

  k_cvtw<<<dim3(8, 24), 256, 0, stream>>>(Wqkv, Wqkvt, 256, 768);
  k_cvtw<<<dim3(8, 8),  256, 0, stream>>>(Wout, Woutt, 256, 256);
  k_prepw1<<<dim3(2048), 256, 0, stream>>>(W1, Wc);
  k_prepw2<<<dim3(2048), 256, 0, stream>>>(W2, Wc);
  k_qkv2<<<dim3(704, 3), 256, 0, stream>>>(X, Wqkvt, bqkv, qbb, kbb, vbb, vbt);
  k_relay<2><<<dim3(44, 64, 2), 256, 0, stream>>>(qbb, kbb, vbb, qw2, kw2, vwt2, 1, 5);
  k_relay<4><<<dim3(11, 64, 2), 256, 0, stream>>>(qbb, kbb, vbb, qw4, kw4, vwt4, 2, 6);
  k_relay<8><<<dim3(3, 64, 2),  256, 0, stream>>>(qbb, kbb, vbb, qw8, kw8, vwt8, 3, 7);
  k_attn1m<<<dim3(11, 64, 2), 256, 0, stream>>>(qbb, kbb, vbt, rel1, ao);
  k_attnm<2, 256><<<dim3(11, 64, 2), 256, 0, stream>>>(qw2, kw2, vwt2, rel2, ao, 1, 5);
  k_attnm<4, 256><<<dim3(3, 64, 2),  256, 0, stream>>>(qw4, kw4, vwt4, rel4, ao, 2, 6);
  k_attnm<8, 512><<<dim3(1, 64, 2),  512, 0, stream>>>(qw8, kw8, vwt8, rel8, ao, 3, 7);
  k_projln<<<dim3(704), 256, 0, stream>>>(ao, Woutt, bout, X, g1, be1, x1, x1b);
  k_ffn3<<<dim3(352), 512, 0, stream>>>(x1b, x1, Wc, b1, b2, g2, be2, out);
}

// Round 7
// 893.676 us; speedup vs baseline: 10.8766x; 1.0211x over previous
//
#include <hip/hip_runtime.h>
#include <hip/hip_bf16.h>
#include <math.h>

#define L_ALL 704
#define NB 64
#define DM 256
#define HD 32
#define M_TOT (L_ALL*NB)
#define Q_SCALE 0.17677669529663687f

typedef __attribute__((ext_vector_type(8))) short bf16x8;
typedef __attribute__((ext_vector_type(4))) float f32x4;
typedef unsigned short ushort_t;

static __device__ __forceinline__ unsigned short f2b(float x) {
  __hip_bfloat16 h = __float2bfloat16(x);
  return *reinterpret_cast<unsigned short*>(&h);
}

__device__ __forceinline__ float wfun(int t, int ws) {
  float f = (float)t / (float)ws;
  return f > 0.5f ? f : 1.0f - f;
}

template<int WS>
__device__ __forceinline__ int tokf(int i, int a, int c, int shift) {
  constexpr int NW8 = 8 / WS;
  constexpr int N1 = NW8 * NW8;
  constexpr int NW24 = 24 / WS;
  if (i < 2 * N1) {
    int fr = i / N1, li2 = i % N1;
    int wi = li2 / NW8, wj = li2 % NW8;
    return fr * 64 + (wi * WS + a) * 8 + (wj * WS + c);
  }
  int ls = i - 2 * N1;
  int wi = ls / NW24, wj = ls % NW24;
  int r = (wi * WS + a + shift) % 24;
  int cc = (wj * WS + c + shift) % 24;
  return 128 + r * 24 + cc;
}

static __device__ __forceinline__ void gl16(const void* g, void* l) {
  __builtin_amdgcn_global_load_lds(
      (const __attribute__((address_space(1))) unsigned*)g,
      (__attribute__((address_space(3))) unsigned*)l, 16, 0, 0);
}

// ---------------------------------------------------------------- weight convert+transpose
__global__ __launch_bounds__(256) void k_cvtw(const float* __restrict__ src,
    ushort_t* __restrict__ dst, int R, int C) {
  __shared__ float tile[32][33];
  const int r0 = blockIdx.x * 32, c0 = blockIdx.y * 32;
  const int tr = threadIdx.x >> 5, tc = threadIdx.x & 31;
#pragma unroll
  for (int i = 0; i < 4; ++i)
    tile[tr + i * 8][tc] = src[(size_t)(r0 + tr + i * 8) * C + c0 + tc];
  __syncthreads();
#pragma unroll
  for (int i = 0; i < 4; ++i)
    dst[(size_t)(c0 + tr + i * 8) * R + r0 + tc] = f2b(tile[tc][tr + i * 8]);
}

// ---------------------------------------------------------------- FFN weight pack (swizzled LDS images)
__global__ __launch_bounds__(256) void k_prepw1(const float* __restrict__ W1,
    char* __restrict__ Wc) {
  int t = blockIdx.x * 256 + threadIdx.x;
  int k = t >> 11, n = t & 2047;
  int ch = n >> 6, hr = n & 63;
  unsigned off = (unsigned)((hr * 512 + k * 2) ^ ((hr & 7) << 4));
  *(ushort_t*)(Wc + (size_t)ch * 65536 + off) = f2b(W1[(size_t)k * 2048 + n]);
}
__global__ __launch_bounds__(256) void k_prepw2(const float* __restrict__ W2,
    char* __restrict__ Wc) {
  int t = blockIdx.x * 256 + threadIdx.x;
  int k = t >> 8, n = t & 255;
  int ch = k >> 6, kk = k & 63;
  unsigned off = 32768u + (unsigned)((n * 128 + kk * 2) ^ ((n & 7) << 4));
  *(ushort_t*)(Wc + (size_t)ch * 65536 + off) = f2b(W2[(size_t)k * 256 + n]);
}

// ---------------------------------------------------------------- QKV GEMM (bf16 MFMA, coalesced epilogue)
__global__ __launch_bounds__(256) void k_qkv2(const float* __restrict__ X,
    const ushort_t* __restrict__ Wt, const float* __restrict__ bias,
    ushort_t* __restrict__ qbb, ushort_t* __restrict__ kbb,
    ushort_t* __restrict__ vbb) {
  __shared__ ushort_t otile[64 * 264];
  const int tid = threadIdx.x;
  const int w = tid >> 6, lane = tid & 63, li = lane & 15, g16 = lane >> 4;
  const int m0 = blockIdx.x * 64;
  const int sec = blockIdx.y;
  f32x4 acc[16];
#pragma unroll
  for (int t = 0; t < 16; ++t) acc[t] = (f32x4){0.f, 0.f, 0.f, 0.f};
  const float* arow = X + (size_t)(m0 + w * 16 + li) * 256;
  for (int k0 = 0; k0 < 256; k0 += 32) {
    float4 xa = *(const float4*)(arow + k0 + g16 * 8);
    float4 xb = *(const float4*)(arow + k0 + g16 * 8 + 4);
    bf16x8 a;
    a[0] = f2b(xa.x); a[1] = f2b(xa.y); a[2] = f2b(xa.z); a[3] = f2b(xa.w);
    a[4] = f2b(xb.x); a[5] = f2b(xb.y); a[6] = f2b(xb.z); a[7] = f2b(xb.w);
#pragma unroll
    for (int t = 0; t < 16; ++t) {
      const ushort_t* bp = Wt + (size_t)(sec * 256 + t * 16 + li) * 256 + k0 + g16 * 8;
      bf16x8 bf = *(const bf16x8*)bp;
      acc[t] = __builtin_amdgcn_mfma_f32_16x16x32_bf16(a, bf, acc[t], 0, 0, 0);
    }
  }
  const float qs = (sec == 0) ? Q_SCALE : 1.0f;
#pragma unroll
  for (int t = 0; t < 16; ++t) {
    int col = t * 16 + li;
    float bv = bias[sec * 256 + col];
#pragma unroll
    for (int r = 0; r < 4; ++r) {
      int row = w * 16 + g16 * 4 + r;
      otile[row * 264 + col] = f2b((acc[t][r] + bv) * qs);
    }
  }
  __syncthreads();
  ushort_t* dst = (sec == 0) ? qbb : (sec == 1) ? kbb : vbb;
  for (int v = tid; v < 2048; v += 256) {
    int row = v >> 5, cg = (v & 31) * 8;
    uint4 d = *(const uint4*)(otile + row * 264 + cg);
    *(uint4*)(dst + (size_t)(m0 + row) * 256 + cg) = d;
  }
}

// ---------------------------------------------------------------- V transpose for ws=1 heads
// vbt[slot*64+b][e(32)][tok(704)] <- vbb[(tok*64+b)*256 + h*32 + e], h = slot?4:0
__global__ __launch_bounds__(256) void k_vt(const ushort_t* __restrict__ vbb,
    ushort_t* __restrict__ vbt) {
  __shared__ ushort_t tile[32 * 34];
  const int b = blockIdx.x, slot = blockIdx.y;
  const int h = slot ? 4 : 0;
  const int tid = threadIdx.x;
  const size_t vrow0 = (size_t)(slot * 64 + b) * 32;
  const int eg = tid & 7, tok_l = tid >> 3;     // load: 8 lanes x 4e, 32 toks
  const int e_w = tid & 31, tg = tid >> 5;      // store: 32 e, 8 groups x 4 toks
  for (int tt = 0; tt < 22; ++tt) {
    int tok0 = tt * 32;
    uint2 d = *(const uint2*)(vbb +
        ((size_t)((tok0 + tok_l) * 64 + b)) * 256 + h * 32 + eg * 4);
    tile[tok_l * 34 + eg * 4 + 0] = (ushort_t)(d.x & 0xffffu);
    tile[tok_l * 34 + eg * 4 + 1] = (ushort_t)(d.x >> 16);
    tile[tok_l * 34 + eg * 4 + 2] = (ushort_t)(d.y & 0xffffu);
    tile[tok_l * 34 + eg * 4 + 3] = (ushort_t)(d.y >> 16);
    __syncthreads();
    uint2 o;
    o.x = (unsigned)tile[(tg * 4 + 0) * 34 + e_w] |
          ((unsigned)tile[(tg * 4 + 1) * 34 + e_w] << 16);
    o.y = (unsigned)tile[(tg * 4 + 2) * 34 + e_w] |
          ((unsigned)tile[(tg * 4 + 3) * 34 + e_w] << 16);
    *(uint2*)(vbt + (vrow0 + e_w) * 704 + tok0 + tg * 4) = o;
    __syncthreads();
  }
}

// ---------------------------------------------------------------- ws=1 attention (MFMA flash)
__global__ __launch_bounds__(256) void k_attn1m(const ushort_t* __restrict__ qbb,
    const ushort_t* __restrict__ kbb, const ushort_t* __restrict__ vbt,
    const float* __restrict__ rel, ushort_t* __restrict__ ao) {
  __shared__ ushort_t P_lds[4 * 512];
  const int tid = threadIdx.x;
  const int w = tid >> 6, lane = tid & 63, li = lane & 15, g16 = lane >> 4;
  const int b = blockIdx.y;
  const int h = blockIdx.z ? 4 : 0;
  const int slot = blockIdx.z;
  const int qrow0 = blockIdx.x * 64 + w * 16;
  char* myP = (char*)P_lds + w * 1024;

  const bf16x8 qfrag = *(const bf16x8*)(qbb +
      (size_t)((qrow0 + li) * 64 + b) * 256 + h * 32 + g16 * 8);
  f32x4 o0 = (f32x4){0.f, 0.f, 0.f, 0.f}, o1 = o0;
  float m_run[4] = {-1e30f, -1e30f, -1e30f, -1e30f};
  float l_run[4] = {0.f, 0.f, 0.f, 0.f};

  const size_t vrow0 = (size_t)(slot * 64 + b) * 32;

  for (int kt = 0; kt < 704; kt += 32) {
    f32x4 s0 = (f32x4){0.f, 0.f, 0.f, 0.f}, s1 = s0;
    bf16x8 kf0 = *(const bf16x8*)(kbb + (size_t)((kt + li) * 64 + b) * 256 + h * 32 + g16 * 8);
    bf16x8 kf1 = *(const bf16x8*)(kbb + (size_t)((kt + 16 + li) * 64 + b) * 256 + h * 32 + g16 * 8);
    s0 = __builtin_amdgcn_mfma_f32_16x16x32_bf16(qfrag, kf0, s0, 0, 0, 0);
    s1 = __builtin_amdgcn_mfma_f32_16x16x32_bf16(qfrag, kf1, s1, 0, 0, 0);
    const float* rb = rel + (size_t)(qrow0 + g16 * 4) * 704 + kt;
#pragma unroll
    for (int r = 0; r < 4; ++r) {
      s0[r] += rb[(size_t)r * 704 + li];
      s1[r] += rb[(size_t)r * 704 + 16 + li];
    }
#pragma unroll
    for (int r = 0; r < 4; ++r) {
      float pm = fmaxf(s0[r], s1[r]);
      for (int m = 1; m < 16; m <<= 1) pm = fmaxf(pm, __shfl_xor(pm, m));
      float mn = fmaxf(m_run[r], pm);
      float corr = __expf(m_run[r] - mn);
      float p0 = __expf(s0[r] - mn);
      float p1 = __expf(s1[r] - mn);
      float ps = p0 + p1;
      for (int m = 1; m < 16; m <<= 1) ps += __shfl_xor(ps, m);
      l_run[r] = l_run[r] * corr + ps;
      m_run[r] = mn;
      o0[r] *= corr; o1[r] *= corr;
      int row = g16 * 4 + r;
      unsigned sw = (unsigned)((row & 7) << 4);
      *(ushort_t*)(myP + (((unsigned)(row * 64 + li * 2)) ^ sw)) = f2b(p0);
      *(ushort_t*)(myP + (((unsigned)(row * 64 + 32 + li * 2)) ^ sw)) = f2b(p1);
    }
    bf16x8 pa = *(const bf16x8*)(myP + (((unsigned)(li * 64 + g16 * 16)) ^ ((unsigned)((li & 7) << 4))));
    bf16x8 v0 = *(const bf16x8*)(vbt + (vrow0 + li) * 704 + kt + g16 * 8);
    bf16x8 v1 = *(const bf16x8*)(vbt + (vrow0 + 16 + li) * 704 + kt + g16 * 8);
    o0 = __builtin_amdgcn_mfma_f32_16x16x32_bf16(pa, v0, o0, 0, 0, 0);
    o1 = __builtin_amdgcn_mfma_f32_16x16x32_bf16(pa, v1, o1, 0, 0, 0);
  }
#pragma unroll
  for (int r = 0; r < 4; ++r) {
    float inv = 1.0f / l_run[r];
    int token = qrow0 + g16 * 4 + r;
    size_t orow = (size_t)(token * 64 + b) * 256 + h * 32;
    ao[orow + li] = f2b(o0[r] * inv);
    ao[orow + 16 + li] = f2b(o1[r] * inv);
  }
}

// ---------------------------------------------------------------- window relayout
template<int WS>
__global__ __launch_bounds__(256) void k_relay(const ushort_t* __restrict__ qbb,
    const ushort_t* __restrict__ kbb, const ushort_t* __restrict__ vbb,
    ushort_t* __restrict__ qw, ushort_t* __restrict__ kw, ushort_t* __restrict__ vwt,
    int hA, int hB) {
  constexpr int G = WS * WS;
  constexpr int M = WS - 1;
  constexpr int LW = (WS == 2) ? 1 : (WS == 4) ? 2 : 3;
  constexpr int NWIN = 704 / G;
  constexpr int CD = G * 32;
  constexpr int LPAD16 = (NWIN + 15) & ~15;
  const int tid = threadIdx.x;
  const int b = blockIdx.y, z = blockIdx.z;
  const int h = z ? hB : hA;
  const int shift = z ? (WS / 2) : 0;
  const size_t sl = (size_t)(z * 64 + b);
  const size_t qkb = sl * NWIN * CD;
  const size_t vb = sl * CD * LPAD16;
  for (int idx2 = tid; idx2 < 4 * (CD / 2); idx2 += 256) {
    int l = blockIdx.x * 4 + idx2 / (CD / 2);
    if (l >= NWIN) break;
    int idx = (idx2 % (CD / 2)) * 2;
    int cell = idx >> 5, e = idx & 31;
    int a = cell >> LW, c = cell & M;
    int tokv = tokf<WS>(l, a, c, shift);
    size_t so = ((size_t)(tokv * 64 + b)) * 256 + h * 32 + e;
    *(unsigned*)(qw + qkb + (size_t)l * CD + idx) = *(const unsigned*)(qbb + so);
    unsigned kv = *(const unsigned*)(kbb + so);
    *(unsigned*)(kw + qkb + (size_t)l * CD + idx) = kv;
    unsigned vv = *(const unsigned*)(vbb + so);
    vwt[vb + (size_t)idx * LPAD16 + l] = (ushort_t)(vv & 0xffffu);
    vwt[vb + (size_t)(idx + 1) * LPAD16 + l] = (ushort_t)(vv >> 16);
  }
  if (LPAD16 > NWIN && blockIdx.x == 0) {
    for (int idx = tid; idx < CD * (LPAD16 - NWIN); idx += 256) {
      int x = idx / (LPAD16 - NWIN);
      int pl = NWIN + idx % (LPAD16 - NWIN);
      vwt[vb + (size_t)x * LPAD16 + pl] = 0;
    }
  }
}

// ---------------------------------------------------------------- ws>1 attention (LDS-staged MFMA group-GEMM)
template<int WS, int NT>
__global__ __launch_bounds__(NT) void k_attnm(const ushort_t* __restrict__ qw,
    const ushort_t* __restrict__ kw, const ushort_t* __restrict__ vwt,
    const float* __restrict__ rel, ushort_t* __restrict__ ao, int hA, int hB) {
  constexpr int G = WS * WS;
  constexpr int M = WS - 1;
  constexpr int LW = (WS == 2) ? 1 : (WS == 4) ? 2 : 3;
  constexpr int NWIN = 704 / G;
  constexpr int CD = G * 32;
  constexpr int LPAD16 = (NWIN + 15) & ~15;
  constexpr int NTL = LPAD16 / 16;
  constexpr int NW = NT / 64;
  constexpr int GPW = G / NW;
  constexpr int TPW_S = GPW * NTL;
  constexpr int XT = CD / 16;
  constexpr int TPW_O = XT / NW;
  constexpr int PSTEPS = (G * LPAD16) / 32;
  constexpr int PSTR = G * LPAD16 + 8;
  constexpr float invG = 1.0f / (float)G;
  constexpr bool KQV_FULL = (WS <= 4);
  constexpr int CDP = CD + 8;
  constexpr int LP  = LPAD16 + 8;
  constexpr int KROWS = NTL * 16;

  constexpr int QS_B = 16 * CDP * 2;
  constexpr int KS_B = KQV_FULL ? (KROWS * CDP * 2) : 0;
  constexpr int VS_B = CD * LP * 2;
  constexpr int OFF_K = 0;
  constexpr int OFF_Q = KQV_FULL ? KS_B : 0;
  constexpr int OFF_V = KQV_FULL ? (KS_B + QS_B) : 0;
  constexpr int OFF_P = KQV_FULL ? (KS_B + QS_B + VS_B)
                                 : ((QS_B > VS_B) ? QS_B : VS_B);
  constexpr int TOT_B = OFF_P + 16 * PSTR * 2;
  __shared__ __align__(16) char smem[TOT_B];
  __shared__ float redm[NW][16], reds[NW][16];

  const int tid = threadIdx.x;
  const int w = tid >> 6, lane = tid & 63, li = lane & 15, g16 = lane >> 4;
  const int i0 = blockIdx.x * 16;
  const int b = blockIdx.y, z = blockIdx.z;
  const int h = z ? hB : hA;
  const int shift = z ? (WS / 2) : 0;
  const size_t sl = (size_t)(z * 64 + b);
  const ushort_t* qs_g = qw + sl * NWIN * CD;
  const ushort_t* ks_g = kw + sl * NWIN * CD;
  const ushort_t* vs_g = vwt + sl * CD * LPAD16;
  ushort_t* Ks = (ushort_t*)(smem + OFF_K);
  ushort_t* Qs = (ushort_t*)(smem + OFF_Q);
  ushort_t* Vs = (ushort_t*)(smem + OFF_V);
  ushort_t* Pl = (ushort_t*)(smem + OFF_P);
  const int laneAoff = ((g16 >> 1) << 4) + ((g16 & 1) << 3);

  {
    const ushort_t* src = qs_g + (size_t)i0 * CD;
    for (int v = tid; v < 16 * CD / 8; v += NT) {
      int row = (v * 8) / CD, col = (v * 8) % CD;
      uint4 d = *(const uint4*)(src + (size_t)v * 8);
      *(uint4*)(Qs + row * CDP + col) = d;
    }
  }
  if constexpr (KQV_FULL) {
    for (int v = tid; v < NWIN * CD / 8; v += NT) {
      int row = (v * 8) / CD, col = (v * 8) % CD;
      uint4 d = *(const uint4*)(ks_g + (size_t)v * 8);
      *(uint4*)(Ks + row * CDP + col) = d;
    }
    for (int v = tid; v < CD * LPAD16 / 8; v += NT) {
      int row = (v * 8) / LPAD16, col = (v * 8) % LPAD16;
      uint4 d = *(const uint4*)(vs_g + (size_t)v * 8);
      *(uint4*)(Vs + row * LP + col) = d;
    }
  }
  __syncthreads();

  f32x4 sreg[TPW_S];
#pragma unroll
  for (int jg = 0; jg < GPW; ++jg) {
    const int g = w * GPW + jg;
    const int p1 = g >> LW, q1 = g & M;
    const float msk = (wfun(p1, WS) * wfun(q1, WS) - 1.0f) * invG;
#pragma unroll
    for (int jn = 0; jn < NTL; ++jn) {
      f32x4 acc = (f32x4){0.f, 0.f, 0.f, 0.f};
#pragma unroll
      for (int ksi = 0; ksi < G; ++ksi) {
        int a = ksi >> LW, c = ksi & M;
        int scell = (((a + p1) & M) << LW) | ((c + q1) & M);
        bf16x8 afr = *(const bf16x8*)(Qs + li * CDP + scell * 32 + g16 * 8);
        bf16x8 bfr;
        if constexpr (KQV_FULL)
          bfr = *(const bf16x8*)(Ks + (jn * 16 + li) * CDP + ksi * 32 + g16 * 8);
        else
          bfr = *(const bf16x8*)(ks_g + (size_t)(jn * 16 + li) * CD + ksi * 32 + g16 * 8);
        acc = __builtin_amdgcn_mfma_f32_16x16x32_bf16(afr, bfr, acc, 0, 0, 0);
      }
#pragma unroll
      for (int r = 0; r < 4; ++r) {
        int iloc = g16 * 4 + r, ig = i0 + iloc, l = jn * 16 + li;
        float s;
        if (ig < NWIN && l < NWIN)
          s = acc[r] * invG + msk + rel[(size_t)ig * 704 + l * G + g];
        else
          s = -3e38f;
        acc[r] = s;
      }
      sreg[jg * NTL + jn] = acc;
    }
  }

  float pm[4] = {-3e38f, -3e38f, -3e38f, -3e38f};
#pragma unroll
  for (int t = 0; t < TPW_S; ++t)
#pragma unroll
    for (int r = 0; r < 4; ++r) pm[r] = fmaxf(pm[r], sreg[t][r]);
#pragma unroll
  for (int mm = 1; mm < 16; mm <<= 1)
#pragma unroll
    for (int r = 0; r < 4; ++r) pm[r] = fmaxf(pm[r], __shfl_xor(pm[r], mm));
  if (li == 0) {
#pragma unroll
    for (int r = 0; r < 4; ++r) redm[w][g16 * 4 + r] = pm[r];
  }
  __syncthreads();
  float mrow[4];
#pragma unroll
  for (int r = 0; r < 4; ++r) {
    float v = redm[0][g16 * 4 + r];
    for (int ww = 1; ww < NW; ++ww) v = fmaxf(v, redm[ww][g16 * 4 + r]);
    mrow[r] = v;
  }
  float ps[4] = {0.f, 0.f, 0.f, 0.f};
#pragma unroll
  for (int t = 0; t < TPW_S; ++t)
#pragma unroll
    for (int r = 0; r < 4; ++r) {
      float p = __expf(sreg[t][r] - mrow[r]);
      sreg[t][r] = p;
      ps[r] += p;
    }
#pragma unroll
  for (int mm = 1; mm < 16; mm <<= 1)
#pragma unroll
    for (int r = 0; r < 4; ++r) ps[r] += __shfl_xor(ps[r], mm);
  if (li == 0) {
#pragma unroll
    for (int r = 0; r < 4; ++r) reds[w][g16 * 4 + r] = ps[r];
  }
  __syncthreads();
  float inv4[4];
#pragma unroll
  for (int r = 0; r < 4; ++r) {
    float v = reds[0][g16 * 4 + r];
    for (int ww = 1; ww < NW; ++ww) v += reds[ww][g16 * 4 + r];
    inv4[r] = 1.0f / v;
  }
#pragma unroll
  for (int t = 0; t < TPW_S; ++t) {
    const int g = w * GPW + t / NTL;
    const int col = g * LPAD16 + (t % NTL) * 16 + li;
#pragma unroll
    for (int r = 0; r < 4; ++r)
      Pl[(size_t)(g16 * 4 + r) * PSTR + col] = f2b(sreg[t][r] * inv4[r]);
  }
  __syncthreads();

  if constexpr (!KQV_FULL) {
    for (int v = tid; v < CD * LPAD16 / 8; v += NT) {
      int row = (v * 8) / LPAD16, col = (v * 8) % LPAD16;
      uint4 d = *(const uint4*)(vs_g + (size_t)v * 8);
      *(uint4*)(Vs + row * LP + col) = d;
    }
    __syncthreads();
  }

  f32x4 oacc[TPW_O];
#pragma unroll
  for (int j = 0; j < TPW_O; ++j) oacc[j] = (f32x4){0.f, 0.f, 0.f, 0.f};
  for (int p = 0; p < PSTEPS; ++p) {
    const int kc0 = 2 * p;
    const int g0 = kc0 / NTL, lb0 = kc0 % NTL;
    const int g1 = (kc0 + 1) / NTL, lb1 = (kc0 + 1) % NTL;
    const int p10 = g0 >> LW, q10 = g0 & M;
    const int p11 = g1 >> LW, q11 = g1 & M;
    bf16x8 A = *(const bf16x8*)(Pl + (size_t)li * PSTR + kc0 * 16 + laneAoff);
#pragma unroll
    for (int j = 0; j < TPW_O; ++j) {
      const int ot = w * TPW_O + j;
      const int oc = ot >> 1, oh16 = (ot & 1) << 4;
      const int a_o = oc >> LW, c_o = oc & M;
      int sc0 = (((a_o - p10) & M) << LW) | ((c_o - q10) & M);
      int sc1 = (((a_o - p11) & M) << LW) | ((c_o - q11) & M);
      int scl = (g16 < 2) ? sc0 : sc1;
      int lbl = (g16 < 2) ? lb0 : lb1;
      bf16x8 B = *(const bf16x8*)(Vs + (size_t)(scl * 32 + oh16 + li) * LP + lbl * 16 + ((g16 & 1) << 3));
      oacc[j] = __builtin_amdgcn_mfma_f32_16x16x32_bf16(A, B, oacc[j], 0, 0, 0);
    }
  }
#pragma unroll
  for (int j = 0; j < TPW_O; ++j) {
    const int ot = w * TPW_O + j;
#pragma unroll
    for (int r = 0; r < 4; ++r) {
      int ig = i0 + g16 * 4 + r;
      if (ig < NWIN) {
        int x = ot * 16 + li;
        int cell = x >> 5, e = x & 31;
        int a = cell >> LW, c = cell & M;
        int tokv = tokf<WS>(ig, a, c, shift);
        ao[((size_t)(tokv * 64 + b)) * 256 + h * 32 + e] = f2b(oacc[j][r]);
      }
    }
  }
}

// ---------------------------------------------------------------- out-proj + residual + LN1 (MFMA)
__global__ __launch_bounds__(256) void k_projln(const ushort_t* __restrict__ ao,
    const ushort_t* __restrict__ Wt, const float* __restrict__ bout,
    const float* __restrict__ X0, const float* __restrict__ g,
    const float* __restrict__ be, float* __restrict__ x1, ushort_t* __restrict__ x1b) {
  const int tid = threadIdx.x;
  const int w = tid >> 6, lane = tid & 63, li = lane & 15, g16 = lane >> 4;
  const int m0 = blockIdx.x * 64;
  f32x4 acc[16];
#pragma unroll
  for (int t = 0; t < 16; ++t) acc[t] = (f32x4){0.f, 0.f, 0.f, 0.f};
  const ushort_t* arow = ao + (size_t)(m0 + w * 16 + li) * 256;
  for (int k0 = 0; k0 < 256; k0 += 32) {
    bf16x8 a = *(const bf16x8*)(arow + k0 + g16 * 8);
#pragma unroll
    for (int t = 0; t < 16; ++t) {
      bf16x8 bf = *(const bf16x8*)(Wt + (size_t)(t * 16 + li) * 256 + k0 + g16 * 8);
      acc[t] = __builtin_amdgcn_mfma_f32_16x16x32_bf16(a, bf, acc[t], 0, 0, 0);
    }
  }
  float s[4] = {0.f, 0.f, 0.f, 0.f}, q[4] = {0.f, 0.f, 0.f, 0.f};
#pragma unroll
  for (int t = 0; t < 16; ++t) {
    int col = t * 16 + li;
    float bb = bout[col];
#pragma unroll
    for (int r = 0; r < 4; ++r) {
      int row = m0 + w * 16 + g16 * 4 + r;
      float v = acc[t][r] + bb + X0[(size_t)row * 256 + col];
      acc[t][r] = v;
      s[r] += v; q[r] += v * v;
    }
  }
#pragma unroll
  for (int r = 0; r < 4; ++r) {
    float ss = s[r], qq = q[r];
    for (int m = 1; m < 16; m <<= 1) { ss += __shfl_xor(ss, m); qq += __shfl_xor(qq, m); }
    float mu = ss * (1.0f / 256.0f);
    float var = qq * (1.0f / 256.0f) - mu * mu;
    s[r] = mu; q[r] = rsqrtf(var + 1e-5f);
  }
#pragma unroll
  for (int t = 0; t < 16; ++t) {
    int col = t * 16 + li;
    float gv = g[col], bv = be[col];
#pragma unroll
    for (int r = 0; r < 4; ++r) {
      int row = m0 + w * 16 + g16 * 4 + r;
      float o = (acc[t][r] - s[r]) * q[r] * gv + bv;
      x1[(size_t)row * 256 + col] = o;
      x1b[(size_t)row * 256 + col] = f2b(o);
    }
  }
}

// ---------------------------------------------------------------- fused FFN + LN2 (counted-vmcnt pipeline)
__global__ __launch_bounds__(512, 2) void k_ffn3(
    const ushort_t* __restrict__ x1b, const float* __restrict__ x1,
    const char* __restrict__ Wc, const float* __restrict__ b1,
    const float* __restrict__ b2, const float* __restrict__ g,
    const float* __restrict__ be, float* __restrict__ out) {
  __shared__ char wbuf[2][65536];
  __shared__ char Hl[16384];
  const int tid = threadIdx.x;
  const int w = tid >> 6, lane = tid & 63, li = lane & 15, g16 = lane >> 4;
  const int m0 = blockIdx.x * 128;

  bf16x8 afrag[8];
  const ushort_t* aptr = x1b + (size_t)(m0 + w * 16 + li) * 256 + g16 * 8;
#pragma unroll
  for (int kk = 0; kk < 8; ++kk) afrag[kk] = *(const bf16x8*)(aptr + kk * 32);

  f32x4 acc2[16];
#pragma unroll
  for (int i = 0; i < 16; ++i) acc2[i] = (f32x4){0.f, 0.f, 0.f, 0.f};

#pragma unroll
  for (int s = 0; s < 8; ++s) {
    int off = (tid + s * 512) * 16;
    gl16(Wc + off, &wbuf[0][0] + off);
  }
  asm volatile("s_waitcnt vmcnt(0)" ::: "memory");
  __builtin_amdgcn_sched_barrier(0);
  __builtin_amdgcn_s_barrier();
  __builtin_amdgcn_sched_barrier(0);

  for (int ch = 0; ch < 32; ++ch) {
    const int cur = ch & 1;
    if (ch + 1 < 32) {
      const char* gsrc = Wc + (size_t)(ch + 1) * 65536;
#pragma unroll
      for (int s = 0; s < 8; ++s) {
        int off = (tid + s * 512) * 16;
        gl16(gsrc + off, &wbuf[cur ^ 1][0] + off);
      }
    }
    f32x4 hacc[4];
#pragma unroll
    for (int f = 0; f < 4; ++f) hacc[f] = (f32x4){0.f, 0.f, 0.f, 0.f};
#pragma unroll
    for (int kk = 0; kk < 8; ++kk) {
#pragma unroll
      for (int f = 0; f < 4; ++f) {
        int row = f * 16 + li;
        unsigned off = (unsigned)((row * 512 + kk * 64 + g16 * 16)) ^ (unsigned)((row & 7) << 4);
        bf16x8 bfr = *(const bf16x8*)(&wbuf[cur][0] + off);
        hacc[f] = __builtin_amdgcn_mfma_f32_16x16x32_bf16(afrag[kk], bfr, hacc[f], 0, 0, 0);
      }
    }
#pragma unroll
    for (int f = 0; f < 4; ++f) {
      int col = f * 16 + li;
      float bb = b1[ch * 64 + col];
#pragma unroll
      for (int r = 0; r < 4; ++r) {
        int row = w * 16 + g16 * 4 + r;
        unsigned off = (unsigned)((row * 128 + col * 2)) ^ (unsigned)((row & 7) << 4);
        *(ushort_t*)(Hl + off) = f2b(fmaxf(hacc[f][r] + bb, 0.f));
      }
    }
    // barrier 1: H visible — drain LDS only, keep staged loads in flight (T4)
    asm volatile("s_waitcnt lgkmcnt(0)" ::: "memory");
    __builtin_amdgcn_sched_barrier(0);
    __builtin_amdgcn_s_barrier();
    __builtin_amdgcn_sched_barrier(0);
#pragma unroll
    for (int ks = 0; ks < 2; ++ks) {
      int hrow = w * 16 + li;
      unsigned aoff = (unsigned)((hrow * 128 + ks * 64 + g16 * 16)) ^ (unsigned)((hrow & 7) << 4);
      bf16x8 a = *(const bf16x8*)(Hl + aoff);
#pragma unroll
      for (int t = 0; t < 16; ++t) {
        int n = t * 16 + li;
        unsigned boff = 32768u + ((unsigned)((n * 128 + ks * 64 + g16 * 16)) ^ (unsigned)((n & 7) << 4));
        bf16x8 bfr = *(const bf16x8*)(&wbuf[cur][0] + boff);
        acc2[t] = __builtin_amdgcn_mfma_f32_16x16x32_bf16(a, bfr, acc2[t], 0, 0, 0);
      }
    }
    // barrier 2: wbuf[cur] consumed; staged loads for ch+1 complete
    asm volatile("s_waitcnt vmcnt(0) lgkmcnt(0)" ::: "memory");
    __builtin_amdgcn_sched_barrier(0);
    __builtin_amdgcn_s_barrier();
    __builtin_amdgcn_sched_barrier(0);
  }

  float s[4] = {0.f, 0.f, 0.f, 0.f}, q[4] = {0.f, 0.f, 0.f, 0.f};
#pragma unroll
  for (int t = 0; t < 16; ++t) {
    int col = t * 16 + li;
    float bb = b2[col];
#pragma unroll
    for (int r = 0; r < 4; ++r) {
      int row = m0 + w * 16 + g16 * 4 + r;
      float v = acc2[t][r] + bb + x1[(size_t)row * 256 + col];
      acc2[t][r] = v;
      s[r] += v; q[r] += v * v;
    }
  }
#pragma unroll
  for (int r = 0; r < 4; ++r) {
    float ss = s[r], qq = q[r];
    for (int m = 1; m < 16; m <<= 1) { ss += __shfl_xor(ss, m); qq += __shfl_xor(qq, m); }
    float mu = ss * (1.0f / 256.0f);
    float var = qq * (1.0f / 256.0f) - mu * mu;
    s[r] = mu; q[r] = rsqrtf(var + 1e-5f);
  }
#pragma unroll
  for (int t = 0; t < 16; ++t) {
    int col = t * 16 + li;
    float gv = g[col], bv = be[col];
#pragma unroll
    for (int r = 0; r < 4; ++r) {
      int row = m0 + w * 16 + g16 * 4 + r;
      out[(size_t)row * 256 + col] = (acc2[t][r] - s[r]) * q[r] * gv + bv;
    }
  }
}

// ---------------------------------------------------------------- launch
extern "C" void kernel_launch(void* const* d_in, const int* in_sizes, int n_in,
                              void* d_out, int out_size, void* d_ws, size_t ws_size,
                              hipStream_t stream) {
  const float* X    = (const float*)d_in[0];
  const float* Wqkv = (const float*)d_in[2];
  const float* bqkv = (const float*)d_in[3];
  const float* Wout = (const float*)d_in[4];
  const float* bout = (const float*)d_in[5];
  const float* W1   = (const float*)d_in[6];
  const float* b1   = (const float*)d_in[7];
  const float* W2   = (const float*)d_in[8];
  const float* b2   = (const float*)d_in[9];
  const float* g1   = (const float*)d_in[10];
  const float* be1  = (const float*)d_in[11];
  const float* g2   = (const float*)d_in[12];
  const float* be2  = (const float*)d_in[13];
  const float* rel1 = (const float*)d_in[14];
  const float* rel2 = (const float*)d_in[15];
  const float* rel4 = (const float*)d_in[16];
  const float* rel8 = (const float*)d_in[17];
  float* out = (float*)d_out;

  char* W = (char*)d_ws;
  ushort_t* qbb  = (ushort_t*)(W);                  // 23,068,672
  ushort_t* kbb  = (ushort_t*)(W + 23068672);       // 23,068,672
  ushort_t* vbb  = (ushort_t*)(W + 46137344);       // 23,068,672
  ushort_t* vbt  = (ushort_t*)(W + 69206016);       //  5,767,168
  ushort_t* ao   = (ushort_t*)(W + 74973184);       // 23,068,672
  const size_t F = 98041856;
  ushort_t* qw2  = (ushort_t*)(W + F);
  ushort_t* kw2  = (ushort_t*)(W + F + 5832704);
  ushort_t* vwt2 = (ushort_t*)(W + F + 11665408);
  ushort_t* qw4  = (ushort_t*)(W + F + 17432576);
  ushort_t* kw4  = (ushort_t*)(W + F + 23265280);
  ushort_t* vwt4 = (ushort_t*)(W + F + 29097984);
  ushort_t* qw8  = (ushort_t*)(W + F + 35389440);
  ushort_t* kw8  = (ushort_t*)(W + F + 41222144);
  ushort_t* vwt8 = (ushort_t*)(W + F + 47054848);
  ushort_t* Wqkvt= (ushort_t*)(W + F + 55443456);   //   393,216
  ushort_t* Woutt= (ushort_t*)(W + F + 55836672);   //   131,072
  char*     Wc   = (char*)    (W + F + 55967744);   // 2,097,152
  float*    x1   = (float*)(W);                     // reuse qbb+kbb after attention
  ushort_t* x1b  = (ushort_t*)(W + 46137344);       // reuse vbb after relays

  k_cvtw<<<dim3(8, 24), 256, 0, stream>>>(Wqkv, Wqkvt, 256, 768);
  k_cvtw<<<dim3(8, 8),  256, 0, stream>>>(Wout, Woutt, 256, 256);
  k_prepw1<<<dim3(2048), 256, 0, stream>>>(W1, Wc);
  k_prepw2<<<dim3(2048), 256, 0, stream>>>(W2, Wc);
  k_qkv2<<<dim3(704, 3), 256, 0, stream>>>(X, Wqkvt, bqkv, qbb, kbb, vbb);
  k_vt<<<dim3(64, 2), 256, 0, stream>>>(vbb, vbt);
  k_relay<2><<<dim3(44, 64, 2), 256, 0, stream>>>(qbb, kbb, vbb, qw2, kw2, vwt2, 1, 5);
  k_relay<4><<<dim3(11, 64, 2), 256, 0, stream>>>(qbb, kbb, vbb, qw4, kw4, vwt4, 2, 6);
  k_relay<8><<<dim3(3, 64, 2),  256, 0, stream>>>(qbb, kbb, vbb, qw8, kw8, vwt8, 3, 7);
  k_attn1m<<<dim3(11, 64, 2), 256, 0, stream>>>(qbb, kbb, vbt, rel1, ao);
  k_attnm<2, 256><<<dim3(11, 64, 2), 256, 0, stream>>>(qw2, kw2, vwt2, rel2, ao, 1, 5);
  k_attnm<4, 256><<<dim3(3, 64, 2),  256, 0, stream>>>(qw4, kw4, vwt4, rel4, ao, 2, 6);
  k_attnm<8, 512><<<dim3(1, 64, 2),  512, 0, stream>>>(qw8, kw8, vwt8, rel8, ao, 3, 7);
  k_projln<<<dim3(704), 256, 0, stream>>>(ao, Woutt, bout, X, g1, be1, x1, x1b);
  k_ffn3<<<dim3(352), 512, 0, stream>>>(x1b, x1, Wc, b1, b2, g2, be2, out);
}